// Round 7
// baseline (5441.639 us; speedup 1.0000x reference)
//
#include <hip/hip_runtime.h>
#include <math.h>

// ---------------------------------------------------------------------------
// Transformer_fPEPS: transformer (f32 VALU GEMMs) + PEPS amplitude.
//
// Math reduction (validated R1, absmax 3.8e-6): every SVD in the reference
// _compress is lossless gauge EXCEPT the bond-(2,3) truncation (64 -> chi=16)
// on each side. amp(b) = < rank16(Psi_L), rank16(Psi_R) >_F.
//
// R7: k_svd was occupancy-bound (64-thread blocks -> WG-slot cap ~9 waves/CU,
// OccupancyPercent 28, VALUBusy 56). Pack 4 independent waves (4 matrices)
// per 256-thread block, launch_bounds(256,4); rot threshold 1e-6 -> 1e-5
// (absmax headroom 140x).
// ---------------------------------------------------------------------------

#define BSZ   2048
#define NS    36
#define EMB   128
#define NHEAD 8
#define DH    16
#define HIDD  512
#define TOTV  10368

typedef float f16v __attribute__((ext_vector_type(16)));

__constant__ int c_offs[37] = {
    0,32,160,288,416,544,576,
    704,1216,1728,2240,2752,2880,
    3008,3520,4032,4544,5056,5184,
    5312,5824,6336,6848,7360,7488,
    7616,8128,8640,9152,9664,9792,
    9824,9952,10080,10208,10336,10368};

// (site, col-chunk) pairs for trimmed GEMM2: 84 pairs
__constant__ int c_ps[84] = {
    0,1,2,3,4,5,
    6,7,7,7,7,8,8,8,8,9,9,9,9,10,10,10,10,11,
    12,13,13,13,13,14,14,14,14,15,15,15,15,16,16,16,16,17,
    18,19,19,19,19,20,20,20,20,21,21,21,21,22,22,22,22,23,
    24,25,25,25,25,26,26,26,26,27,27,27,27,28,28,28,28,29,
    30,31,32,33,34,35};
__constant__ int c_pc[84] = {
    0,0,0,0,0,0,
    0,0,1,2,3,0,1,2,3,0,1,2,3,0,1,2,3,0,
    0,0,1,2,3,0,1,2,3,0,1,2,3,0,1,2,3,0,
    0,0,1,2,3,0,1,2,3,0,1,2,3,0,1,2,3,0,
    0,0,1,2,3,0,1,2,3,0,1,2,3,0,1,2,3,0,
    0,0,0,0,0,0};

// ------------------------------ K1: embed ----------------------------------
__global__ __launch_bounds__(256) void k_embed(const int* __restrict__ x,
        const float* __restrict__ emb, const float* __restrict__ pos,
        float* __restrict__ h) {
    int idx = blockIdx.x * 256 + threadIdx.x;
    if (idx >= BSZ * NS * EMB) return;
    int e = idx & (EMB - 1);
    int g = idx >> 7;            // token
    int s = g % NS;
    h[idx] = emb[x[g] * EMB + e] + pos[s * EMB + e];
}

// ------------------------------ K2a: QKV GEMM ------------------------------
// [73728 x 128] @ [128 x 384] + bias. 64 tokens x 128 cols per block.
__global__ __launch_bounds__(256) void k_qkv(const float* __restrict__ h,
        const float* __restrict__ Wqkv, const float* __restrict__ bqkv,
        float* __restrict__ qkv) {
    __shared__ float As[64 * 132];
    __shared__ float Ws[32 * 132];
    int tid = threadIdx.x;
    int chunk = blockIdx.x;          // 0..2 -> output cols chunk*128..+127
    int tok0 = blockIdx.y * 64;
    int tx = tid & 15, ty = tid >> 4;
    for (int idx = tid; idx < 64 * 128; idx += 256) {
        int t = idx >> 7, k = idx & 127;
        As[t * 132 + k] = h[(size_t)(tok0 + t) * EMB + k];
    }
    float acc[4][8];
    #pragma unroll
    for (int i = 0; i < 4; ++i)
        #pragma unroll
        for (int q = 0; q < 8; ++q) acc[i][q] = 0.f;
    for (int ks = 0; ks < 4; ++ks) {
        __syncthreads();
        for (int idx = tid; idx < 32 * 128; idx += 256) {
            int kk = idx >> 7, c = idx & 127;
            Ws[kk * 132 + c] = Wqkv[(size_t)(ks * 32 + kk) * 384 + chunk * 128 + c];
        }
        __syncthreads();
        #pragma unroll 4
        for (int kk = 0; kk < 32; ++kk) {
            float4 w0 = *(const float4*)&Ws[kk * 132 + tx * 8];
            float4 w1 = *(const float4*)&Ws[kk * 132 + tx * 8 + 4];
            #pragma unroll
            for (int i = 0; i < 4; ++i) {
                float a = As[(ty * 4 + i) * 132 + ks * 32 + kk];
                acc[i][0] += a * w0.x; acc[i][1] += a * w0.y;
                acc[i][2] += a * w0.z; acc[i][3] += a * w0.w;
                acc[i][4] += a * w1.x; acc[i][5] += a * w1.y;
                acc[i][6] += a * w1.z; acc[i][7] += a * w1.w;
            }
        }
    }
    #pragma unroll
    for (int i = 0; i < 4; ++i) {
        size_t base = (size_t)(tok0 + ty * 4 + i) * 384 + chunk * 128 + tx * 8;
        #pragma unroll
        for (int q = 0; q < 8; ++q)
            qkv[base + q] = acc[i][q] + bqkv[chunk * 128 + tx * 8 + q];
    }
}

// ------------------------------ K2b: attention core ------------------------
// One wave per (batch, head). q/k/v staged in padded LDS (stride 17),
// scores in stride-37 LDS, softmax per row, o overwrites the dead q-slot.
__global__ __launch_bounds__(256) void k_attnc(float* __restrict__ qkv) {
    __shared__ float qs[4][NS * 17];
    __shared__ float ks_[4][NS * 17];
    __shared__ float vs[4][NS * 17];
    __shared__ float S[4][NS * 37];
    int wid = threadIdx.x >> 6, lane = threadIdx.x & 63;
    int m = blockIdx.x * 4 + wid;
    int b = m >> 3, hd = m & 7;
    float* Q = qkv + (size_t)b * NS * 384 + hd * DH;   // row stride 384
    for (int idx = lane; idx < NS * DH; idx += 64) {
        int t = idx >> 4, d = idx & 15;
        qs[wid][t * 17 + d]  = Q[t * 384 + d];
        ks_[wid][t * 17 + d] = Q[t * 384 + 128 + d];
        vs[wid][t * 17 + d]  = Q[t * 384 + 256 + d];
    }
    __syncthreads();
    for (int idx = lane; idx < NS * NS; idx += 64) {
        int qp = idx / NS, kp = idx - qp * NS;
        float acc = 0.f;
        #pragma unroll
        for (int d = 0; d < DH; ++d)
            acc += qs[wid][qp * 17 + d] * ks_[wid][kp * 17 + d];
        S[wid][qp * 37 + kp] = acc * 0.25f;     // 1/sqrt(16)
    }
    __syncthreads();
    if (lane < NS) {
        float mx = -1e30f;
        for (int j = 0; j < NS; ++j) mx = fmaxf(mx, S[wid][lane * 37 + j]);
        float z = 0.f;
        for (int j = 0; j < NS; ++j) {
            float e = expf(S[wid][lane * 37 + j] - mx);
            S[wid][lane * 37 + j] = e; z += e;
        }
        float inv = 1.f / z;
        for (int j = 0; j < NS; ++j) S[wid][lane * 37 + j] *= inv;
    }
    __syncthreads();
    for (int idx = lane; idx < NS * DH; idx += 64) {
        int qp = idx >> 4, d = idx & 15;
        float acc = 0.f;
        for (int kp = 0; kp < NS; ++kp)
            acc += S[wid][qp * 37 + kp] * vs[wid][kp * 17 + d];
        Q[qp * 384 + d] = acc;                  // o into dead q-slot
    }
}

// ------------------------------ K2c: out-proj + residual -------------------
// h += o @ Wo + bo, o rows at qkv[tok*384 + 0..127].
__global__ __launch_bounds__(256) void k_oproj(const float* __restrict__ qkv,
        const float* __restrict__ Wo, const float* __restrict__ bo,
        float* __restrict__ h) {
    __shared__ float As[64 * 132];
    __shared__ float Ws[32 * 132];
    int tid = threadIdx.x;
    int tok0 = blockIdx.x * 64;
    int tx = tid & 15, ty = tid >> 4;
    for (int idx = tid; idx < 64 * 128; idx += 256) {
        int t = idx >> 7, k = idx & 127;
        As[t * 132 + k] = qkv[(size_t)(tok0 + t) * 384 + k];
    }
    float acc[4][8];
    #pragma unroll
    for (int i = 0; i < 4; ++i)
        #pragma unroll
        for (int q = 0; q < 8; ++q) acc[i][q] = 0.f;
    for (int ks = 0; ks < 4; ++ks) {
        __syncthreads();
        for (int idx = tid; idx < 32 * 128; idx += 256) {
            int kk = idx >> 7, c = idx & 127;
            Ws[kk * 132 + c] = Wo[(size_t)(ks * 32 + kk) * EMB + c];
        }
        __syncthreads();
        #pragma unroll 4
        for (int kk = 0; kk < 32; ++kk) {
            float4 w0 = *(const float4*)&Ws[kk * 132 + tx * 8];
            float4 w1 = *(const float4*)&Ws[kk * 132 + tx * 8 + 4];
            #pragma unroll
            for (int i = 0; i < 4; ++i) {
                float a = As[(ty * 4 + i) * 132 + ks * 32 + kk];
                acc[i][0] += a * w0.x; acc[i][1] += a * w0.y;
                acc[i][2] += a * w0.z; acc[i][3] += a * w0.w;
                acc[i][4] += a * w1.x; acc[i][5] += a * w1.y;
                acc[i][6] += a * w1.z; acc[i][7] += a * w1.w;
            }
        }
    }
    #pragma unroll
    for (int i = 0; i < 4; ++i) {
        size_t base = (size_t)(tok0 + ty * 4 + i) * EMB + tx * 8;
        #pragma unroll
        for (int q = 0; q < 8; ++q)
            h[base + q] = h[base + q] + acc[i][q] + bo[tx * 8 + q];
    }
}

// ------------------------------ K3a: GEMM1 (h@W1, gelu) --------------------
__global__ __launch_bounds__(256) void k_gemm1(const float* __restrict__ h,
        const float* __restrict__ W1, const float* __restrict__ b1,
        float* __restrict__ Hm) {
    __shared__ float As[64 * 132];   // [token][k], pad 132
    __shared__ float Ws[32 * 132];   // [kk][col], pad 132
    int tid = threadIdx.x;
    int chunk = blockIdx.x;          // 0..3 -> output cols chunk*128..+127
    int tok0 = blockIdx.y * 64;      // token tile (local to eighth)
    int tx = tid & 15, ty = tid >> 4;
    for (int idx = tid; idx < 64 * 128; idx += 256) {
        int t = idx >> 7, k = idx & 127;
        As[t * 132 + k] = h[(size_t)(tok0 + t) * EMB + k];
    }
    float acc[4][8];
    #pragma unroll
    for (int i = 0; i < 4; ++i)
        #pragma unroll
        for (int q = 0; q < 8; ++q) acc[i][q] = 0.f;
    for (int ks = 0; ks < 4; ++ks) {
        __syncthreads();
        for (int idx = tid; idx < 32 * 128; idx += 256) {
            int kk = idx >> 7, c = idx & 127;
            Ws[kk * 132 + c] = W1[(size_t)(ks * 32 + kk) * HIDD + chunk * 128 + c];
        }
        __syncthreads();
        #pragma unroll 4
        for (int kk = 0; kk < 32; ++kk) {
            float4 w0 = *(const float4*)&Ws[kk * 132 + tx * 8];
            float4 w1 = *(const float4*)&Ws[kk * 132 + tx * 8 + 4];
            #pragma unroll
            for (int i = 0; i < 4; ++i) {
                float a = As[(ty * 4 + i) * 132 + ks * 32 + kk];
                acc[i][0] += a * w0.x; acc[i][1] += a * w0.y;
                acc[i][2] += a * w0.z; acc[i][3] += a * w0.w;
                acc[i][4] += a * w1.x; acc[i][5] += a * w1.y;
                acc[i][6] += a * w1.z; acc[i][7] += a * w1.w;
            }
        }
    }
    #pragma unroll
    for (int i = 0; i < 4; ++i) {
        size_t base = (size_t)(tok0 + ty * 4 + i) * HIDD + chunk * 128 + tx * 8;
        #pragma unroll
        for (int q = 0; q < 8; ++q) {
            float a = acc[i][q] + b1[chunk * 128 + tx * 8 + q];
            Hm[base + q] = 0.5f * a * (1.f + erff(a * 0.70710678118654752f));
        }
    }
}

// ------------------------------ K3b: GEMM2 (Hm@W2, backflow) ---------------
__global__ __launch_bounds__(256) void k_gemm2(const float* __restrict__ Hm,
        const float* __restrict__ W2, const float* __restrict__ b2,
        const float* __restrict__ ftn, float* __restrict__ vecs, int e8) {
    __shared__ float As[64 * 33];    // [batch][kk], pad 33
    __shared__ float Ws[32 * 132];   // [kk][col], pad 132
    int tid = threadIdx.x;
    int pair = blockIdx.x;
    int s = c_ps[pair], chunk = c_pc[pair];
    int b0 = blockIdx.y * 64;        // batch tile (local to eighth)
    int off = c_offs[s], size = c_offs[s + 1] - off;
    int tx = tid & 15, ty = tid >> 4;
    float acc[4][8];
    #pragma unroll
    for (int i = 0; i < 4; ++i)
        #pragma unroll
        for (int q = 0; q < 8; ++q) acc[i][q] = 0.f;
    for (int ks = 0; ks < 16; ++ks) {
        __syncthreads();
        for (int idx = tid; idx < 64 * 32; idx += 256) {
            int t = idx >> 5, kk = idx & 31;
            As[t * 33 + kk] = Hm[(size_t)((b0 + t) * NS + s) * HIDD + ks * 32 + kk];
        }
        for (int idx = tid; idx < 32 * 128; idx += 256) {
            int kk = idx >> 7, c = idx & 127;
            Ws[kk * 132 + c] = W2[(size_t)(ks * 32 + kk) * HIDD + chunk * 128 + c];
        }
        __syncthreads();
        #pragma unroll 4
        for (int kk = 0; kk < 32; ++kk) {
            float4 w0 = *(const float4*)&Ws[kk * 132 + tx * 8];
            float4 w1 = *(const float4*)&Ws[kk * 132 + tx * 8 + 4];
            #pragma unroll
            for (int i = 0; i < 4; ++i) {
                float a = As[(ty * 4 + i) * 33 + kk];
                acc[i][0] += a * w0.x; acc[i][1] += a * w0.y;
                acc[i][2] += a * w0.z; acc[i][3] += a * w0.w;
                acc[i][4] += a * w1.x; acc[i][5] += a * w1.y;
                acc[i][6] += a * w1.z; acc[i][7] += a * w1.w;
            }
        }
    }
    #pragma unroll
    for (int i = 0; i < 4; ++i) {
        int bg = e8 * 256 + b0 + ty * 4 + i;     // global batch
        #pragma unroll
        for (int q = 0; q < 8; ++q) {
            int col = chunk * 128 + tx * 8 + q;
            if (col < size) {
                float o = acc[i][q] + b2[col];
                vecs[(size_t)bg * TOTV + off + col] = ftn[off + col] + 0.1f * o;
            }
        }
    }
}

// ------------------------------ K4a: build Psi -----------------------------
__device__ __forceinline__ float* build_half(const float* __restrict__ vb,
        const int* __restrict__ xb, int side, int upper,
        float* cur, float* fre, float* ts0, float* ts1, float* ts2, int tid) {
    if (tid == 0) cur[0] = 1.0f;
    __syncthreads();
    int bd = 1, lgbd = 0;
    for (int t = 0; t < 3; ++t) {
        int xd = t ? 4 : 1, lgxd = t ? 2 : 0;
        int j = side ? (5 - t) : t;
        int rows[3];
        rows[0] = upper ? 0 : 5; rows[1] = upper ? 1 : 4; rows[2] = upper ? 2 : 3;
        for (int role = 0; role < 3; ++role) {
            int i = rows[role];
            int dd = (i < 5) ? 4 : 1, dl = (j > 0) ? 4 : 1, dr = (j < 5) ? 4 : 1;
            int su = dd * dl * dr * 2, sd = dl * dr * 2, sl = dr * 2, sr = 2;
            int xstr = side ? sr : sl, ystr = side ? sl : sr;
            int base = c_offs[i * 6 + j] + xb[i * 6 + j];
            if (role == 0) {
                int astr = upper ? sd : su;
                int n = 4 * xd * 4;
                for (int idx = tid; idx < n; idx += 256) {
                    int y = idx & 3, xx = (idx >> 2) & (xd - 1), a = idx >> (2 + lgxd);
                    ts0[idx] = vb[base + a * astr + xx * xstr + y * ystr];
                }
            } else if (role == 1) {
                int astr = upper ? su : sd, cstr = upper ? sd : su;
                int n = 16 * xd * 4;
                for (int idx = tid; idx < n; idx += 256) {
                    int y = idx & 3, xx = (idx >> 2) & (xd - 1);
                    int c = (idx >> (2 + lgxd)) & 3, a = idx >> (4 + lgxd);
                    ts1[idx] = vb[base + a * astr + c * cstr + xx * xstr + y * ystr];
                }
            } else {
                int cstr = upper ? su : sd, bstr = upper ? sd : su;
                int n = 16 * xd * 4;
                for (int idx = tid; idx < n; idx += 256) {
                    int y = idx & 3, xx = (idx >> 2) & (xd - 1);
                    int bb = (idx >> (2 + lgxd)) & 3, c = idx >> (4 + lgxd);
                    ts2[idx] = vb[base + c * cstr + bb * bstr + xx * xstr + y * ystr];
                }
            }
        }
        __syncthreads();
        int n1 = 16 * xd * xd * bd;
        for (int idx = tid; idx < n1; idx += 256) {
            int bt = idx & (bd - 1);
            int r = idx >> lgbd;
            int x2 = r & (xd - 1); r >>= lgxd;
            int x1 = r & (xd - 1); r >>= lgxd;
            int a = r & 3, y0 = r >> 2;
            float s2 = 0.f;
            for (int x0 = 0; x0 < xd; ++x0)
                s2 += cur[(((((x0 << lgxd) | x1) << lgxd) | x2) << lgbd) | bt]
                    * ts0[(((a << lgxd) | x0) << 2) | y0];
            fre[idx] = s2;
        }
        __syncthreads();
        int n2 = 64 * xd * bd;
        for (int idx = tid; idx < n2; idx += 256) {
            int bt = idx & (bd - 1);
            int r = idx >> lgbd;
            int x2 = r & (xd - 1); r >>= lgxd;
            int c = r & 3, y1 = (r >> 2) & 3, y0 = r >> 4;
            float s2 = 0.f;
            for (int a = 0; a < 4; ++a)
                for (int x1 = 0; x1 < xd; ++x1)
                    s2 += fre[((((((((y0 << 2) | a) << lgxd) | x1) << lgxd) | x2)) << lgbd) | bt]
                        * ts1[((((a * 4 + c) << lgxd) | x1) << 2) | y1];
            cur[idx] = s2;
        }
        __syncthreads();
        int n3 = 256 * bd;
        for (int idx = tid; idx < n3; idx += 256) {
            int bn = idx & (4 * bd - 1);
            int bt = bn >> 2, bb = bn & 3;
            int r = idx >> (lgbd + 2);
            int y2 = r & 3, y1 = (r >> 2) & 3, y0 = r >> 4;
            float s2 = 0.f;
            for (int c = 0; c < 4; ++c)
                for (int x2 = 0; x2 < xd; ++x2)
                    s2 += cur[((((((y0 << 2) | y1) << 2 | c) << lgxd) | x2) << lgbd) | bt]
                        * ts2[((((c * 4 + bb) << lgxd) | x2) << 2) | y2];
            fre[idx] = s2;
        }
        __syncthreads();
        float* tmp = cur; cur = fre; fre = tmp;
        bd <<= 2; lgbd += 2;
    }
    return cur;
}

__global__ __launch_bounds__(256) void k_build(const float* __restrict__ vecs,
        const int* __restrict__ x, float* __restrict__ psi) {
    __shared__ float X1[4096], X2[4096], X3[4096];
    __shared__ float ts0[64], ts1[256], ts2[256];
    int m = blockIdx.x;
    int b = m >> 1, side = m & 1;
    int tid = threadIdx.x;
    const float* vb = vecs + (size_t)b * TOTV;
    const int* xb = x + b * NS;
    float* A  = build_half(vb, xb, side, 1, X1, X2, ts0, ts1, ts2, tid);
    float* Bt = build_half(vb, xb, side, 0, X1, X3, ts0, ts1, ts2, tid);
    float* po = psi + (size_t)m * 4096;
    for (int idx = tid; idx < 4096; idx += 256) {
        int u = idx >> 6, l = idx & 63;
        const float4* a4 = (const float4*)(A + u * 64);
        const float4* b4 = (const float4*)(Bt + l * 64);
        float s2 = 0.f;
        #pragma unroll
        for (int q = 0; q < 16; ++q) {
            float4 av = a4[q], bv = b4[q];
            s2 += av.x * bv.x + av.y * bv.y + av.z * bv.z + av.w * bv.w;
        }
        po[idx] = s2;
    }
}

// ------------------------------ K4b: Jacobi SVD ----------------------------
// R7: 4 waves per 256-thread block, each wave owns one 64x64 matrix (no
// inter-wave deps until the epilogue __syncthreads). Lane j holds column j
// of W in 4 ext_vector(16) values (constant-indexed after unroll -> VGPRs).
// Epilogue: Q = top-16 normalized cols, T = Q^T Psi via per-wave LDS slab.
__global__ __launch_bounds__(256, 4) void k_svd(const float* __restrict__ psi,
                                                float* __restrict__ wv) {
    __shared__ __align__(16) float qlds[4][64 * 20];   // per-wave Q slab
    int wid = threadIdx.x >> 6, lane = threadIdx.x & 63;
    int m = blockIdx.x * 4 + wid;
    const float* P = psi + (size_t)m * 4096;
    f16v w0, w1, w2, w3;
    #pragma unroll
    for (int r = 0; r < 16; ++r) w0[r] = P[r * 64 + lane];
    #pragma unroll
    for (int r = 0; r < 16; ++r) w1[r] = P[(r + 16) * 64 + lane];
    #pragma unroll
    for (int r = 0; r < 16; ++r) w2[r] = P[(r + 32) * 64 + lane];
    #pragma unroll
    for (int r = 0; r < 16; ++r) w3[r] = P[(r + 48) * 64 + lane];

    float n2 = 0.f;
    for (int sweep = 0; sweep < 10; ++sweep) {
        n2 = 0.f;                               // exact refresh per sweep
        #pragma unroll
        for (int r = 0; r < 16; ++r)
            n2 += w0[r] * w0[r] + w1[r] * w1[r] + w2[r] * w2[r] + w3[r] * w3[r];
        bool any = false;
        for (int mm = 1; mm < 64; ++mm) {
            int partner = lane ^ mm;
            f16v p0, p1, p2, p3;
            #pragma unroll
            for (int r = 0; r < 16; ++r) p0[r] = __shfl(w0[r], partner);
            #pragma unroll
            for (int r = 0; r < 16; ++r) p1[r] = __shfl(w1[r], partner);
            #pragma unroll
            for (int r = 0; r < 16; ++r) p2[r] = __shfl(w2[r], partner);
            #pragma unroll
            for (int r = 0; r < 16; ++r) p3[r] = __shfl(w3[r], partner);
            float gam = 0.f;
            #pragma unroll
            for (int r = 0; r < 16; ++r)
                gam += w0[r] * p0[r] + w1[r] * p1[r] + w2[r] * p2[r] + w3[r] * p3[r];
            float beta2 = __shfl(n2, partner);
            bool rot = fabsf(gam) > 1e-5f * sqrtf(fmaxf(n2 * beta2, 0.f));
            unsigned long long bal = __ballot(rot);
            if (bal == 0ull) continue;
            any = true;
            float c = 1.f, s = 0.f;
            if (rot) {
                float zeta = (n2 - beta2) / (2.f * gam);
                float sgn = (zeta > 0.f) ? 1.f :
                            ((zeta < 0.f) ? -1.f : ((lane < partner) ? 1.f : -1.f));
                float tt = sgn / (fabsf(zeta) + sqrtf(1.f + zeta * zeta));
                c = 1.f / sqrtf(1.f + tt * tt);
                s = c * tt;
            }
            #pragma unroll
            for (int r = 0; r < 16; ++r) {
                w0[r] = c * w0[r] + s * p0[r];
                w1[r] = c * w1[r] + s * p1[r];
                w2[r] = c * w2[r] + s * p2[r];
                w3[r] = c * w3[r] + s * p3[r];
            }
            n2 = c * c * n2 + s * s * beta2 + 2.f * c * s * gam;
        }
        if (!any) break;
    }
    // exact norms -> rank by descending norm (index tie-break)
    float n2e = 0.f;
    #pragma unroll
    for (int r = 0; r < 16; ++r)
        n2e += w0[r] * w0[r] + w1[r] * w1[r] + w2[r] * w2[r] + w3[r] * w3[r];
    int rank = 0;
    for (int j = 0; j < 64; ++j) {
        float nj = __shfl(n2e, j);
        if (nj > n2e || (nj == n2e && j < lane)) ++rank;
    }
    float inv = (n2e > 1e-30f) ? 1.f / sqrtf(n2e) : 0.f;
    // stage Q (top-16 normalized columns) into this wave's LDS slab
    if (rank < 16) {
        #pragma unroll
        for (int r = 0; r < 16; ++r) {
            qlds[wid][r * 20 + rank]        = w0[r] * inv;
            qlds[wid][(r + 16) * 20 + rank] = w1[r] * inv;
            qlds[wid][(r + 32) * 20 + rank] = w2[r] * inv;
            qlds[wid][(r + 48) * 20 + rank] = w3[r] * inv;
        }
    }
    __syncthreads();
    float* o = wv + (size_t)m * 2048;
    #pragma unroll
    for (int k = 0; k < 16; ++k) o[k * 64 + lane] = qlds[wid][lane * 20 + k];
    // T = Q^T Psi : lane computes T[0..15][lane], re-reading Psi from L2
    f16v t;
    #pragma unroll
    for (int k = 0; k < 16; ++k) t[k] = 0.f;
    for (int r = 0; r < 64; ++r) {
        float pr = P[r * 64 + lane];
        const float4* q4 = (const float4*)&qlds[wid][r * 20];
        float4 a = q4[0], b = q4[1], cc = q4[2], d = q4[3];
        t[0]  += a.x  * pr; t[1]  += a.y  * pr; t[2]  += a.z  * pr; t[3]  += a.w  * pr;
        t[4]  += b.x  * pr; t[5]  += b.y  * pr; t[6]  += b.z  * pr; t[7]  += b.w  * pr;
        t[8]  += cc.x * pr; t[9]  += cc.y * pr; t[10] += cc.z * pr; t[11] += cc.w * pr;
        t[12] += d.x  * pr; t[13] += d.y  * pr; t[14] += d.z  * pr; t[15] += d.w  * pr;
    }
    #pragma unroll
    for (int k = 0; k < 16; ++k) o[1024 + k * 64 + lane] = t[k];
}

// ------------------------------ K4c: amplitude -----------------------------
__global__ __launch_bounds__(256) void k_amp(const float* __restrict__ wv,
                                             float* __restrict__ out) {
    __shared__ float s[4096];
    __shared__ float part[4];
    int b = blockIdx.x, tid = threadIdx.x;
    const float* src = wv + (size_t)b * 4096;
    for (int i = tid; i < 4096; i += 256) s[i] = src[i];
    __syncthreads();
    int k = tid >> 4, mm = tid & 15;
    const float* WL = s;
    const float* VL = s + 1024;
    const float* WR = s + 2048;
    const float* VR = s + 3072;
    float du = 0.f, dv = 0.f;
    for (int r = 0; r < 64; ++r) {
        du += WL[k * 64 + r] * WR[mm * 64 + r];
        dv += VL[k * 64 + r] * VR[mm * 64 + r];
    }
    float p = du * dv;
    for (int off = 32; off > 0; off >>= 1) p += __shfl_down(p, off);
    if ((tid & 63) == 0) part[tid >> 6] = p;
    __syncthreads();
    if (tid == 0) out[b] = part[0] + part[1] + part[2] + part[3];
}

// ------------------------------ launch -------------------------------------
extern "C" void kernel_launch(void* const* d_in, const int* in_sizes, int n_in,
                              void* d_out, int out_size, void* d_ws, size_t ws_size,
                              hipStream_t stream) {
    const int*   x    = (const int*)d_in[0];
    const float* ftn  = (const float*)d_in[1];
    const float* emb  = (const float*)d_in[2];
    const float* pos  = (const float*)d_in[3];
    const float* Wqkv = (const float*)d_in[4];
    const float* bqkv = (const float*)d_in[5];
    const float* Wo   = (const float*)d_in[6];
    const float* bo   = (const float*)d_in[7];
    const float* W1   = (const float*)d_in[8];
    const float* b1   = (const float*)d_in[9];
    const float* W2   = (const float*)d_in[10];
    const float* b2   = (const float*)d_in[11];
    float* out = (float*)d_out;
    float* ws  = (float*)d_ws;

    // layout (floats), total 46.4M = 186 MB:
    //   [0, 16777216)           psi; h at [0, 9437184), Hm_e at [9437184,..)
    //   [16777216, 38010880)    vecs (2048*10368)
    //   [38010880, 46399488)    wv
    //   qkv (28.3M) transiently occupies [16777216, 45088768) -- dead before
    //   gemm2 writes vecs and before svd writes wv.
    float* h    = ws;
    float* Hm_e = ws + 9437184;          // 2304 tokens * 512
    float* psi  = ws;
    float* vecs = ws + 16777216;
    float* qkv  = ws + 16777216;
    float* wv   = ws + 16777216 + 21233664;

    hipLaunchKernelGGL(k_embed, dim3((BSZ * NS * EMB + 255) / 256), dim3(256), 0, stream,
                       x, emb, pos, h);
    hipLaunchKernelGGL(k_qkv, dim3(3, 1152), dim3(256), 0, stream,
                       h, Wqkv, bqkv, qkv);
    hipLaunchKernelGGL(k_attnc, dim3(BSZ * NHEAD / 4), dim3(256), 0, stream, qkv);
    hipLaunchKernelGGL(k_oproj, dim3(1152), dim3(256), 0, stream,
                       qkv, Wo, bo, h);
    for (int e8 = 0; e8 < 8; ++e8) {
        const float* h_e = h + (size_t)e8 * 9216 * EMB;
        hipLaunchKernelGGL(k_gemm1, dim3(4, 144), dim3(256), 0, stream,
                           h_e, W1, b1, Hm_e);
        hipLaunchKernelGGL(k_gemm2, dim3(84, 4), dim3(256), 0, stream,
                           Hm_e, W2, b2, ftn, vecs, e8);
    }
    hipLaunchKernelGGL(k_build, dim3(2 * BSZ), dim3(256), 0, stream, vecs, x, psi);
    hipLaunchKernelGGL(k_svd, dim3(BSZ / 2), dim3(256), 0, stream, psi, wv);
    hipLaunchKernelGGL(k_amp, dim3(BSZ), dim3(256), 0, stream, wv, out);
}

// Round 8
// 3796.811 us; speedup vs baseline: 1.4332x; 1.4332x over previous
//
#include <hip/hip_runtime.h>
#include <math.h>

// ---------------------------------------------------------------------------
// Transformer_fPEPS: transformer (f32 VALU GEMMs) + PEPS amplitude.
//
// Math reduction (validated R1, absmax 3.8e-6): every SVD in the reference
// _compress is lossless gauge EXCEPT the bond-(2,3) truncation (64 -> chi=16)
// on each side. amp(b) = < rank16(Psi_L), rank16(Psi_R) >_F.
//
// R8: R7's launch_bounds(256,4) capped VGPRs at 64 -> W spilled to scratch
// (WRITE_SIZE 33MB -> 3.37GB, dur 2.07 -> 3.84ms). Keep the 4-wave packing,
// relax to launch_bounds(256,2): VGPR cap 256, compiler uses ~76-100 with
// zero spill (R5 evidence); register-limited residency ~6 waves/SIMD.
// ---------------------------------------------------------------------------

#define BSZ   2048
#define NS    36
#define EMB   128
#define NHEAD 8
#define DH    16
#define HIDD  512
#define TOTV  10368

typedef float f16v __attribute__((ext_vector_type(16)));

__constant__ int c_offs[37] = {
    0,32,160,288,416,544,576,
    704,1216,1728,2240,2752,2880,
    3008,3520,4032,4544,5056,5184,
    5312,5824,6336,6848,7360,7488,
    7616,8128,8640,9152,9664,9792,
    9824,9952,10080,10208,10336,10368};

// (site, col-chunk) pairs for trimmed GEMM2: 84 pairs
__constant__ int c_ps[84] = {
    0,1,2,3,4,5,
    6,7,7,7,7,8,8,8,8,9,9,9,9,10,10,10,10,11,
    12,13,13,13,13,14,14,14,14,15,15,15,15,16,16,16,16,17,
    18,19,19,19,19,20,20,20,20,21,21,21,21,22,22,22,22,23,
    24,25,25,25,25,26,26,26,26,27,27,27,27,28,28,28,28,29,
    30,31,32,33,34,35};
__constant__ int c_pc[84] = {
    0,0,0,0,0,0,
    0,0,1,2,3,0,1,2,3,0,1,2,3,0,1,2,3,0,
    0,0,1,2,3,0,1,2,3,0,1,2,3,0,1,2,3,0,
    0,0,1,2,3,0,1,2,3,0,1,2,3,0,1,2,3,0,
    0,0,1,2,3,0,1,2,3,0,1,2,3,0,1,2,3,0,
    0,0,0,0,0,0};

// ------------------------------ K1: embed ----------------------------------
__global__ __launch_bounds__(256) void k_embed(const int* __restrict__ x,
        const float* __restrict__ emb, const float* __restrict__ pos,
        float* __restrict__ h) {
    int idx = blockIdx.x * 256 + threadIdx.x;
    if (idx >= BSZ * NS * EMB) return;
    int e = idx & (EMB - 1);
    int g = idx >> 7;            // token
    int s = g % NS;
    h[idx] = emb[x[g] * EMB + e] + pos[s * EMB + e];
}

// ------------------------------ K2a: QKV GEMM ------------------------------
// [73728 x 128] @ [128 x 384] + bias. 64 tokens x 128 cols per block.
__global__ __launch_bounds__(256) void k_qkv(const float* __restrict__ h,
        const float* __restrict__ Wqkv, const float* __restrict__ bqkv,
        float* __restrict__ qkv) {
    __shared__ float As[64 * 132];
    __shared__ float Ws[32 * 132];
    int tid = threadIdx.x;
    int chunk = blockIdx.x;          // 0..2 -> output cols chunk*128..+127
    int tok0 = blockIdx.y * 64;
    int tx = tid & 15, ty = tid >> 4;
    for (int idx = tid; idx < 64 * 128; idx += 256) {
        int t = idx >> 7, k = idx & 127;
        As[t * 132 + k] = h[(size_t)(tok0 + t) * EMB + k];
    }
    float acc[4][8];
    #pragma unroll
    for (int i = 0; i < 4; ++i)
        #pragma unroll
        for (int q = 0; q < 8; ++q) acc[i][q] = 0.f;
    for (int ks = 0; ks < 4; ++ks) {
        __syncthreads();
        for (int idx = tid; idx < 32 * 128; idx += 256) {
            int kk = idx >> 7, c = idx & 127;
            Ws[kk * 132 + c] = Wqkv[(size_t)(ks * 32 + kk) * 384 + chunk * 128 + c];
        }
        __syncthreads();
        #pragma unroll 4
        for (int kk = 0; kk < 32; ++kk) {
            float4 w0 = *(const float4*)&Ws[kk * 132 + tx * 8];
            float4 w1 = *(const float4*)&Ws[kk * 132 + tx * 8 + 4];
            #pragma unroll
            for (int i = 0; i < 4; ++i) {
                float a = As[(ty * 4 + i) * 132 + ks * 32 + kk];
                acc[i][0] += a * w0.x; acc[i][1] += a * w0.y;
                acc[i][2] += a * w0.z; acc[i][3] += a * w0.w;
                acc[i][4] += a * w1.x; acc[i][5] += a * w1.y;
                acc[i][6] += a * w1.z; acc[i][7] += a * w1.w;
            }
        }
    }
    #pragma unroll
    for (int i = 0; i < 4; ++i) {
        size_t base = (size_t)(tok0 + ty * 4 + i) * 384 + chunk * 128 + tx * 8;
        #pragma unroll
        for (int q = 0; q < 8; ++q)
            qkv[base + q] = acc[i][q] + bqkv[chunk * 128 + tx * 8 + q];
    }
}

// ------------------------------ K2b: attention core ------------------------
// One wave per (batch, head). q/k/v staged in padded LDS (stride 17),
// scores in stride-37 LDS, softmax per row, o overwrites the dead q-slot.
__global__ __launch_bounds__(256) void k_attnc(float* __restrict__ qkv) {
    __shared__ float qs[4][NS * 17];
    __shared__ float ks_[4][NS * 17];
    __shared__ float vs[4][NS * 17];
    __shared__ float S[4][NS * 37];
    int wid = threadIdx.x >> 6, lane = threadIdx.x & 63;
    int m = blockIdx.x * 4 + wid;
    int b = m >> 3, hd = m & 7;
    float* Q = qkv + (size_t)b * NS * 384 + hd * DH;   // row stride 384
    for (int idx = lane; idx < NS * DH; idx += 64) {
        int t = idx >> 4, d = idx & 15;
        qs[wid][t * 17 + d]  = Q[t * 384 + d];
        ks_[wid][t * 17 + d] = Q[t * 384 + 128 + d];
        vs[wid][t * 17 + d]  = Q[t * 384 + 256 + d];
    }
    __syncthreads();
    for (int idx = lane; idx < NS * NS; idx += 64) {
        int qp = idx / NS, kp = idx - qp * NS;
        float acc = 0.f;
        #pragma unroll
        for (int d = 0; d < DH; ++d)
            acc += qs[wid][qp * 17 + d] * ks_[wid][kp * 17 + d];
        S[wid][qp * 37 + kp] = acc * 0.25f;     // 1/sqrt(16)
    }
    __syncthreads();
    if (lane < NS) {
        float mx = -1e30f;
        for (int j = 0; j < NS; ++j) mx = fmaxf(mx, S[wid][lane * 37 + j]);
        float z = 0.f;
        for (int j = 0; j < NS; ++j) {
            float e = expf(S[wid][lane * 37 + j] - mx);
            S[wid][lane * 37 + j] = e; z += e;
        }
        float inv = 1.f / z;
        for (int j = 0; j < NS; ++j) S[wid][lane * 37 + j] *= inv;
    }
    __syncthreads();
    for (int idx = lane; idx < NS * DH; idx += 64) {
        int qp = idx >> 4, d = idx & 15;
        float acc = 0.f;
        for (int kp = 0; kp < NS; ++kp)
            acc += S[wid][qp * 37 + kp] * vs[wid][kp * 17 + d];
        Q[qp * 384 + d] = acc;                  // o into dead q-slot
    }
}

// ------------------------------ K2c: out-proj + residual -------------------
// h += o @ Wo + bo, o rows at qkv[tok*384 + 0..127].
__global__ __launch_bounds__(256) void k_oproj(const float* __restrict__ qkv,
        const float* __restrict__ Wo, const float* __restrict__ bo,
        float* __restrict__ h) {
    __shared__ float As[64 * 132];
    __shared__ float Ws[32 * 132];
    int tid = threadIdx.x;
    int tok0 = blockIdx.x * 64;
    int tx = tid & 15, ty = tid >> 4;
    for (int idx = tid; idx < 64 * 128; idx += 256) {
        int t = idx >> 7, k = idx & 127;
        As[t * 132 + k] = qkv[(size_t)(tok0 + t) * 384 + k];
    }
    float acc[4][8];
    #pragma unroll
    for (int i = 0; i < 4; ++i)
        #pragma unroll
        for (int q = 0; q < 8; ++q) acc[i][q] = 0.f;
    for (int ks = 0; ks < 4; ++ks) {
        __syncthreads();
        for (int idx = tid; idx < 32 * 128; idx += 256) {
            int kk = idx >> 7, c = idx & 127;
            Ws[kk * 132 + c] = Wo[(size_t)(ks * 32 + kk) * EMB + c];
        }
        __syncthreads();
        #pragma unroll 4
        for (int kk = 0; kk < 32; ++kk) {
            float4 w0 = *(const float4*)&Ws[kk * 132 + tx * 8];
            float4 w1 = *(const float4*)&Ws[kk * 132 + tx * 8 + 4];
            #pragma unroll
            for (int i = 0; i < 4; ++i) {
                float a = As[(ty * 4 + i) * 132 + ks * 32 + kk];
                acc[i][0] += a * w0.x; acc[i][1] += a * w0.y;
                acc[i][2] += a * w0.z; acc[i][3] += a * w0.w;
                acc[i][4] += a * w1.x; acc[i][5] += a * w1.y;
                acc[i][6] += a * w1.z; acc[i][7] += a * w1.w;
            }
        }
    }
    #pragma unroll
    for (int i = 0; i < 4; ++i) {
        size_t base = (size_t)(tok0 + ty * 4 + i) * EMB + tx * 8;
        #pragma unroll
        for (int q = 0; q < 8; ++q)
            h[base + q] = h[base + q] + acc[i][q] + bo[tx * 8 + q];
    }
}

// ------------------------------ K3a: GEMM1 (h@W1, gelu) --------------------
__global__ __launch_bounds__(256) void k_gemm1(const float* __restrict__ h,
        const float* __restrict__ W1, const float* __restrict__ b1,
        float* __restrict__ Hm) {
    __shared__ float As[64 * 132];   // [token][k], pad 132
    __shared__ float Ws[32 * 132];   // [kk][col], pad 132
    int tid = threadIdx.x;
    int chunk = blockIdx.x;          // 0..3 -> output cols chunk*128..+127
    int tok0 = blockIdx.y * 64;      // token tile (local to eighth)
    int tx = tid & 15, ty = tid >> 4;
    for (int idx = tid; idx < 64 * 128; idx += 256) {
        int t = idx >> 7, k = idx & 127;
        As[t * 132 + k] = h[(size_t)(tok0 + t) * EMB + k];
    }
    float acc[4][8];
    #pragma unroll
    for (int i = 0; i < 4; ++i)
        #pragma unroll
        for (int q = 0; q < 8; ++q) acc[i][q] = 0.f;
    for (int ks = 0; ks < 4; ++ks) {
        __syncthreads();
        for (int idx = tid; idx < 32 * 128; idx += 256) {
            int kk = idx >> 7, c = idx & 127;
            Ws[kk * 132 + c] = W1[(size_t)(ks * 32 + kk) * HIDD + chunk * 128 + c];
        }
        __syncthreads();
        #pragma unroll 4
        for (int kk = 0; kk < 32; ++kk) {
            float4 w0 = *(const float4*)&Ws[kk * 132 + tx * 8];
            float4 w1 = *(const float4*)&Ws[kk * 132 + tx * 8 + 4];
            #pragma unroll
            for (int i = 0; i < 4; ++i) {
                float a = As[(ty * 4 + i) * 132 + ks * 32 + kk];
                acc[i][0] += a * w0.x; acc[i][1] += a * w0.y;
                acc[i][2] += a * w0.z; acc[i][3] += a * w0.w;
                acc[i][4] += a * w1.x; acc[i][5] += a * w1.y;
                acc[i][6] += a * w1.z; acc[i][7] += a * w1.w;
            }
        }
    }
    #pragma unroll
    for (int i = 0; i < 4; ++i) {
        size_t base = (size_t)(tok0 + ty * 4 + i) * HIDD + chunk * 128 + tx * 8;
        #pragma unroll
        for (int q = 0; q < 8; ++q) {
            float a = acc[i][q] + b1[chunk * 128 + tx * 8 + q];
            Hm[base + q] = 0.5f * a * (1.f + erff(a * 0.70710678118654752f));
        }
    }
}

// ------------------------------ K3b: GEMM2 (Hm@W2, backflow) ---------------
__global__ __launch_bounds__(256) void k_gemm2(const float* __restrict__ Hm,
        const float* __restrict__ W2, const float* __restrict__ b2,
        const float* __restrict__ ftn, float* __restrict__ vecs, int e8) {
    __shared__ float As[64 * 33];    // [batch][kk], pad 33
    __shared__ float Ws[32 * 132];   // [kk][col], pad 132
    int tid = threadIdx.x;
    int pair = blockIdx.x;
    int s = c_ps[pair], chunk = c_pc[pair];
    int b0 = blockIdx.y * 64;        // batch tile (local to eighth)
    int off = c_offs[s], size = c_offs[s + 1] - off;
    int tx = tid & 15, ty = tid >> 4;
    float acc[4][8];
    #pragma unroll
    for (int i = 0; i < 4; ++i)
        #pragma unroll
        for (int q = 0; q < 8; ++q) acc[i][q] = 0.f;
    for (int ks = 0; ks < 16; ++ks) {
        __syncthreads();
        for (int idx = tid; idx < 64 * 32; idx += 256) {
            int t = idx >> 5, kk = idx & 31;
            As[t * 33 + kk] = Hm[(size_t)((b0 + t) * NS + s) * HIDD + ks * 32 + kk];
        }
        for (int idx = tid; idx < 32 * 128; idx += 256) {
            int kk = idx >> 7, c = idx & 127;
            Ws[kk * 132 + c] = W2[(size_t)(ks * 32 + kk) * HIDD + chunk * 128 + c];
        }
        __syncthreads();
        #pragma unroll 4
        for (int kk = 0; kk < 32; ++kk) {
            float4 w0 = *(const float4*)&Ws[kk * 132 + tx * 8];
            float4 w1 = *(const float4*)&Ws[kk * 132 + tx * 8 + 4];
            #pragma unroll
            for (int i = 0; i < 4; ++i) {
                float a = As[(ty * 4 + i) * 33 + kk];
                acc[i][0] += a * w0.x; acc[i][1] += a * w0.y;
                acc[i][2] += a * w0.z; acc[i][3] += a * w0.w;
                acc[i][4] += a * w1.x; acc[i][5] += a * w1.y;
                acc[i][6] += a * w1.z; acc[i][7] += a * w1.w;
            }
        }
    }
    #pragma unroll
    for (int i = 0; i < 4; ++i) {
        int bg = e8 * 256 + b0 + ty * 4 + i;     // global batch
        #pragma unroll
        for (int q = 0; q < 8; ++q) {
            int col = chunk * 128 + tx * 8 + q;
            if (col < size) {
                float o = acc[i][q] + b2[col];
                vecs[(size_t)bg * TOTV + off + col] = ftn[off + col] + 0.1f * o;
            }
        }
    }
}

// ------------------------------ K4a: build Psi -----------------------------
__device__ __forceinline__ float* build_half(const float* __restrict__ vb,
        const int* __restrict__ xb, int side, int upper,
        float* cur, float* fre, float* ts0, float* ts1, float* ts2, int tid) {
    if (tid == 0) cur[0] = 1.0f;
    __syncthreads();
    int bd = 1, lgbd = 0;
    for (int t = 0; t < 3; ++t) {
        int xd = t ? 4 : 1, lgxd = t ? 2 : 0;
        int j = side ? (5 - t) : t;
        int rows[3];
        rows[0] = upper ? 0 : 5; rows[1] = upper ? 1 : 4; rows[2] = upper ? 2 : 3;
        for (int role = 0; role < 3; ++role) {
            int i = rows[role];
            int dd = (i < 5) ? 4 : 1, dl = (j > 0) ? 4 : 1, dr = (j < 5) ? 4 : 1;
            int su = dd * dl * dr * 2, sd = dl * dr * 2, sl = dr * 2, sr = 2;
            int xstr = side ? sr : sl, ystr = side ? sl : sr;
            int base = c_offs[i * 6 + j] + xb[i * 6 + j];
            if (role == 0) {
                int astr = upper ? sd : su;
                int n = 4 * xd * 4;
                for (int idx = tid; idx < n; idx += 256) {
                    int y = idx & 3, xx = (idx >> 2) & (xd - 1), a = idx >> (2 + lgxd);
                    ts0[idx] = vb[base + a * astr + xx * xstr + y * ystr];
                }
            } else if (role == 1) {
                int astr = upper ? su : sd, cstr = upper ? sd : su;
                int n = 16 * xd * 4;
                for (int idx = tid; idx < n; idx += 256) {
                    int y = idx & 3, xx = (idx >> 2) & (xd - 1);
                    int c = (idx >> (2 + lgxd)) & 3, a = idx >> (4 + lgxd);
                    ts1[idx] = vb[base + a * astr + c * cstr + xx * xstr + y * ystr];
                }
            } else {
                int cstr = upper ? su : sd, bstr = upper ? sd : su;
                int n = 16 * xd * 4;
                for (int idx = tid; idx < n; idx += 256) {
                    int y = idx & 3, xx = (idx >> 2) & (xd - 1);
                    int bb = (idx >> (2 + lgxd)) & 3, c = idx >> (4 + lgxd);
                    ts2[idx] = vb[base + c * cstr + bb * bstr + xx * xstr + y * ystr];
                }
            }
        }
        __syncthreads();
        int n1 = 16 * xd * xd * bd;
        for (int idx = tid; idx < n1; idx += 256) {
            int bt = idx & (bd - 1);
            int r = idx >> lgbd;
            int x2 = r & (xd - 1); r >>= lgxd;
            int x1 = r & (xd - 1); r >>= lgxd;
            int a = r & 3, y0 = r >> 2;
            float s2 = 0.f;
            for (int x0 = 0; x0 < xd; ++x0)
                s2 += cur[(((((x0 << lgxd) | x1) << lgxd) | x2) << lgbd) | bt]
                    * ts0[(((a << lgxd) | x0) << 2) | y0];
            fre[idx] = s2;
        }
        __syncthreads();
        int n2 = 64 * xd * bd;
        for (int idx = tid; idx < n2; idx += 256) {
            int bt = idx & (bd - 1);
            int r = idx >> lgbd;
            int x2 = r & (xd - 1); r >>= lgxd;
            int c = r & 3, y1 = (r >> 2) & 3, y0 = r >> 4;
            float s2 = 0.f;
            for (int a = 0; a < 4; ++a)
                for (int x1 = 0; x1 < xd; ++x1)
                    s2 += fre[((((((((y0 << 2) | a) << lgxd) | x1) << lgxd) | x2)) << lgbd) | bt]
                        * ts1[((((a * 4 + c) << lgxd) | x1) << 2) | y1];
            cur[idx] = s2;
        }
        __syncthreads();
        int n3 = 256 * bd;
        for (int idx = tid; idx < n3; idx += 256) {
            int bn = idx & (4 * bd - 1);
            int bt = bn >> 2, bb = bn & 3;
            int r = idx >> (lgbd + 2);
            int y2 = r & 3, y1 = (r >> 2) & 3, y0 = r >> 4;
            float s2 = 0.f;
            for (int c = 0; c < 4; ++c)
                for (int x2 = 0; x2 < xd; ++x2)
                    s2 += cur[((((((y0 << 2) | y1) << 2 | c) << lgxd) | x2) << lgbd) | bt]
                        * ts2[((((c * 4 + bb) << lgxd) | x2) << 2) | y2];
            fre[idx] = s2;
        }
        __syncthreads();
        float* tmp = cur; cur = fre; fre = tmp;
        bd <<= 2; lgbd += 2;
    }
    return cur;
}

__global__ __launch_bounds__(256) void k_build(const float* __restrict__ vecs,
        const int* __restrict__ x, float* __restrict__ psi) {
    __shared__ float X1[4096], X2[4096], X3[4096];
    __shared__ float ts0[64], ts1[256], ts2[256];
    int m = blockIdx.x;
    int b = m >> 1, side = m & 1;
    int tid = threadIdx.x;
    const float* vb = vecs + (size_t)b * TOTV;
    const int* xb = x + b * NS;
    float* A  = build_half(vb, xb, side, 1, X1, X2, ts0, ts1, ts2, tid);
    float* Bt = build_half(vb, xb, side, 0, X1, X3, ts0, ts1, ts2, tid);
    float* po = psi + (size_t)m * 4096;
    for (int idx = tid; idx < 4096; idx += 256) {
        int u = idx >> 6, l = idx & 63;
        const float4* a4 = (const float4*)(A + u * 64);
        const float4* b4 = (const float4*)(Bt + l * 64);
        float s2 = 0.f;
        #pragma unroll
        for (int q = 0; q < 16; ++q) {
            float4 av = a4[q], bv = b4[q];
            s2 += av.x * bv.x + av.y * bv.y + av.z * bv.z + av.w * bv.w;
        }
        po[idx] = s2;
    }
}

// ------------------------------ K4b: Jacobi SVD ----------------------------
// 4 waves per 256-thread block, each wave owns one 64x64 matrix. Lane j
// holds column j of W in 4 ext_vector(16) values (constant-indexed after
// unroll -> VGPR-resident). launch_bounds(256,2): VGPR cap 256 so the ~80
// live floats stay in registers (R7's (256,4) capped at 64 -> 3.4GB spill).
// Epilogue: Q = top-16 normalized cols, T = Q^T Psi via per-wave LDS slab.
__global__ __launch_bounds__(256, 2) void k_svd(const float* __restrict__ psi,
                                                float* __restrict__ wv) {
    __shared__ __align__(16) float qlds[4][64 * 20];   // per-wave Q slab
    int wid = threadIdx.x >> 6, lane = threadIdx.x & 63;
    int m = blockIdx.x * 4 + wid;
    const float* P = psi + (size_t)m * 4096;
    f16v w0, w1, w2, w3;
    #pragma unroll
    for (int r = 0; r < 16; ++r) w0[r] = P[r * 64 + lane];
    #pragma unroll
    for (int r = 0; r < 16; ++r) w1[r] = P[(r + 16) * 64 + lane];
    #pragma unroll
    for (int r = 0; r < 16; ++r) w2[r] = P[(r + 32) * 64 + lane];
    #pragma unroll
    for (int r = 0; r < 16; ++r) w3[r] = P[(r + 48) * 64 + lane];

    float n2 = 0.f;
    for (int sweep = 0; sweep < 10; ++sweep) {
        n2 = 0.f;                               // exact refresh per sweep
        #pragma unroll
        for (int r = 0; r < 16; ++r)
            n2 += w0[r] * w0[r] + w1[r] * w1[r] + w2[r] * w2[r] + w3[r] * w3[r];
        bool any = false;
        for (int mm = 1; mm < 64; ++mm) {
            int partner = lane ^ mm;
            f16v p0, p1, p2, p3;
            #pragma unroll
            for (int r = 0; r < 16; ++r) p0[r] = __shfl(w0[r], partner);
            #pragma unroll
            for (int r = 0; r < 16; ++r) p1[r] = __shfl(w1[r], partner);
            #pragma unroll
            for (int r = 0; r < 16; ++r) p2[r] = __shfl(w2[r], partner);
            #pragma unroll
            for (int r = 0; r < 16; ++r) p3[r] = __shfl(w3[r], partner);
            float gam = 0.f;
            #pragma unroll
            for (int r = 0; r < 16; ++r)
                gam += w0[r] * p0[r] + w1[r] * p1[r] + w2[r] * p2[r] + w3[r] * p3[r];
            float beta2 = __shfl(n2, partner);
            bool rot = fabsf(gam) > 1e-5f * sqrtf(fmaxf(n2 * beta2, 0.f));
            unsigned long long bal = __ballot(rot);
            if (bal == 0ull) continue;
            any = true;
            float c = 1.f, s = 0.f;
            if (rot) {
                float zeta = (n2 - beta2) / (2.f * gam);
                float sgn = (zeta > 0.f) ? 1.f :
                            ((zeta < 0.f) ? -1.f : ((lane < partner) ? 1.f : -1.f));
                float tt = sgn / (fabsf(zeta) + sqrtf(1.f + zeta * zeta));
                c = 1.f / sqrtf(1.f + tt * tt);
                s = c * tt;
            }
            #pragma unroll
            for (int r = 0; r < 16; ++r) {
                w0[r] = c * w0[r] + s * p0[r];
                w1[r] = c * w1[r] + s * p1[r];
                w2[r] = c * w2[r] + s * p2[r];
                w3[r] = c * w3[r] + s * p3[r];
            }
            n2 = c * c * n2 + s * s * beta2 + 2.f * c * s * gam;
        }
        if (!any) break;
    }
    // exact norms -> rank by descending norm (index tie-break)
    float n2e = 0.f;
    #pragma unroll
    for (int r = 0; r < 16; ++r)
        n2e += w0[r] * w0[r] + w1[r] * w1[r] + w2[r] * w2[r] + w3[r] * w3[r];
    int rank = 0;
    for (int j = 0; j < 64; ++j) {
        float nj = __shfl(n2e, j);
        if (nj > n2e || (nj == n2e && j < lane)) ++rank;
    }
    float inv = (n2e > 1e-30f) ? 1.f / sqrtf(n2e) : 0.f;
    // stage Q (top-16 normalized columns) into this wave's LDS slab
    if (rank < 16) {
        #pragma unroll
        for (int r = 0; r < 16; ++r) {
            qlds[wid][r * 20 + rank]        = w0[r] * inv;
            qlds[wid][(r + 16) * 20 + rank] = w1[r] * inv;
            qlds[wid][(r + 32) * 20 + rank] = w2[r] * inv;
            qlds[wid][(r + 48) * 20 + rank] = w3[r] * inv;
        }
    }
    __syncthreads();
    float* o = wv + (size_t)m * 2048;
    #pragma unroll
    for (int k = 0; k < 16; ++k) o[k * 64 + lane] = qlds[wid][lane * 20 + k];
    // T = Q^T Psi : lane computes T[0..15][lane], re-reading Psi from L2
    f16v t;
    #pragma unroll
    for (int k = 0; k < 16; ++k) t[k] = 0.f;
    for (int r = 0; r < 64; ++r) {
        float pr = P[r * 64 + lane];
        const float4* q4 = (const float4*)&qlds[wid][r * 20];
        float4 a = q4[0], b = q4[1], cc = q4[2], d = q4[3];
        t[0]  += a.x  * pr; t[1]  += a.y  * pr; t[2]  += a.z  * pr; t[3]  += a.w  * pr;
        t[4]  += b.x  * pr; t[5]  += b.y  * pr; t[6]  += b.z  * pr; t[7]  += b.w  * pr;
        t[8]  += cc.x * pr; t[9]  += cc.y * pr; t[10] += cc.z * pr; t[11] += cc.w * pr;
        t[12] += d.x  * pr; t[13] += d.y  * pr; t[14] += d.z  * pr; t[15] += d.w  * pr;
    }
    #pragma unroll
    for (int k = 0; k < 16; ++k) o[1024 + k * 64 + lane] = t[k];
}

// ------------------------------ K4c: amplitude -----------------------------
__global__ __launch_bounds__(256) void k_amp(const float* __restrict__ wv,
                                             float* __restrict__ out) {
    __shared__ float s[4096];
    __shared__ float part[4];
    int b = blockIdx.x, tid = threadIdx.x;
    const float* src = wv + (size_t)b * 4096;
    for (int i = tid; i < 4096; i += 256) s[i] = src[i];
    __syncthreads();
    int k = tid >> 4, mm = tid & 15;
    const float* WL = s;
    const float* VL = s + 1024;
    const float* WR = s + 2048;
    const float* VR = s + 3072;
    float du = 0.f, dv = 0.f;
    for (int r = 0; r < 64; ++r) {
        du += WL[k * 64 + r] * WR[mm * 64 + r];
        dv += VL[k * 64 + r] * VR[mm * 64 + r];
    }
    float p = du * dv;
    for (int off = 32; off > 0; off >>= 1) p += __shfl_down(p, off);
    if ((tid & 63) == 0) part[tid >> 6] = p;
    __syncthreads();
    if (tid == 0) out[b] = part[0] + part[1] + part[2] + part[3];
}

// ------------------------------ launch -------------------------------------
extern "C" void kernel_launch(void* const* d_in, const int* in_sizes, int n_in,
                              void* d_out, int out_size, void* d_ws, size_t ws_size,
                              hipStream_t stream) {
    const int*   x    = (const int*)d_in[0];
    const float* ftn  = (const float*)d_in[1];
    const float* emb  = (const float*)d_in[2];
    const float* pos  = (const float*)d_in[3];
    const float* Wqkv = (const float*)d_in[4];
    const float* bqkv = (const float*)d_in[5];
    const float* Wo   = (const float*)d_in[6];
    const float* bo   = (const float*)d_in[7];
    const float* W1   = (const float*)d_in[8];
    const float* b1   = (const float*)d_in[9];
    const float* W2   = (const float*)d_in[10];
    const float* b2   = (const float*)d_in[11];
    float* out = (float*)d_out;
    float* ws  = (float*)d_ws;

    // layout (floats), total 46.4M = 186 MB:
    //   [0, 16777216)           psi; h at [0, 9437184), Hm_e at [9437184,..)
    //   [16777216, 38010880)    vecs (2048*10368)
    //   [38010880, 46399488)    wv
    //   qkv (28.3M) transiently occupies [16777216, 45088768) -- dead before
    //   gemm2 writes vecs and before svd writes wv.
    float* h    = ws;
    float* Hm_e = ws + 9437184;          // 2304 tokens * 512
    float* psi  = ws;
    float* vecs = ws + 16777216;
    float* qkv  = ws + 16777216;
    float* wv   = ws + 16777216 + 21233664;

    hipLaunchKernelGGL(k_embed, dim3((BSZ * NS * EMB + 255) / 256), dim3(256), 0, stream,
                       x, emb, pos, h);
    hipLaunchKernelGGL(k_qkv, dim3(3, 1152), dim3(256), 0, stream,
                       h, Wqkv, bqkv, qkv);
    hipLaunchKernelGGL(k_attnc, dim3(BSZ * NHEAD / 4), dim3(256), 0, stream, qkv);
    hipLaunchKernelGGL(k_oproj, dim3(1152), dim3(256), 0, stream,
                       qkv, Wo, bo, h);
    for (int e8 = 0; e8 < 8; ++e8) {
        const float* h_e = h + (size_t)e8 * 9216 * EMB;
        hipLaunchKernelGGL(k_gemm1, dim3(4, 144), dim3(256), 0, stream,
                           h_e, W1, b1, Hm_e);
        hipLaunchKernelGGL(k_gemm2, dim3(84, 4), dim3(256), 0, stream,
                           Hm_e, W2, b2, ftn, vecs, e8);
    }
    hipLaunchKernelGGL(k_build, dim3(2 * BSZ), dim3(256), 0, stream, vecs, x, psi);
    hipLaunchKernelGGL(k_svd, dim3(BSZ / 2), dim3(256), 0, stream, psi, wv);
    hipLaunchKernelGGL(k_amp, dim3(BSZ), dim3(256), 0, stream, wv, out);
}

// Round 9
// 3787.048 us; speedup vs baseline: 1.4369x; 1.0026x over previous
//
#include <hip/hip_runtime.h>
#include <math.h>

// ---------------------------------------------------------------------------
// Transformer_fPEPS: transformer (f32 VALU GEMMs) + PEPS amplitude.
//
// Math reduction (validated R1, absmax 3.8e-6): every SVD in the reference
// _compress is lossless gauge EXCEPT the bond-(2,3) truncation (64 -> chi=16)
// on each side. amp(b) = < rank16(Psi_L), rank16(Psi_R) >_F.
//
// R9: k_svd is VALU-throughput-bound (R8: occupancy lever exhausted, 55%
// VALUBusy on ~290 scalar ops/batch incl. a serial 64-FMA gam chain).
// Rewrite inner math as whole-ext_vector expressions -> v_pk_fma_f32
// (2xFP32/instr) + depth-4 tree reduction for gam. DS traffic unchanged.
// ---------------------------------------------------------------------------

#define BSZ   2048
#define NS    36
#define EMB   128
#define NHEAD 8
#define DH    16
#define HIDD  512
#define TOTV  10368

typedef float f16v __attribute__((ext_vector_type(16)));

__device__ __forceinline__ float hsum16(f16v v) {
    float a = (v[0] + v[1]) + (v[2] + v[3]);
    float b = (v[4] + v[5]) + (v[6] + v[7]);
    float c = (v[8] + v[9]) + (v[10] + v[11]);
    float d = (v[12] + v[13]) + (v[14] + v[15]);
    return (a + b) + (c + d);
}

__constant__ int c_offs[37] = {
    0,32,160,288,416,544,576,
    704,1216,1728,2240,2752,2880,
    3008,3520,4032,4544,5056,5184,
    5312,5824,6336,6848,7360,7488,
    7616,8128,8640,9152,9664,9792,
    9824,9952,10080,10208,10336,10368};

// (site, col-chunk) pairs for trimmed GEMM2: 84 pairs
__constant__ int c_ps[84] = {
    0,1,2,3,4,5,
    6,7,7,7,7,8,8,8,8,9,9,9,9,10,10,10,10,11,
    12,13,13,13,13,14,14,14,14,15,15,15,15,16,16,16,16,17,
    18,19,19,19,19,20,20,20,20,21,21,21,21,22,22,22,22,23,
    24,25,25,25,25,26,26,26,26,27,27,27,27,28,28,28,28,29,
    30,31,32,33,34,35};
__constant__ int c_pc[84] = {
    0,0,0,0,0,0,
    0,0,1,2,3,0,1,2,3,0,1,2,3,0,1,2,3,0,
    0,0,1,2,3,0,1,2,3,0,1,2,3,0,1,2,3,0,
    0,0,1,2,3,0,1,2,3,0,1,2,3,0,1,2,3,0,
    0,0,1,2,3,0,1,2,3,0,1,2,3,0,1,2,3,0,
    0,0,0,0,0,0};

// ------------------------------ K1: embed ----------------------------------
__global__ __launch_bounds__(256) void k_embed(const int* __restrict__ x,
        const float* __restrict__ emb, const float* __restrict__ pos,
        float* __restrict__ h) {
    int idx = blockIdx.x * 256 + threadIdx.x;
    if (idx >= BSZ * NS * EMB) return;
    int e = idx & (EMB - 1);
    int g = idx >> 7;            // token
    int s = g % NS;
    h[idx] = emb[x[g] * EMB + e] + pos[s * EMB + e];
}

// ------------------------------ K2a: QKV GEMM ------------------------------
// [73728 x 128] @ [128 x 384] + bias. 64 tokens x 128 cols per block.
__global__ __launch_bounds__(256) void k_qkv(const float* __restrict__ h,
        const float* __restrict__ Wqkv, const float* __restrict__ bqkv,
        float* __restrict__ qkv) {
    __shared__ float As[64 * 132];
    __shared__ float Ws[32 * 132];
    int tid = threadIdx.x;
    int chunk = blockIdx.x;          // 0..2 -> output cols chunk*128..+127
    int tok0 = blockIdx.y * 64;
    int tx = tid & 15, ty = tid >> 4;
    for (int idx = tid; idx < 64 * 128; idx += 256) {
        int t = idx >> 7, k = idx & 127;
        As[t * 132 + k] = h[(size_t)(tok0 + t) * EMB + k];
    }
    float acc[4][8];
    #pragma unroll
    for (int i = 0; i < 4; ++i)
        #pragma unroll
        for (int q = 0; q < 8; ++q) acc[i][q] = 0.f;
    for (int ks = 0; ks < 4; ++ks) {
        __syncthreads();
        for (int idx = tid; idx < 32 * 128; idx += 256) {
            int kk = idx >> 7, c = idx & 127;
            Ws[kk * 132 + c] = Wqkv[(size_t)(ks * 32 + kk) * 384 + chunk * 128 + c];
        }
        __syncthreads();
        #pragma unroll 4
        for (int kk = 0; kk < 32; ++kk) {
            float4 w0 = *(const float4*)&Ws[kk * 132 + tx * 8];
            float4 w1 = *(const float4*)&Ws[kk * 132 + tx * 8 + 4];
            #pragma unroll
            for (int i = 0; i < 4; ++i) {
                float a = As[(ty * 4 + i) * 132 + ks * 32 + kk];
                acc[i][0] += a * w0.x; acc[i][1] += a * w0.y;
                acc[i][2] += a * w0.z; acc[i][3] += a * w0.w;
                acc[i][4] += a * w1.x; acc[i][5] += a * w1.y;
                acc[i][6] += a * w1.z; acc[i][7] += a * w1.w;
            }
        }
    }
    #pragma unroll
    for (int i = 0; i < 4; ++i) {
        size_t base = (size_t)(tok0 + ty * 4 + i) * 384 + chunk * 128 + tx * 8;
        #pragma unroll
        for (int q = 0; q < 8; ++q)
            qkv[base + q] = acc[i][q] + bqkv[chunk * 128 + tx * 8 + q];
    }
}

// ------------------------------ K2b: attention core ------------------------
// One wave per (batch, head). q/k/v staged in padded LDS (stride 17),
// scores in stride-37 LDS, softmax per row, o overwrites the dead q-slot.
__global__ __launch_bounds__(256) void k_attnc(float* __restrict__ qkv) {
    __shared__ float qs[4][NS * 17];
    __shared__ float ks_[4][NS * 17];
    __shared__ float vs[4][NS * 17];
    __shared__ float S[4][NS * 37];
    int wid = threadIdx.x >> 6, lane = threadIdx.x & 63;
    int m = blockIdx.x * 4 + wid;
    int b = m >> 3, hd = m & 7;
    float* Q = qkv + (size_t)b * NS * 384 + hd * DH;   // row stride 384
    for (int idx = lane; idx < NS * DH; idx += 64) {
        int t = idx >> 4, d = idx & 15;
        qs[wid][t * 17 + d]  = Q[t * 384 + d];
        ks_[wid][t * 17 + d] = Q[t * 384 + 128 + d];
        vs[wid][t * 17 + d]  = Q[t * 384 + 256 + d];
    }
    __syncthreads();
    for (int idx = lane; idx < NS * NS; idx += 64) {
        int qp = idx / NS, kp = idx - qp * NS;
        float acc = 0.f;
        #pragma unroll
        for (int d = 0; d < DH; ++d)
            acc += qs[wid][qp * 17 + d] * ks_[wid][kp * 17 + d];
        S[wid][qp * 37 + kp] = acc * 0.25f;     // 1/sqrt(16)
    }
    __syncthreads();
    if (lane < NS) {
        float mx = -1e30f;
        for (int j = 0; j < NS; ++j) mx = fmaxf(mx, S[wid][lane * 37 + j]);
        float z = 0.f;
        for (int j = 0; j < NS; ++j) {
            float e = expf(S[wid][lane * 37 + j] - mx);
            S[wid][lane * 37 + j] = e; z += e;
        }
        float inv = 1.f / z;
        for (int j = 0; j < NS; ++j) S[wid][lane * 37 + j] *= inv;
    }
    __syncthreads();
    for (int idx = lane; idx < NS * DH; idx += 64) {
        int qp = idx >> 4, d = idx & 15;
        float acc = 0.f;
        for (int kp = 0; kp < NS; ++kp)
            acc += S[wid][qp * 37 + kp] * vs[wid][kp * 17 + d];
        Q[qp * 384 + d] = acc;                  // o into dead q-slot
    }
}

// ------------------------------ K2c: out-proj + residual -------------------
// h += o @ Wo + bo, o rows at qkv[tok*384 + 0..127].
__global__ __launch_bounds__(256) void k_oproj(const float* __restrict__ qkv,
        const float* __restrict__ Wo, const float* __restrict__ bo,
        float* __restrict__ h) {
    __shared__ float As[64 * 132];
    __shared__ float Ws[32 * 132];
    int tid = threadIdx.x;
    int tok0 = blockIdx.x * 64;
    int tx = tid & 15, ty = tid >> 4;
    for (int idx = tid; idx < 64 * 128; idx += 256) {
        int t = idx >> 7, k = idx & 127;
        As[t * 132 + k] = qkv[(size_t)(tok0 + t) * 384 + k];
    }
    float acc[4][8];
    #pragma unroll
    for (int i = 0; i < 4; ++i)
        #pragma unroll
        for (int q = 0; q < 8; ++q) acc[i][q] = 0.f;
    for (int ks = 0; ks < 4; ++ks) {
        __syncthreads();
        for (int idx = tid; idx < 32 * 128; idx += 256) {
            int kk = idx >> 7, c = idx & 127;
            Ws[kk * 132 + c] = Wo[(size_t)(ks * 32 + kk) * EMB + c];
        }
        __syncthreads();
        #pragma unroll 4
        for (int kk = 0; kk < 32; ++kk) {
            float4 w0 = *(const float4*)&Ws[kk * 132 + tx * 8];
            float4 w1 = *(const float4*)&Ws[kk * 132 + tx * 8 + 4];
            #pragma unroll
            for (int i = 0; i < 4; ++i) {
                float a = As[(ty * 4 + i) * 132 + ks * 32 + kk];
                acc[i][0] += a * w0.x; acc[i][1] += a * w0.y;
                acc[i][2] += a * w0.z; acc[i][3] += a * w0.w;
                acc[i][4] += a * w1.x; acc[i][5] += a * w1.y;
                acc[i][6] += a * w1.z; acc[i][7] += a * w1.w;
            }
        }
    }
    #pragma unroll
    for (int i = 0; i < 4; ++i) {
        size_t base = (size_t)(tok0 + ty * 4 + i) * EMB + tx * 8;
        #pragma unroll
        for (int q = 0; q < 8; ++q)
            h[base + q] = h[base + q] + acc[i][q] + bo[tx * 8 + q];
    }
}

// ------------------------------ K3a: GEMM1 (h@W1, gelu) --------------------
__global__ __launch_bounds__(256) void k_gemm1(const float* __restrict__ h,
        const float* __restrict__ W1, const float* __restrict__ b1,
        float* __restrict__ Hm) {
    __shared__ float As[64 * 132];   // [token][k], pad 132
    __shared__ float Ws[32 * 132];   // [kk][col], pad 132
    int tid = threadIdx.x;
    int chunk = blockIdx.x;          // 0..3 -> output cols chunk*128..+127
    int tok0 = blockIdx.y * 64;      // token tile (local to eighth)
    int tx = tid & 15, ty = tid >> 4;
    for (int idx = tid; idx < 64 * 128; idx += 256) {
        int t = idx >> 7, k = idx & 127;
        As[t * 132 + k] = h[(size_t)(tok0 + t) * EMB + k];
    }
    float acc[4][8];
    #pragma unroll
    for (int i = 0; i < 4; ++i)
        #pragma unroll
        for (int q = 0; q < 8; ++q) acc[i][q] = 0.f;
    for (int ks = 0; ks < 4; ++ks) {
        __syncthreads();
        for (int idx = tid; idx < 32 * 128; idx += 256) {
            int kk = idx >> 7, c = idx & 127;
            Ws[kk * 132 + c] = W1[(size_t)(ks * 32 + kk) * HIDD + chunk * 128 + c];
        }
        __syncthreads();
        #pragma unroll 4
        for (int kk = 0; kk < 32; ++kk) {
            float4 w0 = *(const float4*)&Ws[kk * 132 + tx * 8];
            float4 w1 = *(const float4*)&Ws[kk * 132 + tx * 8 + 4];
            #pragma unroll
            for (int i = 0; i < 4; ++i) {
                float a = As[(ty * 4 + i) * 132 + ks * 32 + kk];
                acc[i][0] += a * w0.x; acc[i][1] += a * w0.y;
                acc[i][2] += a * w0.z; acc[i][3] += a * w0.w;
                acc[i][4] += a * w1.x; acc[i][5] += a * w1.y;
                acc[i][6] += a * w1.z; acc[i][7] += a * w1.w;
            }
        }
    }
    #pragma unroll
    for (int i = 0; i < 4; ++i) {
        size_t base = (size_t)(tok0 + ty * 4 + i) * HIDD + chunk * 128 + tx * 8;
        #pragma unroll
        for (int q = 0; q < 8; ++q) {
            float a = acc[i][q] + b1[chunk * 128 + tx * 8 + q];
            Hm[base + q] = 0.5f * a * (1.f + erff(a * 0.70710678118654752f));
        }
    }
}

// ------------------------------ K3b: GEMM2 (Hm@W2, backflow) ---------------
__global__ __launch_bounds__(256) void k_gemm2(const float* __restrict__ Hm,
        const float* __restrict__ W2, const float* __restrict__ b2,
        const float* __restrict__ ftn, float* __restrict__ vecs, int e8) {
    __shared__ float As[64 * 33];    // [batch][kk], pad 33
    __shared__ float Ws[32 * 132];   // [kk][col], pad 132
    int tid = threadIdx.x;
    int pair = blockIdx.x;
    int s = c_ps[pair], chunk = c_pc[pair];
    int b0 = blockIdx.y * 64;        // batch tile (local to eighth)
    int off = c_offs[s], size = c_offs[s + 1] - off;
    int tx = tid & 15, ty = tid >> 4;
    float acc[4][8];
    #pragma unroll
    for (int i = 0; i < 4; ++i)
        #pragma unroll
        for (int q = 0; q < 8; ++q) acc[i][q] = 0.f;
    for (int ks = 0; ks < 16; ++ks) {
        __syncthreads();
        for (int idx = tid; idx < 64 * 32; idx += 256) {
            int t = idx >> 5, kk = idx & 31;
            As[t * 33 + kk] = Hm[(size_t)((b0 + t) * NS + s) * HIDD + ks * 32 + kk];
        }
        for (int idx = tid; idx < 32 * 128; idx += 256) {
            int kk = idx >> 7, c = idx & 127;
            Ws[kk * 132 + c] = W2[(size_t)(ks * 32 + kk) * HIDD + chunk * 128 + c];
        }
        __syncthreads();
        #pragma unroll 4
        for (int kk = 0; kk < 32; ++kk) {
            float4 w0 = *(const float4*)&Ws[kk * 132 + tx * 8];
            float4 w1 = *(const float4*)&Ws[kk * 132 + tx * 8 + 4];
            #pragma unroll
            for (int i = 0; i < 4; ++i) {
                float a = As[(ty * 4 + i) * 33 + kk];
                acc[i][0] += a * w0.x; acc[i][1] += a * w0.y;
                acc[i][2] += a * w0.z; acc[i][3] += a * w0.w;
                acc[i][4] += a * w1.x; acc[i][5] += a * w1.y;
                acc[i][6] += a * w1.z; acc[i][7] += a * w1.w;
            }
        }
    }
    #pragma unroll
    for (int i = 0; i < 4; ++i) {
        int bg = e8 * 256 + b0 + ty * 4 + i;     // global batch
        #pragma unroll
        for (int q = 0; q < 8; ++q) {
            int col = chunk * 128 + tx * 8 + q;
            if (col < size) {
                float o = acc[i][q] + b2[col];
                vecs[(size_t)bg * TOTV + off + col] = ftn[off + col] + 0.1f * o;
            }
        }
    }
}

// ------------------------------ K4a: build Psi -----------------------------
__device__ __forceinline__ float* build_half(const float* __restrict__ vb,
        const int* __restrict__ xb, int side, int upper,
        float* cur, float* fre, float* ts0, float* ts1, float* ts2, int tid) {
    if (tid == 0) cur[0] = 1.0f;
    __syncthreads();
    int bd = 1, lgbd = 0;
    for (int t = 0; t < 3; ++t) {
        int xd = t ? 4 : 1, lgxd = t ? 2 : 0;
        int j = side ? (5 - t) : t;
        int rows[3];
        rows[0] = upper ? 0 : 5; rows[1] = upper ? 1 : 4; rows[2] = upper ? 2 : 3;
        for (int role = 0; role < 3; ++role) {
            int i = rows[role];
            int dd = (i < 5) ? 4 : 1, dl = (j > 0) ? 4 : 1, dr = (j < 5) ? 4 : 1;
            int su = dd * dl * dr * 2, sd = dl * dr * 2, sl = dr * 2, sr = 2;
            int xstr = side ? sr : sl, ystr = side ? sl : sr;
            int base = c_offs[i * 6 + j] + xb[i * 6 + j];
            if (role == 0) {
                int astr = upper ? sd : su;
                int n = 4 * xd * 4;
                for (int idx = tid; idx < n; idx += 256) {
                    int y = idx & 3, xx = (idx >> 2) & (xd - 1), a = idx >> (2 + lgxd);
                    ts0[idx] = vb[base + a * astr + xx * xstr + y * ystr];
                }
            } else if (role == 1) {
                int astr = upper ? su : sd, cstr = upper ? sd : su;
                int n = 16 * xd * 4;
                for (int idx = tid; idx < n; idx += 256) {
                    int y = idx & 3, xx = (idx >> 2) & (xd - 1);
                    int c = (idx >> (2 + lgxd)) & 3, a = idx >> (4 + lgxd);
                    ts1[idx] = vb[base + a * astr + c * cstr + xx * xstr + y * ystr];
                }
            } else {
                int cstr = upper ? su : sd, bstr = upper ? sd : su;
                int n = 16 * xd * 4;
                for (int idx = tid; idx < n; idx += 256) {
                    int y = idx & 3, xx = (idx >> 2) & (xd - 1);
                    int bb = (idx >> (2 + lgxd)) & 3, c = idx >> (4 + lgxd);
                    ts2[idx] = vb[base + c * cstr + bb * bstr + xx * xstr + y * ystr];
                }
            }
        }
        __syncthreads();
        int n1 = 16 * xd * xd * bd;
        for (int idx = tid; idx < n1; idx += 256) {
            int bt = idx & (bd - 1);
            int r = idx >> lgbd;
            int x2 = r & (xd - 1); r >>= lgxd;
            int x1 = r & (xd - 1); r >>= lgxd;
            int a = r & 3, y0 = r >> 2;
            float s2 = 0.f;
            for (int x0 = 0; x0 < xd; ++x0)
                s2 += cur[(((((x0 << lgxd) | x1) << lgxd) | x2) << lgbd) | bt]
                    * ts0[(((a << lgxd) | x0) << 2) | y0];
            fre[idx] = s2;
        }
        __syncthreads();
        int n2 = 64 * xd * bd;
        for (int idx = tid; idx < n2; idx += 256) {
            int bt = idx & (bd - 1);
            int r = idx >> lgbd;
            int x2 = r & (xd - 1); r >>= lgxd;
            int c = r & 3, y1 = (r >> 2) & 3, y0 = r >> 4;
            float s2 = 0.f;
            for (int a = 0; a < 4; ++a)
                for (int x1 = 0; x1 < xd; ++x1)
                    s2 += fre[((((((((y0 << 2) | a) << lgxd) | x1) << lgxd) | x2)) << lgbd) | bt]
                        * ts1[((((a * 4 + c) << lgxd) | x1) << 2) | y1];
            cur[idx] = s2;
        }
        __syncthreads();
        int n3 = 256 * bd;
        for (int idx = tid; idx < n3; idx += 256) {
            int bn = idx & (4 * bd - 1);
            int bt = bn >> 2, bb = bn & 3;
            int r = idx >> (lgbd + 2);
            int y2 = r & 3, y1 = (r >> 2) & 3, y0 = r >> 4;
            float s2 = 0.f;
            for (int c = 0; c < 4; ++c)
                for (int x2 = 0; x2 < xd; ++x2)
                    s2 += cur[((((((y0 << 2) | y1) << 2 | c) << lgxd) | x2) << lgbd) | bt]
                        * ts2[((((c * 4 + bb) << lgxd) | x2) << 2) | y2];
            fre[idx] = s2;
        }
        __syncthreads();
        float* tmp = cur; cur = fre; fre = tmp;
        bd <<= 2; lgbd += 2;
    }
    return cur;
}

__global__ __launch_bounds__(256) void k_build(const float* __restrict__ vecs,
        const int* __restrict__ x, float* __restrict__ psi) {
    __shared__ float X1[4096], X2[4096], X3[4096];
    __shared__ float ts0[64], ts1[256], ts2[256];
    int m = blockIdx.x;
    int b = m >> 1, side = m & 1;
    int tid = threadIdx.x;
    const float* vb = vecs + (size_t)b * TOTV;
    const int* xb = x + b * NS;
    float* A  = build_half(vb, xb, side, 1, X1, X2, ts0, ts1, ts2, tid);
    float* Bt = build_half(vb, xb, side, 0, X1, X3, ts0, ts1, ts2, tid);
    float* po = psi + (size_t)m * 4096;
    for (int idx = tid; idx < 4096; idx += 256) {
        int u = idx >> 6, l = idx & 63;
        const float4* a4 = (const float4*)(A + u * 64);
        const float4* b4 = (const float4*)(Bt + l * 64);
        float s2 = 0.f;
        #pragma unroll
        for (int q = 0; q < 16; ++q) {
            float4 av = a4[q], bv = b4[q];
            s2 += av.x * bv.x + av.y * bv.y + av.z * bv.z + av.w * bv.w;
        }
        po[idx] = s2;
    }
}

// ------------------------------ K4b: Jacobi SVD ----------------------------
// 4 waves per 256-thread block, each wave owns one 64x64 matrix. Lane j
// holds column j of W in 4 ext_vector(16) values. Whole-vector expressions
// for gam/update -> v_pk_fma_f32 packed fp32 + depth-4 tree reductions
// (replaces the serial 64-FMA gam chain). launch_bounds(256,2): no spill.
__global__ __launch_bounds__(256, 2) void k_svd(const float* __restrict__ psi,
                                                float* __restrict__ wv) {
    __shared__ __align__(16) float qlds[4][64 * 20];   // per-wave Q slab
    int wid = threadIdx.x >> 6, lane = threadIdx.x & 63;
    int m = blockIdx.x * 4 + wid;
    const float* P = psi + (size_t)m * 4096;
    f16v w0, w1, w2, w3;
    #pragma unroll
    for (int r = 0; r < 16; ++r) w0[r] = P[r * 64 + lane];
    #pragma unroll
    for (int r = 0; r < 16; ++r) w1[r] = P[(r + 16) * 64 + lane];
    #pragma unroll
    for (int r = 0; r < 16; ++r) w2[r] = P[(r + 32) * 64 + lane];
    #pragma unroll
    for (int r = 0; r < 16; ++r) w3[r] = P[(r + 48) * 64 + lane];

    for (int sweep = 0; sweep < 10; ++sweep) {
        f16v nv = w0 * w0 + w1 * w1 + w2 * w2 + w3 * w3;
        float n2 = hsum16(nv);                  // exact refresh per sweep
        bool any = false;
        for (int mm = 1; mm < 64; ++mm) {
            int partner = lane ^ mm;
            f16v p0, p1, p2, p3;
            #pragma unroll
            for (int r = 0; r < 16; ++r) p0[r] = __shfl(w0[r], partner);
            #pragma unroll
            for (int r = 0; r < 16; ++r) p1[r] = __shfl(w1[r], partner);
            #pragma unroll
            for (int r = 0; r < 16; ++r) p2[r] = __shfl(w2[r], partner);
            #pragma unroll
            for (int r = 0; r < 16; ++r) p3[r] = __shfl(w3[r], partner);
            f16v gv = w0 * p0 + w1 * p1 + w2 * p2 + w3 * p3;
            float gam = hsum16(gv);
            float beta2 = __shfl(n2, partner);
            bool rot = fabsf(gam) > 1e-5f * sqrtf(fmaxf(n2 * beta2, 0.f));
            unsigned long long bal = __ballot(rot);
            if (bal == 0ull) continue;
            any = true;
            float c = 1.f, s = 0.f;
            if (rot) {
                float zeta = (n2 - beta2) / (2.f * gam);
                float sgn = (zeta > 0.f) ? 1.f :
                            ((zeta < 0.f) ? -1.f : ((lane < partner) ? 1.f : -1.f));
                float tt = sgn / (fabsf(zeta) + sqrtf(1.f + zeta * zeta));
                c = 1.f / sqrtf(1.f + tt * tt);
                s = c * tt;
            }
            w0 = c * w0 + s * p0;
            w1 = c * w1 + s * p1;
            w2 = c * w2 + s * p2;
            w3 = c * w3 + s * p3;
            n2 = c * c * n2 + s * s * beta2 + 2.f * c * s * gam;
        }
        if (!any) break;
    }
    // exact norms -> rank by descending norm (index tie-break)
    f16v ne = w0 * w0 + w1 * w1 + w2 * w2 + w3 * w3;
    float n2e = hsum16(ne);
    int rank = 0;
    for (int j = 0; j < 64; ++j) {
        float nj = __shfl(n2e, j);
        if (nj > n2e || (nj == n2e && j < lane)) ++rank;
    }
    float inv = (n2e > 1e-30f) ? 1.f / sqrtf(n2e) : 0.f;
    // stage Q (top-16 normalized columns) into this wave's LDS slab
    if (rank < 16) {
        #pragma unroll
        for (int r = 0; r < 16; ++r) {
            qlds[wid][r * 20 + rank]        = w0[r] * inv;
            qlds[wid][(r + 16) * 20 + rank] = w1[r] * inv;
            qlds[wid][(r + 32) * 20 + rank] = w2[r] * inv;
            qlds[wid][(r + 48) * 20 + rank] = w3[r] * inv;
        }
    }
    __syncthreads();
    float* o = wv + (size_t)m * 2048;
    #pragma unroll
    for (int k = 0; k < 16; ++k) o[k * 64 + lane] = qlds[wid][lane * 20 + k];
    // T = Q^T Psi : lane computes T[0..15][lane], re-reading Psi from L2
    f16v t;
    #pragma unroll
    for (int k = 0; k < 16; ++k) t[k] = 0.f;
    for (int r = 0; r < 64; ++r) {
        float pr = P[r * 64 + lane];
        const float4* q4 = (const float4*)&qlds[wid][r * 20];
        float4 a = q4[0], b = q4[1], cc = q4[2], d = q4[3];
        t[0]  += a.x  * pr; t[1]  += a.y  * pr; t[2]  += a.z  * pr; t[3]  += a.w  * pr;
        t[4]  += b.x  * pr; t[5]  += b.y  * pr; t[6]  += b.z  * pr; t[7]  += b.w  * pr;
        t[8]  += cc.x * pr; t[9]  += cc.y * pr; t[10] += cc.z * pr; t[11] += cc.w * pr;
        t[12] += d.x  * pr; t[13] += d.y  * pr; t[14] += d.z  * pr; t[15] += d.w  * pr;
    }
    #pragma unroll
    for (int k = 0; k < 16; ++k) o[1024 + k * 64 + lane] = t[k];
}

// ------------------------------ K4c: amplitude -----------------------------
__global__ __launch_bounds__(256) void k_amp(const float* __restrict__ wv,
                                             float* __restrict__ out) {
    __shared__ float s[4096];
    __shared__ float part[4];
    int b = blockIdx.x, tid = threadIdx.x;
    const float* src = wv + (size_t)b * 4096;
    for (int i = tid; i < 4096; i += 256) s[i] = src[i];
    __syncthreads();
    int k = tid >> 4, mm = tid & 15;
    const float* WL = s;
    const float* VL = s + 1024;
    const float* WR = s + 2048;
    const float* VR = s + 3072;
    float du = 0.f, dv = 0.f;
    for (int r = 0; r < 64; ++r) {
        du += WL[k * 64 + r] * WR[mm * 64 + r];
        dv += VL[k * 64 + r] * VR[mm * 64 + r];
    }
    float p = du * dv;
    for (int off = 32; off > 0; off >>= 1) p += __shfl_down(p, off);
    if ((tid & 63) == 0) part[tid >> 6] = p;
    __syncthreads();
    if (tid == 0) out[b] = part[0] + part[1] + part[2] + part[3];
}

// ------------------------------ launch -------------------------------------
extern "C" void kernel_launch(void* const* d_in, const int* in_sizes, int n_in,
                              void* d_out, int out_size, void* d_ws, size_t ws_size,
                              hipStream_t stream) {
    const int*   x    = (const int*)d_in[0];
    const float* ftn  = (const float*)d_in[1];
    const float* emb  = (const float*)d_in[2];
    const float* pos  = (const float*)d_in[3];
    const float* Wqkv = (const float*)d_in[4];
    const float* bqkv = (const float*)d_in[5];
    const float* Wo   = (const float*)d_in[6];
    const float* bo   = (const float*)d_in[7];
    const float* W1   = (const float*)d_in[8];
    const float* b1   = (const float*)d_in[9];
    const float* W2   = (const float*)d_in[10];
    const float* b2   = (const float*)d_in[11];
    float* out = (float*)d_out;
    float* ws  = (float*)d_ws;

    // layout (floats), total 46.4M = 186 MB:
    //   [0, 16777216)           psi; h at [0, 9437184), Hm_e at [9437184,..)
    //   [16777216, 38010880)    vecs (2048*10368)
    //   [38010880, 46399488)    wv
    //   qkv (28.3M) transiently occupies [16777216, 45088768) -- dead before
    //   gemm2 writes vecs and before svd writes wv.
    float* h    = ws;
    float* Hm_e = ws + 9437184;          // 2304 tokens * 512
    float* psi  = ws;
    float* vecs = ws + 16777216;
    float* qkv  = ws + 16777216;
    float* wv   = ws + 16777216 + 21233664;

    hipLaunchKernelGGL(k_embed, dim3((BSZ * NS * EMB + 255) / 256), dim3(256), 0, stream,
                       x, emb, pos, h);
    hipLaunchKernelGGL(k_qkv, dim3(3, 1152), dim3(256), 0, stream,
                       h, Wqkv, bqkv, qkv);
    hipLaunchKernelGGL(k_attnc, dim3(BSZ * NHEAD / 4), dim3(256), 0, stream, qkv);
    hipLaunchKernelGGL(k_oproj, dim3(1152), dim3(256), 0, stream,
                       qkv, Wo, bo, h);
    for (int e8 = 0; e8 < 8; ++e8) {
        const float* h_e = h + (size_t)e8 * 9216 * EMB;
        hipLaunchKernelGGL(k_gemm1, dim3(4, 144), dim3(256), 0, stream,
                           h_e, W1, b1, Hm_e);
        hipLaunchKernelGGL(k_gemm2, dim3(84, 4), dim3(256), 0, stream,
                           Hm_e, W2, b2, ftn, vecs, e8);
    }
    hipLaunchKernelGGL(k_build, dim3(2 * BSZ), dim3(256), 0, stream, vecs, x, psi);
    hipLaunchKernelGGL(k_svd, dim3(BSZ / 2), dim3(256), 0, stream, psi, wv);
    hipLaunchKernelGGL(k_amp, dim3(BSZ), dim3(256), 0, stream, wv, out);
}

// Round 10
// 3763.526 us; speedup vs baseline: 1.4459x; 1.0063x over previous
//
#include <hip/hip_runtime.h>
#include <math.h>

// ---------------------------------------------------------------------------
// Transformer_fPEPS: transformer (f32 VALU GEMMs) + PEPS amplitude.
//
// Math reduction (validated R1, absmax 3.8e-6): every SVD in the reference
// _compress is lossless gauge EXCEPT the bond-(2,3) truncation (64 -> chi=16)
// on each side. amp(b) = < rank16(Psi_L), rank16(Psi_R) >_F.
//
// R10: k_svd latency-bound on shfl->gam->rotate chain, residency pinned ~9
// waves/CU in all prior configs (R5/R8/R9 all ~2.0ms). Probe: 2-wave
// 128-thread blocks, grid 2048 -> 8 blocks/CU -> up to 16 waves/CU.
// Sweep cap 10 -> 8 (18x accuracy margin) to trim the convergence tail.
// ---------------------------------------------------------------------------

#define BSZ   2048
#define NS    36
#define EMB   128
#define NHEAD 8
#define DH    16
#define HIDD  512
#define TOTV  10368

typedef float f16v __attribute__((ext_vector_type(16)));

__device__ __forceinline__ float hsum16(f16v v) {
    float a = (v[0] + v[1]) + (v[2] + v[3]);
    float b = (v[4] + v[5]) + (v[6] + v[7]);
    float c = (v[8] + v[9]) + (v[10] + v[11]);
    float d = (v[12] + v[13]) + (v[14] + v[15]);
    return (a + b) + (c + d);
}

__constant__ int c_offs[37] = {
    0,32,160,288,416,544,576,
    704,1216,1728,2240,2752,2880,
    3008,3520,4032,4544,5056,5184,
    5312,5824,6336,6848,7360,7488,
    7616,8128,8640,9152,9664,9792,
    9824,9952,10080,10208,10336,10368};

// (site, col-chunk) pairs for trimmed GEMM2: 84 pairs
__constant__ int c_ps[84] = {
    0,1,2,3,4,5,
    6,7,7,7,7,8,8,8,8,9,9,9,9,10,10,10,10,11,
    12,13,13,13,13,14,14,14,14,15,15,15,15,16,16,16,16,17,
    18,19,19,19,19,20,20,20,20,21,21,21,21,22,22,22,22,23,
    24,25,25,25,25,26,26,26,26,27,27,27,27,28,28,28,28,29,
    30,31,32,33,34,35};
__constant__ int c_pc[84] = {
    0,0,0,0,0,0,
    0,0,1,2,3,0,1,2,3,0,1,2,3,0,1,2,3,0,
    0,0,1,2,3,0,1,2,3,0,1,2,3,0,1,2,3,0,
    0,0,1,2,3,0,1,2,3,0,1,2,3,0,1,2,3,0,
    0,0,1,2,3,0,1,2,3,0,1,2,3,0,1,2,3,0,
    0,0,0,0,0,0};

// ------------------------------ K1: embed ----------------------------------
__global__ __launch_bounds__(256) void k_embed(const int* __restrict__ x,
        const float* __restrict__ emb, const float* __restrict__ pos,
        float* __restrict__ h) {
    int idx = blockIdx.x * 256 + threadIdx.x;
    if (idx >= BSZ * NS * EMB) return;
    int e = idx & (EMB - 1);
    int g = idx >> 7;            // token
    int s = g % NS;
    h[idx] = emb[x[g] * EMB + e] + pos[s * EMB + e];
}

// ------------------------------ K2a: QKV GEMM ------------------------------
// [73728 x 128] @ [128 x 384] + bias. 64 tokens x 128 cols per block.
__global__ __launch_bounds__(256) void k_qkv(const float* __restrict__ h,
        const float* __restrict__ Wqkv, const float* __restrict__ bqkv,
        float* __restrict__ qkv) {
    __shared__ float As[64 * 132];
    __shared__ float Ws[32 * 132];
    int tid = threadIdx.x;
    int chunk = blockIdx.x;          // 0..2 -> output cols chunk*128..+127
    int tok0 = blockIdx.y * 64;
    int tx = tid & 15, ty = tid >> 4;
    for (int idx = tid; idx < 64 * 128; idx += 256) {
        int t = idx >> 7, k = idx & 127;
        As[t * 132 + k] = h[(size_t)(tok0 + t) * EMB + k];
    }
    float acc[4][8];
    #pragma unroll
    for (int i = 0; i < 4; ++i)
        #pragma unroll
        for (int q = 0; q < 8; ++q) acc[i][q] = 0.f;
    for (int ks = 0; ks < 4; ++ks) {
        __syncthreads();
        for (int idx = tid; idx < 32 * 128; idx += 256) {
            int kk = idx >> 7, c = idx & 127;
            Ws[kk * 132 + c] = Wqkv[(size_t)(ks * 32 + kk) * 384 + chunk * 128 + c];
        }
        __syncthreads();
        #pragma unroll 4
        for (int kk = 0; kk < 32; ++kk) {
            float4 w0 = *(const float4*)&Ws[kk * 132 + tx * 8];
            float4 w1 = *(const float4*)&Ws[kk * 132 + tx * 8 + 4];
            #pragma unroll
            for (int i = 0; i < 4; ++i) {
                float a = As[(ty * 4 + i) * 132 + ks * 32 + kk];
                acc[i][0] += a * w0.x; acc[i][1] += a * w0.y;
                acc[i][2] += a * w0.z; acc[i][3] += a * w0.w;
                acc[i][4] += a * w1.x; acc[i][5] += a * w1.y;
                acc[i][6] += a * w1.z; acc[i][7] += a * w1.w;
            }
        }
    }
    #pragma unroll
    for (int i = 0; i < 4; ++i) {
        size_t base = (size_t)(tok0 + ty * 4 + i) * 384 + chunk * 128 + tx * 8;
        #pragma unroll
        for (int q = 0; q < 8; ++q)
            qkv[base + q] = acc[i][q] + bqkv[chunk * 128 + tx * 8 + q];
    }
}

// ------------------------------ K2b: attention core ------------------------
// One wave per (batch, head). q/k/v staged in padded LDS (stride 17),
// scores in stride-37 LDS, softmax per row, o overwrites the dead q-slot.
__global__ __launch_bounds__(256) void k_attnc(float* __restrict__ qkv) {
    __shared__ float qs[4][NS * 17];
    __shared__ float ks_[4][NS * 17];
    __shared__ float vs[4][NS * 17];
    __shared__ float S[4][NS * 37];
    int wid = threadIdx.x >> 6, lane = threadIdx.x & 63;
    int m = blockIdx.x * 4 + wid;
    int b = m >> 3, hd = m & 7;
    float* Q = qkv + (size_t)b * NS * 384 + hd * DH;   // row stride 384
    for (int idx = lane; idx < NS * DH; idx += 64) {
        int t = idx >> 4, d = idx & 15;
        qs[wid][t * 17 + d]  = Q[t * 384 + d];
        ks_[wid][t * 17 + d] = Q[t * 384 + 128 + d];
        vs[wid][t * 17 + d]  = Q[t * 384 + 256 + d];
    }
    __syncthreads();
    for (int idx = lane; idx < NS * NS; idx += 64) {
        int qp = idx / NS, kp = idx - qp * NS;
        float acc = 0.f;
        #pragma unroll
        for (int d = 0; d < DH; ++d)
            acc += qs[wid][qp * 17 + d] * ks_[wid][kp * 17 + d];
        S[wid][qp * 37 + kp] = acc * 0.25f;     // 1/sqrt(16)
    }
    __syncthreads();
    if (lane < NS) {
        float mx = -1e30f;
        for (int j = 0; j < NS; ++j) mx = fmaxf(mx, S[wid][lane * 37 + j]);
        float z = 0.f;
        for (int j = 0; j < NS; ++j) {
            float e = expf(S[wid][lane * 37 + j] - mx);
            S[wid][lane * 37 + j] = e; z += e;
        }
        float inv = 1.f / z;
        for (int j = 0; j < NS; ++j) S[wid][lane * 37 + j] *= inv;
    }
    __syncthreads();
    for (int idx = lane; idx < NS * DH; idx += 64) {
        int qp = idx >> 4, d = idx & 15;
        float acc = 0.f;
        for (int kp = 0; kp < NS; ++kp)
            acc += S[wid][qp * 37 + kp] * vs[wid][kp * 17 + d];
        Q[qp * 384 + d] = acc;                  // o into dead q-slot
    }
}

// ------------------------------ K2c: out-proj + residual -------------------
// h += o @ Wo + bo, o rows at qkv[tok*384 + 0..127].
__global__ __launch_bounds__(256) void k_oproj(const float* __restrict__ qkv,
        const float* __restrict__ Wo, const float* __restrict__ bo,
        float* __restrict__ h) {
    __shared__ float As[64 * 132];
    __shared__ float Ws[32 * 132];
    int tid = threadIdx.x;
    int tok0 = blockIdx.x * 64;
    int tx = tid & 15, ty = tid >> 4;
    for (int idx = tid; idx < 64 * 128; idx += 256) {
        int t = idx >> 7, k = idx & 127;
        As[t * 132 + k] = qkv[(size_t)(tok0 + t) * 384 + k];
    }
    float acc[4][8];
    #pragma unroll
    for (int i = 0; i < 4; ++i)
        #pragma unroll
        for (int q = 0; q < 8; ++q) acc[i][q] = 0.f;
    for (int ks = 0; ks < 4; ++ks) {
        __syncthreads();
        for (int idx = tid; idx < 32 * 128; idx += 256) {
            int kk = idx >> 7, c = idx & 127;
            Ws[kk * 132 + c] = Wo[(size_t)(ks * 32 + kk) * EMB + c];
        }
        __syncthreads();
        #pragma unroll 4
        for (int kk = 0; kk < 32; ++kk) {
            float4 w0 = *(const float4*)&Ws[kk * 132 + tx * 8];
            float4 w1 = *(const float4*)&Ws[kk * 132 + tx * 8 + 4];
            #pragma unroll
            for (int i = 0; i < 4; ++i) {
                float a = As[(ty * 4 + i) * 132 + ks * 32 + kk];
                acc[i][0] += a * w0.x; acc[i][1] += a * w0.y;
                acc[i][2] += a * w0.z; acc[i][3] += a * w0.w;
                acc[i][4] += a * w1.x; acc[i][5] += a * w1.y;
                acc[i][6] += a * w1.z; acc[i][7] += a * w1.w;
            }
        }
    }
    #pragma unroll
    for (int i = 0; i < 4; ++i) {
        size_t base = (size_t)(tok0 + ty * 4 + i) * EMB + tx * 8;
        #pragma unroll
        for (int q = 0; q < 8; ++q)
            h[base + q] = h[base + q] + acc[i][q] + bo[tx * 8 + q];
    }
}

// ------------------------------ K3a: GEMM1 (h@W1, gelu) --------------------
__global__ __launch_bounds__(256) void k_gemm1(const float* __restrict__ h,
        const float* __restrict__ W1, const float* __restrict__ b1,
        float* __restrict__ Hm) {
    __shared__ float As[64 * 132];   // [token][k], pad 132
    __shared__ float Ws[32 * 132];   // [kk][col], pad 132
    int tid = threadIdx.x;
    int chunk = blockIdx.x;          // 0..3 -> output cols chunk*128..+127
    int tok0 = blockIdx.y * 64;      // token tile (local to eighth)
    int tx = tid & 15, ty = tid >> 4;
    for (int idx = tid; idx < 64 * 128; idx += 256) {
        int t = idx >> 7, k = idx & 127;
        As[t * 132 + k] = h[(size_t)(tok0 + t) * EMB + k];
    }
    float acc[4][8];
    #pragma unroll
    for (int i = 0; i < 4; ++i)
        #pragma unroll
        for (int q = 0; q < 8; ++q) acc[i][q] = 0.f;
    for (int ks = 0; ks < 4; ++ks) {
        __syncthreads();
        for (int idx = tid; idx < 32 * 128; idx += 256) {
            int kk = idx >> 7, c = idx & 127;
            Ws[kk * 132 + c] = W1[(size_t)(ks * 32 + kk) * HIDD + chunk * 128 + c];
        }
        __syncthreads();
        #pragma unroll 4
        for (int kk = 0; kk < 32; ++kk) {
            float4 w0 = *(const float4*)&Ws[kk * 132 + tx * 8];
            float4 w1 = *(const float4*)&Ws[kk * 132 + tx * 8 + 4];
            #pragma unroll
            for (int i = 0; i < 4; ++i) {
                float a = As[(ty * 4 + i) * 132 + ks * 32 + kk];
                acc[i][0] += a * w0.x; acc[i][1] += a * w0.y;
                acc[i][2] += a * w0.z; acc[i][3] += a * w0.w;
                acc[i][4] += a * w1.x; acc[i][5] += a * w1.y;
                acc[i][6] += a * w1.z; acc[i][7] += a * w1.w;
            }
        }
    }
    #pragma unroll
    for (int i = 0; i < 4; ++i) {
        size_t base = (size_t)(tok0 + ty * 4 + i) * HIDD + chunk * 128 + tx * 8;
        #pragma unroll
        for (int q = 0; q < 8; ++q) {
            float a = acc[i][q] + b1[chunk * 128 + tx * 8 + q];
            Hm[base + q] = 0.5f * a * (1.f + erff(a * 0.70710678118654752f));
        }
    }
}

// ------------------------------ K3b: GEMM2 (Hm@W2, backflow) ---------------
__global__ __launch_bounds__(256) void k_gemm2(const float* __restrict__ Hm,
        const float* __restrict__ W2, const float* __restrict__ b2,
        const float* __restrict__ ftn, float* __restrict__ vecs, int e8) {
    __shared__ float As[64 * 33];    // [batch][kk], pad 33
    __shared__ float Ws[32 * 132];   // [kk][col], pad 132
    int tid = threadIdx.x;
    int pair = blockIdx.x;
    int s = c_ps[pair], chunk = c_pc[pair];
    int b0 = blockIdx.y * 64;        // batch tile (local to eighth)
    int off = c_offs[s], size = c_offs[s + 1] - off;
    int tx = tid & 15, ty = tid >> 4;
    float acc[4][8];
    #pragma unroll
    for (int i = 0; i < 4; ++i)
        #pragma unroll
        for (int q = 0; q < 8; ++q) acc[i][q] = 0.f;
    for (int ks = 0; ks < 16; ++ks) {
        __syncthreads();
        for (int idx = tid; idx < 64 * 32; idx += 256) {
            int t = idx >> 5, kk = idx & 31;
            As[t * 33 + kk] = Hm[(size_t)((b0 + t) * NS + s) * HIDD + ks * 32 + kk];
        }
        for (int idx = tid; idx < 32 * 128; idx += 256) {
            int kk = idx >> 7, c = idx & 127;
            Ws[kk * 132 + c] = W2[(size_t)(ks * 32 + kk) * HIDD + chunk * 128 + c];
        }
        __syncthreads();
        #pragma unroll 4
        for (int kk = 0; kk < 32; ++kk) {
            float4 w0 = *(const float4*)&Ws[kk * 132 + tx * 8];
            float4 w1 = *(const float4*)&Ws[kk * 132 + tx * 8 + 4];
            #pragma unroll
            for (int i = 0; i < 4; ++i) {
                float a = As[(ty * 4 + i) * 33 + kk];
                acc[i][0] += a * w0.x; acc[i][1] += a * w0.y;
                acc[i][2] += a * w0.z; acc[i][3] += a * w0.w;
                acc[i][4] += a * w1.x; acc[i][5] += a * w1.y;
                acc[i][6] += a * w1.z; acc[i][7] += a * w1.w;
            }
        }
    }
    #pragma unroll
    for (int i = 0; i < 4; ++i) {
        int bg = e8 * 256 + b0 + ty * 4 + i;     // global batch
        #pragma unroll
        for (int q = 0; q < 8; ++q) {
            int col = chunk * 128 + tx * 8 + q;
            if (col < size) {
                float o = acc[i][q] + b2[col];
                vecs[(size_t)bg * TOTV + off + col] = ftn[off + col] + 0.1f * o;
            }
        }
    }
}

// ------------------------------ K4a: build Psi -----------------------------
__device__ __forceinline__ float* build_half(const float* __restrict__ vb,
        const int* __restrict__ xb, int side, int upper,
        float* cur, float* fre, float* ts0, float* ts1, float* ts2, int tid) {
    if (tid == 0) cur[0] = 1.0f;
    __syncthreads();
    int bd = 1, lgbd = 0;
    for (int t = 0; t < 3; ++t) {
        int xd = t ? 4 : 1, lgxd = t ? 2 : 0;
        int j = side ? (5 - t) : t;
        int rows[3];
        rows[0] = upper ? 0 : 5; rows[1] = upper ? 1 : 4; rows[2] = upper ? 2 : 3;
        for (int role = 0; role < 3; ++role) {
            int i = rows[role];
            int dd = (i < 5) ? 4 : 1, dl = (j > 0) ? 4 : 1, dr = (j < 5) ? 4 : 1;
            int su = dd * dl * dr * 2, sd = dl * dr * 2, sl = dr * 2, sr = 2;
            int xstr = side ? sr : sl, ystr = side ? sl : sr;
            int base = c_offs[i * 6 + j] + xb[i * 6 + j];
            if (role == 0) {
                int astr = upper ? sd : su;
                int n = 4 * xd * 4;
                for (int idx = tid; idx < n; idx += 256) {
                    int y = idx & 3, xx = (idx >> 2) & (xd - 1), a = idx >> (2 + lgxd);
                    ts0[idx] = vb[base + a * astr + xx * xstr + y * ystr];
                }
            } else if (role == 1) {
                int astr = upper ? su : sd, cstr = upper ? sd : su;
                int n = 16 * xd * 4;
                for (int idx = tid; idx < n; idx += 256) {
                    int y = idx & 3, xx = (idx >> 2) & (xd - 1);
                    int c = (idx >> (2 + lgxd)) & 3, a = idx >> (4 + lgxd);
                    ts1[idx] = vb[base + a * astr + c * cstr + xx * xstr + y * ystr];
                }
            } else {
                int cstr = upper ? su : sd, bstr = upper ? sd : su;
                int n = 16 * xd * 4;
                for (int idx = tid; idx < n; idx += 256) {
                    int y = idx & 3, xx = (idx >> 2) & (xd - 1);
                    int bb = (idx >> (2 + lgxd)) & 3, c = idx >> (4 + lgxd);
                    ts2[idx] = vb[base + c * cstr + bb * bstr + xx * xstr + y * ystr];
                }
            }
        }
        __syncthreads();
        int n1 = 16 * xd * xd * bd;
        for (int idx = tid; idx < n1; idx += 256) {
            int bt = idx & (bd - 1);
            int r = idx >> lgbd;
            int x2 = r & (xd - 1); r >>= lgxd;
            int x1 = r & (xd - 1); r >>= lgxd;
            int a = r & 3, y0 = r >> 2;
            float s2 = 0.f;
            for (int x0 = 0; x0 < xd; ++x0)
                s2 += cur[(((((x0 << lgxd) | x1) << lgxd) | x2) << lgbd) | bt]
                    * ts0[(((a << lgxd) | x0) << 2) | y0];
            fre[idx] = s2;
        }
        __syncthreads();
        int n2 = 64 * xd * bd;
        for (int idx = tid; idx < n2; idx += 256) {
            int bt = idx & (bd - 1);
            int r = idx >> lgbd;
            int x2 = r & (xd - 1); r >>= lgxd;
            int c = r & 3, y1 = (r >> 2) & 3, y0 = r >> 4;
            float s2 = 0.f;
            for (int a = 0; a < 4; ++a)
                for (int x1 = 0; x1 < xd; ++x1)
                    s2 += fre[((((((((y0 << 2) | a) << lgxd) | x1) << lgxd) | x2)) << lgbd) | bt]
                        * ts1[((((a * 4 + c) << lgxd) | x1) << 2) | y1];
            cur[idx] = s2;
        }
        __syncthreads();
        int n3 = 256 * bd;
        for (int idx = tid; idx < n3; idx += 256) {
            int bn = idx & (4 * bd - 1);
            int bt = bn >> 2, bb = bn & 3;
            int r = idx >> (lgbd + 2);
            int y2 = r & 3, y1 = (r >> 2) & 3, y0 = r >> 4;
            float s2 = 0.f;
            for (int c = 0; c < 4; ++c)
                for (int x2 = 0; x2 < xd; ++x2)
                    s2 += cur[((((((y0 << 2) | y1) << 2 | c) << lgxd) | x2) << lgbd) | bt]
                        * ts2[((((c * 4 + bb) << lgxd) | x2) << 2) | y2];
            fre[idx] = s2;
        }
        __syncthreads();
        float* tmp = cur; cur = fre; fre = tmp;
        bd <<= 2; lgbd += 2;
    }
    return cur;
}

__global__ __launch_bounds__(256) void k_build(const float* __restrict__ vecs,
        const int* __restrict__ x, float* __restrict__ psi) {
    __shared__ float X1[4096], X2[4096], X3[4096];
    __shared__ float ts0[64], ts1[256], ts2[256];
    int m = blockIdx.x;
    int b = m >> 1, side = m & 1;
    int tid = threadIdx.x;
    const float* vb = vecs + (size_t)b * TOTV;
    const int* xb = x + b * NS;
    float* A  = build_half(vb, xb, side, 1, X1, X2, ts0, ts1, ts2, tid);
    float* Bt = build_half(vb, xb, side, 0, X1, X3, ts0, ts1, ts2, tid);
    float* po = psi + (size_t)m * 4096;
    for (int idx = tid; idx < 4096; idx += 256) {
        int u = idx >> 6, l = idx & 63;
        const float4* a4 = (const float4*)(A + u * 64);
        const float4* b4 = (const float4*)(Bt + l * 64);
        float s2 = 0.f;
        #pragma unroll
        for (int q = 0; q < 16; ++q) {
            float4 av = a4[q], bv = b4[q];
            s2 += av.x * bv.x + av.y * bv.y + av.z * bv.z + av.w * bv.w;
        }
        po[idx] = s2;
    }
}

// ------------------------------ K4b: Jacobi SVD ----------------------------
// R10: 2 waves per 128-thread block, grid 2048 -> 8 blocks/CU -> up to 16
// waves/CU (prior configs pinned ~9). Lane j holds column j of W in 4
// ext_vector(16) values (packed fp32 math, depth-4 tree reductions).
// Sweep cap 8. Epilogue: Q = top-16 normalized cols, T = Q^T Psi via LDS.
__global__ __launch_bounds__(128, 2) void k_svd(const float* __restrict__ psi,
                                                float* __restrict__ wv) {
    __shared__ __align__(16) float qlds[2][64 * 20];   // per-wave Q slab
    int wid = threadIdx.x >> 6, lane = threadIdx.x & 63;
    int m = blockIdx.x * 2 + wid;
    const float* P = psi + (size_t)m * 4096;
    f16v w0, w1, w2, w3;
    #pragma unroll
    for (int r = 0; r < 16; ++r) w0[r] = P[r * 64 + lane];
    #pragma unroll
    for (int r = 0; r < 16; ++r) w1[r] = P[(r + 16) * 64 + lane];
    #pragma unroll
    for (int r = 0; r < 16; ++r) w2[r] = P[(r + 32) * 64 + lane];
    #pragma unroll
    for (int r = 0; r < 16; ++r) w3[r] = P[(r + 48) * 64 + lane];

    for (int sweep = 0; sweep < 8; ++sweep) {
        f16v nv = w0 * w0 + w1 * w1 + w2 * w2 + w3 * w3;
        float n2 = hsum16(nv);                  // exact refresh per sweep
        bool any = false;
        for (int mm = 1; mm < 64; ++mm) {
            int partner = lane ^ mm;
            f16v p0, p1, p2, p3;
            #pragma unroll
            for (int r = 0; r < 16; ++r) p0[r] = __shfl(w0[r], partner);
            #pragma unroll
            for (int r = 0; r < 16; ++r) p1[r] = __shfl(w1[r], partner);
            #pragma unroll
            for (int r = 0; r < 16; ++r) p2[r] = __shfl(w2[r], partner);
            #pragma unroll
            for (int r = 0; r < 16; ++r) p3[r] = __shfl(w3[r], partner);
            f16v gv = w0 * p0 + w1 * p1 + w2 * p2 + w3 * p3;
            float gam = hsum16(gv);
            float beta2 = __shfl(n2, partner);
            bool rot = fabsf(gam) > 1e-5f * sqrtf(fmaxf(n2 * beta2, 0.f));
            unsigned long long bal = __ballot(rot);
            if (bal == 0ull) continue;
            any = true;
            float c = 1.f, s = 0.f;
            if (rot) {
                float zeta = (n2 - beta2) / (2.f * gam);
                float sgn = (zeta > 0.f) ? 1.f :
                            ((zeta < 0.f) ? -1.f : ((lane < partner) ? 1.f : -1.f));
                float tt = sgn / (fabsf(zeta) + sqrtf(1.f + zeta * zeta));
                c = 1.f / sqrtf(1.f + tt * tt);
                s = c * tt;
            }
            w0 = c * w0 + s * p0;
            w1 = c * w1 + s * p1;
            w2 = c * w2 + s * p2;
            w3 = c * w3 + s * p3;
            n2 = c * c * n2 + s * s * beta2 + 2.f * c * s * gam;
        }
        if (!any) break;
    }
    // exact norms -> rank by descending norm (index tie-break)
    f16v ne = w0 * w0 + w1 * w1 + w2 * w2 + w3 * w3;
    float n2e = hsum16(ne);
    int rank = 0;
    for (int j = 0; j < 64; ++j) {
        float nj = __shfl(n2e, j);
        if (nj > n2e || (nj == n2e && j < lane)) ++rank;
    }
    float inv = (n2e > 1e-30f) ? 1.f / sqrtf(n2e) : 0.f;
    // stage Q (top-16 normalized columns) into this wave's LDS slab
    if (rank < 16) {
        #pragma unroll
        for (int r = 0; r < 16; ++r) {
            qlds[wid][r * 20 + rank]        = w0[r] * inv;
            qlds[wid][(r + 16) * 20 + rank] = w1[r] * inv;
            qlds[wid][(r + 32) * 20 + rank] = w2[r] * inv;
            qlds[wid][(r + 48) * 20 + rank] = w3[r] * inv;
        }
    }
    __syncthreads();
    float* o = wv + (size_t)m * 2048;
    #pragma unroll
    for (int k = 0; k < 16; ++k) o[k * 64 + lane] = qlds[wid][lane * 20 + k];
    // T = Q^T Psi : lane computes T[0..15][lane], re-reading Psi from L2
    f16v t;
    #pragma unroll
    for (int k = 0; k < 16; ++k) t[k] = 0.f;
    for (int r = 0; r < 64; ++r) {
        float pr = P[r * 64 + lane];
        const float4* q4 = (const float4*)&qlds[wid][r * 20];
        float4 a = q4[0], b = q4[1], cc = q4[2], d = q4[3];
        t[0]  += a.x  * pr; t[1]  += a.y  * pr; t[2]  += a.z  * pr; t[3]  += a.w  * pr;
        t[4]  += b.x  * pr; t[5]  += b.y  * pr; t[6]  += b.z  * pr; t[7]  += b.w  * pr;
        t[8]  += cc.x * pr; t[9]  += cc.y * pr; t[10] += cc.z * pr; t[11] += cc.w * pr;
        t[12] += d.x  * pr; t[13] += d.y  * pr; t[14] += d.z  * pr; t[15] += d.w  * pr;
    }
    #pragma unroll
    for (int k = 0; k < 16; ++k) o[1024 + k * 64 + lane] = t[k];
}

// ------------------------------ K4c: amplitude -----------------------------
__global__ __launch_bounds__(256) void k_amp(const float* __restrict__ wv,
                                             float* __restrict__ out) {
    __shared__ float s[4096];
    __shared__ float part[4];
    int b = blockIdx.x, tid = threadIdx.x;
    const float* src = wv + (size_t)b * 4096;
    for (int i = tid; i < 4096; i += 256) s[i] = src[i];
    __syncthreads();
    int k = tid >> 4, mm = tid & 15;
    const float* WL = s;
    const float* VL = s + 1024;
    const float* WR = s + 2048;
    const float* VR = s + 3072;
    float du = 0.f, dv = 0.f;
    for (int r = 0; r < 64; ++r) {
        du += WL[k * 64 + r] * WR[mm * 64 + r];
        dv += VL[k * 64 + r] * VR[mm * 64 + r];
    }
    float p = du * dv;
    for (int off = 32; off > 0; off >>= 1) p += __shfl_down(p, off);
    if ((tid & 63) == 0) part[tid >> 6] = p;
    __syncthreads();
    if (tid == 0) out[b] = part[0] + part[1] + part[2] + part[3];
}

// ------------------------------ launch -------------------------------------
extern "C" void kernel_launch(void* const* d_in, const int* in_sizes, int n_in,
                              void* d_out, int out_size, void* d_ws, size_t ws_size,
                              hipStream_t stream) {
    const int*   x    = (const int*)d_in[0];
    const float* ftn  = (const float*)d_in[1];
    const float* emb  = (const float*)d_in[2];
    const float* pos  = (const float*)d_in[3];
    const float* Wqkv = (const float*)d_in[4];
    const float* bqkv = (const float*)d_in[5];
    const float* Wo   = (const float*)d_in[6];
    const float* bo   = (const float*)d_in[7];
    const float* W1   = (const float*)d_in[8];
    const float* b1   = (const float*)d_in[9];
    const float* W2   = (const float*)d_in[10];
    const float* b2   = (const float*)d_in[11];
    float* out = (float*)d_out;
    float* ws  = (float*)d_ws;

    // layout (floats), total 46.4M = 186 MB:
    //   [0, 16777216)           psi; h at [0, 9437184), Hm_e at [9437184,..)
    //   [16777216, 38010880)    vecs (2048*10368)
    //   [38010880, 46399488)    wv
    //   qkv (28.3M) transiently occupies [16777216, 45088768) -- dead before
    //   gemm2 writes vecs and before svd writes wv.
    float* h    = ws;
    float* Hm_e = ws + 9437184;          // 2304 tokens * 512
    float* psi  = ws;
    float* vecs = ws + 16777216;
    float* qkv  = ws + 16777216;
    float* wv   = ws + 16777216 + 21233664;

    hipLaunchKernelGGL(k_embed, dim3((BSZ * NS * EMB + 255) / 256), dim3(256), 0, stream,
                       x, emb, pos, h);
    hipLaunchKernelGGL(k_qkv, dim3(3, 1152), dim3(256), 0, stream,
                       h, Wqkv, bqkv, qkv);
    hipLaunchKernelGGL(k_attnc, dim3(BSZ * NHEAD / 4), dim3(256), 0, stream, qkv);
    hipLaunchKernelGGL(k_oproj, dim3(1152), dim3(256), 0, stream,
                       qkv, Wo, bo, h);
    for (int e8 = 0; e8 < 8; ++e8) {
        const float* h_e = h + (size_t)e8 * 9216 * EMB;
        hipLaunchKernelGGL(k_gemm1, dim3(4, 144), dim3(256), 0, stream,
                           h_e, W1, b1, Hm_e);
        hipLaunchKernelGGL(k_gemm2, dim3(84, 4), dim3(256), 0, stream,
                           Hm_e, W2, b2, ftn, vecs, e8);
    }
    hipLaunchKernelGGL(k_build, dim3(2 * BSZ), dim3(256), 0, stream, vecs, x, psi);
    hipLaunchKernelGGL(k_svd, dim3(BSZ), dim3(128), 0, stream, psi, wv);
    hipLaunchKernelGGL(k_amp, dim3(BSZ), dim3(256), 0, stream, wv, out);
}

// Round 11
// 3291.850 us; speedup vs baseline: 1.6531x; 1.1433x over previous
//
#include <hip/hip_runtime.h>
#include <math.h>

// ---------------------------------------------------------------------------
// Transformer_fPEPS: transformer (f32 VALU GEMMs) + PEPS amplitude.
//
// Math reduction (validated R1, absmax 3.8e-6): every SVD in the reference
// _compress is lossless gauge EXCEPT the bond-(2,3) truncation (64 -> chi=16)
// on each side. amp(b) = < rank16(Psi_L), rank16(Psi_R) >_F.
//
// R11: k_svd is DS-pipe-bound (R5/R8/R9/R10 all ~2.0ms across occupancy/
// packing configs; invariant = ds_bpermute count). Only lever: fewer sweeps.
// Coarse sweep-exit: stop once no pair exceeds 1e-3 relative in a sweep
// (rotations still applied down to 1e-5 while sweeping); cap 6 sweeps.
// Projector error ~1e-3 rel -> amp error ~2e-6 abs << 3.43e-5 threshold.
// ---------------------------------------------------------------------------

#define BSZ   2048
#define NS    36
#define EMB   128
#define NHEAD 8
#define DH    16
#define HIDD  512
#define TOTV  10368

typedef float f16v __attribute__((ext_vector_type(16)));

__device__ __forceinline__ float hsum16(f16v v) {
    float a = (v[0] + v[1]) + (v[2] + v[3]);
    float b = (v[4] + v[5]) + (v[6] + v[7]);
    float c = (v[8] + v[9]) + (v[10] + v[11]);
    float d = (v[12] + v[13]) + (v[14] + v[15]);
    return (a + b) + (c + d);
}

__constant__ int c_offs[37] = {
    0,32,160,288,416,544,576,
    704,1216,1728,2240,2752,2880,
    3008,3520,4032,4544,5056,5184,
    5312,5824,6336,6848,7360,7488,
    7616,8128,8640,9152,9664,9792,
    9824,9952,10080,10208,10336,10368};

// (site, col-chunk) pairs for trimmed GEMM2: 84 pairs
__constant__ int c_ps[84] = {
    0,1,2,3,4,5,
    6,7,7,7,7,8,8,8,8,9,9,9,9,10,10,10,10,11,
    12,13,13,13,13,14,14,14,14,15,15,15,15,16,16,16,16,17,
    18,19,19,19,19,20,20,20,20,21,21,21,21,22,22,22,22,23,
    24,25,25,25,25,26,26,26,26,27,27,27,27,28,28,28,28,29,
    30,31,32,33,34,35};
__constant__ int c_pc[84] = {
    0,0,0,0,0,0,
    0,0,1,2,3,0,1,2,3,0,1,2,3,0,1,2,3,0,
    0,0,1,2,3,0,1,2,3,0,1,2,3,0,1,2,3,0,
    0,0,1,2,3,0,1,2,3,0,1,2,3,0,1,2,3,0,
    0,0,1,2,3,0,1,2,3,0,1,2,3,0,1,2,3,0,
    0,0,0,0,0,0};

// ------------------------------ K1: embed ----------------------------------
__global__ __launch_bounds__(256) void k_embed(const int* __restrict__ x,
        const float* __restrict__ emb, const float* __restrict__ pos,
        float* __restrict__ h) {
    int idx = blockIdx.x * 256 + threadIdx.x;
    if (idx >= BSZ * NS * EMB) return;
    int e = idx & (EMB - 1);
    int g = idx >> 7;            // token
    int s = g % NS;
    h[idx] = emb[x[g] * EMB + e] + pos[s * EMB + e];
}

// ------------------------------ K2a: QKV GEMM ------------------------------
// [73728 x 128] @ [128 x 384] + bias. 64 tokens x 128 cols per block.
__global__ __launch_bounds__(256) void k_qkv(const float* __restrict__ h,
        const float* __restrict__ Wqkv, const float* __restrict__ bqkv,
        float* __restrict__ qkv) {
    __shared__ float As[64 * 132];
    __shared__ float Ws[32 * 132];
    int tid = threadIdx.x;
    int chunk = blockIdx.x;          // 0..2 -> output cols chunk*128..+127
    int tok0 = blockIdx.y * 64;
    int tx = tid & 15, ty = tid >> 4;
    for (int idx = tid; idx < 64 * 128; idx += 256) {
        int t = idx >> 7, k = idx & 127;
        As[t * 132 + k] = h[(size_t)(tok0 + t) * EMB + k];
    }
    float acc[4][8];
    #pragma unroll
    for (int i = 0; i < 4; ++i)
        #pragma unroll
        for (int q = 0; q < 8; ++q) acc[i][q] = 0.f;
    for (int ks = 0; ks < 4; ++ks) {
        __syncthreads();
        for (int idx = tid; idx < 32 * 128; idx += 256) {
            int kk = idx >> 7, c = idx & 127;
            Ws[kk * 132 + c] = Wqkv[(size_t)(ks * 32 + kk) * 384 + chunk * 128 + c];
        }
        __syncthreads();
        #pragma unroll 4
        for (int kk = 0; kk < 32; ++kk) {
            float4 w0 = *(const float4*)&Ws[kk * 132 + tx * 8];
            float4 w1 = *(const float4*)&Ws[kk * 132 + tx * 8 + 4];
            #pragma unroll
            for (int i = 0; i < 4; ++i) {
                float a = As[(ty * 4 + i) * 132 + ks * 32 + kk];
                acc[i][0] += a * w0.x; acc[i][1] += a * w0.y;
                acc[i][2] += a * w0.z; acc[i][3] += a * w0.w;
                acc[i][4] += a * w1.x; acc[i][5] += a * w1.y;
                acc[i][6] += a * w1.z; acc[i][7] += a * w1.w;
            }
        }
    }
    #pragma unroll
    for (int i = 0; i < 4; ++i) {
        size_t base = (size_t)(tok0 + ty * 4 + i) * 384 + chunk * 128 + tx * 8;
        #pragma unroll
        for (int q = 0; q < 8; ++q)
            qkv[base + q] = acc[i][q] + bqkv[chunk * 128 + tx * 8 + q];
    }
}

// ------------------------------ K2b: attention core ------------------------
// One wave per (batch, head). q/k/v staged in padded LDS (stride 17),
// scores in stride-37 LDS, softmax per row, o overwrites the dead q-slot.
__global__ __launch_bounds__(256) void k_attnc(float* __restrict__ qkv) {
    __shared__ float qs[4][NS * 17];
    __shared__ float ks_[4][NS * 17];
    __shared__ float vs[4][NS * 17];
    __shared__ float S[4][NS * 37];
    int wid = threadIdx.x >> 6, lane = threadIdx.x & 63;
    int m = blockIdx.x * 4 + wid;
    int b = m >> 3, hd = m & 7;
    float* Q = qkv + (size_t)b * NS * 384 + hd * DH;   // row stride 384
    for (int idx = lane; idx < NS * DH; idx += 64) {
        int t = idx >> 4, d = idx & 15;
        qs[wid][t * 17 + d]  = Q[t * 384 + d];
        ks_[wid][t * 17 + d] = Q[t * 384 + 128 + d];
        vs[wid][t * 17 + d]  = Q[t * 384 + 256 + d];
    }
    __syncthreads();
    for (int idx = lane; idx < NS * NS; idx += 64) {
        int qp = idx / NS, kp = idx - qp * NS;
        float acc = 0.f;
        #pragma unroll
        for (int d = 0; d < DH; ++d)
            acc += qs[wid][qp * 17 + d] * ks_[wid][kp * 17 + d];
        S[wid][qp * 37 + kp] = acc * 0.25f;     // 1/sqrt(16)
    }
    __syncthreads();
    if (lane < NS) {
        float mx = -1e30f;
        for (int j = 0; j < NS; ++j) mx = fmaxf(mx, S[wid][lane * 37 + j]);
        float z = 0.f;
        for (int j = 0; j < NS; ++j) {
            float e = expf(S[wid][lane * 37 + j] - mx);
            S[wid][lane * 37 + j] = e; z += e;
        }
        float inv = 1.f / z;
        for (int j = 0; j < NS; ++j) S[wid][lane * 37 + j] *= inv;
    }
    __syncthreads();
    for (int idx = lane; idx < NS * DH; idx += 64) {
        int qp = idx >> 4, d = idx & 15;
        float acc = 0.f;
        for (int kp = 0; kp < NS; ++kp)
            acc += S[wid][qp * 37 + kp] * vs[wid][kp * 17 + d];
        Q[qp * 384 + d] = acc;                  // o into dead q-slot
    }
}

// ------------------------------ K2c: out-proj + residual -------------------
// h += o @ Wo + bo, o rows at qkv[tok*384 + 0..127].
__global__ __launch_bounds__(256) void k_oproj(const float* __restrict__ qkv,
        const float* __restrict__ Wo, const float* __restrict__ bo,
        float* __restrict__ h) {
    __shared__ float As[64 * 132];
    __shared__ float Ws[32 * 132];
    int tid = threadIdx.x;
    int tok0 = blockIdx.x * 64;
    int tx = tid & 15, ty = tid >> 4;
    for (int idx = tid; idx < 64 * 128; idx += 256) {
        int t = idx >> 7, k = idx & 127;
        As[t * 132 + k] = qkv[(size_t)(tok0 + t) * 384 + k];
    }
    float acc[4][8];
    #pragma unroll
    for (int i = 0; i < 4; ++i)
        #pragma unroll
        for (int q = 0; q < 8; ++q) acc[i][q] = 0.f;
    for (int ks = 0; ks < 4; ++ks) {
        __syncthreads();
        for (int idx = tid; idx < 32 * 128; idx += 256) {
            int kk = idx >> 7, c = idx & 127;
            Ws[kk * 132 + c] = Wo[(size_t)(ks * 32 + kk) * EMB + c];
        }
        __syncthreads();
        #pragma unroll 4
        for (int kk = 0; kk < 32; ++kk) {
            float4 w0 = *(const float4*)&Ws[kk * 132 + tx * 8];
            float4 w1 = *(const float4*)&Ws[kk * 132 + tx * 8 + 4];
            #pragma unroll
            for (int i = 0; i < 4; ++i) {
                float a = As[(ty * 4 + i) * 132 + ks * 32 + kk];
                acc[i][0] += a * w0.x; acc[i][1] += a * w0.y;
                acc[i][2] += a * w0.z; acc[i][3] += a * w0.w;
                acc[i][4] += a * w1.x; acc[i][5] += a * w1.y;
                acc[i][6] += a * w1.z; acc[i][7] += a * w1.w;
            }
        }
    }
    #pragma unroll
    for (int i = 0; i < 4; ++i) {
        size_t base = (size_t)(tok0 + ty * 4 + i) * EMB + tx * 8;
        #pragma unroll
        for (int q = 0; q < 8; ++q)
            h[base + q] = h[base + q] + acc[i][q] + bo[tx * 8 + q];
    }
}

// ------------------------------ K3a: GEMM1 (h@W1, gelu) --------------------
__global__ __launch_bounds__(256) void k_gemm1(const float* __restrict__ h,
        const float* __restrict__ W1, const float* __restrict__ b1,
        float* __restrict__ Hm) {
    __shared__ float As[64 * 132];   // [token][k], pad 132
    __shared__ float Ws[32 * 132];   // [kk][col], pad 132
    int tid = threadIdx.x;
    int chunk = blockIdx.x;          // 0..3 -> output cols chunk*128..+127
    int tok0 = blockIdx.y * 64;      // token tile (local to eighth)
    int tx = tid & 15, ty = tid >> 4;
    for (int idx = tid; idx < 64 * 128; idx += 256) {
        int t = idx >> 7, k = idx & 127;
        As[t * 132 + k] = h[(size_t)(tok0 + t) * EMB + k];
    }
    float acc[4][8];
    #pragma unroll
    for (int i = 0; i < 4; ++i)
        #pragma unroll
        for (int q = 0; q < 8; ++q) acc[i][q] = 0.f;
    for (int ks = 0; ks < 4; ++ks) {
        __syncthreads();
        for (int idx = tid; idx < 32 * 128; idx += 256) {
            int kk = idx >> 7, c = idx & 127;
            Ws[kk * 132 + c] = W1[(size_t)(ks * 32 + kk) * HIDD + chunk * 128 + c];
        }
        __syncthreads();
        #pragma unroll 4
        for (int kk = 0; kk < 32; ++kk) {
            float4 w0 = *(const float4*)&Ws[kk * 132 + tx * 8];
            float4 w1 = *(const float4*)&Ws[kk * 132 + tx * 8 + 4];
            #pragma unroll
            for (int i = 0; i < 4; ++i) {
                float a = As[(ty * 4 + i) * 132 + ks * 32 + kk];
                acc[i][0] += a * w0.x; acc[i][1] += a * w0.y;
                acc[i][2] += a * w0.z; acc[i][3] += a * w0.w;
                acc[i][4] += a * w1.x; acc[i][5] += a * w1.y;
                acc[i][6] += a * w1.z; acc[i][7] += a * w1.w;
            }
        }
    }
    #pragma unroll
    for (int i = 0; i < 4; ++i) {
        size_t base = (size_t)(tok0 + ty * 4 + i) * HIDD + chunk * 128 + tx * 8;
        #pragma unroll
        for (int q = 0; q < 8; ++q) {
            float a = acc[i][q] + b1[chunk * 128 + tx * 8 + q];
            Hm[base + q] = 0.5f * a * (1.f + erff(a * 0.70710678118654752f));
        }
    }
}

// ------------------------------ K3b: GEMM2 (Hm@W2, backflow) ---------------
__global__ __launch_bounds__(256) void k_gemm2(const float* __restrict__ Hm,
        const float* __restrict__ W2, const float* __restrict__ b2,
        const float* __restrict__ ftn, float* __restrict__ vecs, int e8) {
    __shared__ float As[64 * 33];    // [batch][kk], pad 33
    __shared__ float Ws[32 * 132];   // [kk][col], pad 132
    int tid = threadIdx.x;
    int pair = blockIdx.x;
    int s = c_ps[pair], chunk = c_pc[pair];
    int b0 = blockIdx.y * 64;        // batch tile (local to eighth)
    int off = c_offs[s], size = c_offs[s + 1] - off;
    int tx = tid & 15, ty = tid >> 4;
    float acc[4][8];
    #pragma unroll
    for (int i = 0; i < 4; ++i)
        #pragma unroll
        for (int q = 0; q < 8; ++q) acc[i][q] = 0.f;
    for (int ks = 0; ks < 16; ++ks) {
        __syncthreads();
        for (int idx = tid; idx < 64 * 32; idx += 256) {
            int t = idx >> 5, kk = idx & 31;
            As[t * 33 + kk] = Hm[(size_t)((b0 + t) * NS + s) * HIDD + ks * 32 + kk];
        }
        for (int idx = tid; idx < 32 * 128; idx += 256) {
            int kk = idx >> 7, c = idx & 127;
            Ws[kk * 132 + c] = W2[(size_t)(ks * 32 + kk) * HIDD + chunk * 128 + c];
        }
        __syncthreads();
        #pragma unroll 4
        for (int kk = 0; kk < 32; ++kk) {
            float4 w0 = *(const float4*)&Ws[kk * 132 + tx * 8];
            float4 w1 = *(const float4*)&Ws[kk * 132 + tx * 8 + 4];
            #pragma unroll
            for (int i = 0; i < 4; ++i) {
                float a = As[(ty * 4 + i) * 33 + kk];
                acc[i][0] += a * w0.x; acc[i][1] += a * w0.y;
                acc[i][2] += a * w0.z; acc[i][3] += a * w0.w;
                acc[i][4] += a * w1.x; acc[i][5] += a * w1.y;
                acc[i][6] += a * w1.z; acc[i][7] += a * w1.w;
            }
        }
    }
    #pragma unroll
    for (int i = 0; i < 4; ++i) {
        int bg = e8 * 256 + b0 + ty * 4 + i;     // global batch
        #pragma unroll
        for (int q = 0; q < 8; ++q) {
            int col = chunk * 128 + tx * 8 + q;
            if (col < size) {
                float o = acc[i][q] + b2[col];
                vecs[(size_t)bg * TOTV + off + col] = ftn[off + col] + 0.1f * o;
            }
        }
    }
}

// ------------------------------ K4a: build Psi -----------------------------
__device__ __forceinline__ float* build_half(const float* __restrict__ vb,
        const int* __restrict__ xb, int side, int upper,
        float* cur, float* fre, float* ts0, float* ts1, float* ts2, int tid) {
    if (tid == 0) cur[0] = 1.0f;
    __syncthreads();
    int bd = 1, lgbd = 0;
    for (int t = 0; t < 3; ++t) {
        int xd = t ? 4 : 1, lgxd = t ? 2 : 0;
        int j = side ? (5 - t) : t;
        int rows[3];
        rows[0] = upper ? 0 : 5; rows[1] = upper ? 1 : 4; rows[2] = upper ? 2 : 3;
        for (int role = 0; role < 3; ++role) {
            int i = rows[role];
            int dd = (i < 5) ? 4 : 1, dl = (j > 0) ? 4 : 1, dr = (j < 5) ? 4 : 1;
            int su = dd * dl * dr * 2, sd = dl * dr * 2, sl = dr * 2, sr = 2;
            int xstr = side ? sr : sl, ystr = side ? sl : sr;
            int base = c_offs[i * 6 + j] + xb[i * 6 + j];
            if (role == 0) {
                int astr = upper ? sd : su;
                int n = 4 * xd * 4;
                for (int idx = tid; idx < n; idx += 256) {
                    int y = idx & 3, xx = (idx >> 2) & (xd - 1), a = idx >> (2 + lgxd);
                    ts0[idx] = vb[base + a * astr + xx * xstr + y * ystr];
                }
            } else if (role == 1) {
                int astr = upper ? su : sd, cstr = upper ? sd : su;
                int n = 16 * xd * 4;
                for (int idx = tid; idx < n; idx += 256) {
                    int y = idx & 3, xx = (idx >> 2) & (xd - 1);
                    int c = (idx >> (2 + lgxd)) & 3, a = idx >> (4 + lgxd);
                    ts1[idx] = vb[base + a * astr + c * cstr + xx * xstr + y * ystr];
                }
            } else {
                int cstr = upper ? su : sd, bstr = upper ? sd : su;
                int n = 16 * xd * 4;
                for (int idx = tid; idx < n; idx += 256) {
                    int y = idx & 3, xx = (idx >> 2) & (xd - 1);
                    int bb = (idx >> (2 + lgxd)) & 3, c = idx >> (4 + lgxd);
                    ts2[idx] = vb[base + c * cstr + bb * bstr + xx * xstr + y * ystr];
                }
            }
        }
        __syncthreads();
        int n1 = 16 * xd * xd * bd;
        for (int idx = tid; idx < n1; idx += 256) {
            int bt = idx & (bd - 1);
            int r = idx >> lgbd;
            int x2 = r & (xd - 1); r >>= lgxd;
            int x1 = r & (xd - 1); r >>= lgxd;
            int a = r & 3, y0 = r >> 2;
            float s2 = 0.f;
            for (int x0 = 0; x0 < xd; ++x0)
                s2 += cur[(((((x0 << lgxd) | x1) << lgxd) | x2) << lgbd) | bt]
                    * ts0[(((a << lgxd) | x0) << 2) | y0];
            fre[idx] = s2;
        }
        __syncthreads();
        int n2 = 64 * xd * bd;
        for (int idx = tid; idx < n2; idx += 256) {
            int bt = idx & (bd - 1);
            int r = idx >> lgbd;
            int x2 = r & (xd - 1); r >>= lgxd;
            int c = r & 3, y1 = (r >> 2) & 3, y0 = r >> 4;
            float s2 = 0.f;
            for (int a = 0; a < 4; ++a)
                for (int x1 = 0; x1 < xd; ++x1)
                    s2 += fre[((((((((y0 << 2) | a) << lgxd) | x1) << lgxd) | x2)) << lgbd) | bt]
                        * ts1[((((a * 4 + c) << lgxd) | x1) << 2) | y1];
            cur[idx] = s2;
        }
        __syncthreads();
        int n3 = 256 * bd;
        for (int idx = tid; idx < n3; idx += 256) {
            int bn = idx & (4 * bd - 1);
            int bt = bn >> 2, bb = bn & 3;
            int r = idx >> (lgbd + 2);
            int y2 = r & 3, y1 = (r >> 2) & 3, y0 = r >> 4;
            float s2 = 0.f;
            for (int c = 0; c < 4; ++c)
                for (int x2 = 0; x2 < xd; ++x2)
                    s2 += cur[((((((y0 << 2) | y1) << 2 | c) << lgxd) | x2) << lgbd) | bt]
                        * ts2[((((c * 4 + bb) << lgxd) | x2) << 2) | y2];
            fre[idx] = s2;
        }
        __syncthreads();
        float* tmp = cur; cur = fre; fre = tmp;
        bd <<= 2; lgbd += 2;
    }
    return cur;
}

__global__ __launch_bounds__(256) void k_build(const float* __restrict__ vecs,
        const int* __restrict__ x, float* __restrict__ psi) {
    __shared__ float X1[4096], X2[4096], X3[4096];
    __shared__ float ts0[64], ts1[256], ts2[256];
    int m = blockIdx.x;
    int b = m >> 1, side = m & 1;
    int tid = threadIdx.x;
    const float* vb = vecs + (size_t)b * TOTV;
    const int* xb = x + b * NS;
    float* A  = build_half(vb, xb, side, 1, X1, X2, ts0, ts1, ts2, tid);
    float* Bt = build_half(vb, xb, side, 0, X1, X3, ts0, ts1, ts2, tid);
    float* po = psi + (size_t)m * 4096;
    for (int idx = tid; idx < 4096; idx += 256) {
        int u = idx >> 6, l = idx & 63;
        const float4* a4 = (const float4*)(A + u * 64);
        const float4* b4 = (const float4*)(Bt + l * 64);
        float s2 = 0.f;
        #pragma unroll
        for (int q = 0; q < 16; ++q) {
            float4 av = a4[q], bv = b4[q];
            s2 += av.x * bv.x + av.y * bv.y + av.z * bv.z + av.w * bv.w;
        }
        po[idx] = s2;
    }
}

// ------------------------------ K4b: Jacobi SVD ----------------------------
// 2 waves per 128-thread block, each wave owns one 64x64 matrix. Lane j
// holds column j of W in 4 ext_vector(16) values (packed fp32 math).
// R11: coarse sweep-exit -- keep rotating pairs above 1e-5 rel, but exit
// the sweep loop once a full sweep sees no pair above 1e-3 rel (quadratic
// convergence makes later sweeps pure polish; projector error ~1e-3 rel
// -> amp error ~2e-6 abs, threshold 3.43e-5). Cap 6 sweeps.
__global__ __launch_bounds__(128, 2) void k_svd(const float* __restrict__ psi,
                                                float* __restrict__ wv) {
    __shared__ __align__(16) float qlds[2][64 * 20];   // per-wave Q slab
    int wid = threadIdx.x >> 6, lane = threadIdx.x & 63;
    int m = blockIdx.x * 2 + wid;
    const float* P = psi + (size_t)m * 4096;
    f16v w0, w1, w2, w3;
    #pragma unroll
    for (int r = 0; r < 16; ++r) w0[r] = P[r * 64 + lane];
    #pragma unroll
    for (int r = 0; r < 16; ++r) w1[r] = P[(r + 16) * 64 + lane];
    #pragma unroll
    for (int r = 0; r < 16; ++r) w2[r] = P[(r + 32) * 64 + lane];
    #pragma unroll
    for (int r = 0; r < 16; ++r) w3[r] = P[(r + 48) * 64 + lane];

    for (int sweep = 0; sweep < 6; ++sweep) {
        f16v nv = w0 * w0 + w1 * w1 + w2 * w2 + w3 * w3;
        float n2 = hsum16(nv);                  // exact refresh per sweep
        bool anyBig = false;
        for (int mm = 1; mm < 64; ++mm) {
            int partner = lane ^ mm;
            f16v p0, p1, p2, p3;
            #pragma unroll
            for (int r = 0; r < 16; ++r) p0[r] = __shfl(w0[r], partner);
            #pragma unroll
            for (int r = 0; r < 16; ++r) p1[r] = __shfl(w1[r], partner);
            #pragma unroll
            for (int r = 0; r < 16; ++r) p2[r] = __shfl(w2[r], partner);
            #pragma unroll
            for (int r = 0; r < 16; ++r) p3[r] = __shfl(w3[r], partner);
            f16v gv = w0 * p0 + w1 * p1 + w2 * p2 + w3 * p3;
            float gam = hsum16(gv);
            float beta2 = __shfl(n2, partner);
            float scale = sqrtf(fmaxf(n2 * beta2, 0.f));
            bool rot = fabsf(gam) > 1e-5f * scale;
            bool big = fabsf(gam) > 1e-3f * scale;
            unsigned long long balBig = __ballot(big);
            if (balBig != 0ull) anyBig = true;
            unsigned long long bal = __ballot(rot);
            if (bal == 0ull) continue;
            float c = 1.f, s = 0.f;
            if (rot) {
                float zeta = (n2 - beta2) / (2.f * gam);
                float sgn = (zeta > 0.f) ? 1.f :
                            ((zeta < 0.f) ? -1.f : ((lane < partner) ? 1.f : -1.f));
                float tt = sgn / (fabsf(zeta) + sqrtf(1.f + zeta * zeta));
                c = 1.f / sqrtf(1.f + tt * tt);
                s = c * tt;
            }
            w0 = c * w0 + s * p0;
            w1 = c * w1 + s * p1;
            w2 = c * w2 + s * p2;
            w3 = c * w3 + s * p3;
            n2 = c * c * n2 + s * s * beta2 + 2.f * c * s * gam;
        }
        if (!anyBig) break;
    }
    // exact norms -> rank by descending norm (index tie-break)
    f16v ne = w0 * w0 + w1 * w1 + w2 * w2 + w3 * w3;
    float n2e = hsum16(ne);
    int rank = 0;
    for (int j = 0; j < 64; ++j) {
        float nj = __shfl(n2e, j);
        if (nj > n2e || (nj == n2e && j < lane)) ++rank;
    }
    float inv = (n2e > 1e-30f) ? 1.f / sqrtf(n2e) : 0.f;
    // stage Q (top-16 normalized columns) into this wave's LDS slab
    if (rank < 16) {
        #pragma unroll
        for (int r = 0; r < 16; ++r) {
            qlds[wid][r * 20 + rank]        = w0[r] * inv;
            qlds[wid][(r + 16) * 20 + rank] = w1[r] * inv;
            qlds[wid][(r + 32) * 20 + rank] = w2[r] * inv;
            qlds[wid][(r + 48) * 20 + rank] = w3[r] * inv;
        }
    }
    __syncthreads();
    float* o = wv + (size_t)m * 2048;
    #pragma unroll
    for (int k = 0; k < 16; ++k) o[k * 64 + lane] = qlds[wid][lane * 20 + k];
    // T = Q^T Psi : lane computes T[0..15][lane], re-reading Psi from L2
    f16v t;
    #pragma unroll
    for (int k = 0; k < 16; ++k) t[k] = 0.f;
    for (int r = 0; r < 64; ++r) {
        float pr = P[r * 64 + lane];
        const float4* q4 = (const float4*)&qlds[wid][r * 20];
        float4 a = q4[0], b = q4[1], cc = q4[2], d = q4[3];
        t[0]  += a.x  * pr; t[1]  += a.y  * pr; t[2]  += a.z  * pr; t[3]  += a.w  * pr;
        t[4]  += b.x  * pr; t[5]  += b.y  * pr; t[6]  += b.z  * pr; t[7]  += b.w  * pr;
        t[8]  += cc.x * pr; t[9]  += cc.y * pr; t[10] += cc.z * pr; t[11] += cc.w * pr;
        t[12] += d.x  * pr; t[13] += d.y  * pr; t[14] += d.z  * pr; t[15] += d.w  * pr;
    }
    #pragma unroll
    for (int k = 0; k < 16; ++k) o[1024 + k * 64 + lane] = t[k];
}

// ------------------------------ K4c: amplitude -----------------------------
__global__ __launch_bounds__(256) void k_amp(const float* __restrict__ wv,
                                             float* __restrict__ out) {
    __shared__ float s[4096];
    __shared__ float part[4];
    int b = blockIdx.x, tid = threadIdx.x;
    const float* src = wv + (size_t)b * 4096;
    for (int i = tid; i < 4096; i += 256) s[i] = src[i];
    __syncthreads();
    int k = tid >> 4, mm = tid & 15;
    const float* WL = s;
    const float* VL = s + 1024;
    const float* WR = s + 2048;
    const float* VR = s + 3072;
    float du = 0.f, dv = 0.f;
    for (int r = 0; r < 64; ++r) {
        du += WL[k * 64 + r] * WR[mm * 64 + r];
        dv += VL[k * 64 + r] * VR[mm * 64 + r];
    }
    float p = du * dv;
    for (int off = 32; off > 0; off >>= 1) p += __shfl_down(p, off);
    if ((tid & 63) == 0) part[tid >> 6] = p;
    __syncthreads();
    if (tid == 0) out[b] = part[0] + part[1] + part[2] + part[3];
}

// ------------------------------ launch -------------------------------------
extern "C" void kernel_launch(void* const* d_in, const int* in_sizes, int n_in,
                              void* d_out, int out_size, void* d_ws, size_t ws_size,
                              hipStream_t stream) {
    const int*   x    = (const int*)d_in[0];
    const float* ftn  = (const float*)d_in[1];
    const float* emb  = (const float*)d_in[2];
    const float* pos  = (const float*)d_in[3];
    const float* Wqkv = (const float*)d_in[4];
    const float* bqkv = (const float*)d_in[5];
    const float* Wo   = (const float*)d_in[6];
    const float* bo   = (const float*)d_in[7];
    const float* W1   = (const float*)d_in[8];
    const float* b1   = (const float*)d_in[9];
    const float* W2   = (const float*)d_in[10];
    const float* b2   = (const float*)d_in[11];
    float* out = (float*)d_out;
    float* ws  = (float*)d_ws;

    // layout (floats), total 46.4M = 186 MB:
    //   [0, 16777216)           psi; h at [0, 9437184), Hm_e at [9437184,..)
    //   [16777216, 38010880)    vecs (2048*10368)
    //   [38010880, 46399488)    wv
    //   qkv (28.3M) transiently occupies [16777216, 45088768) -- dead before
    //   gemm2 writes vecs and before svd writes wv.
    float* h    = ws;
    float* Hm_e = ws + 9437184;          // 2304 tokens * 512
    float* psi  = ws;
    float* vecs = ws + 16777216;
    float* qkv  = ws + 16777216;
    float* wv   = ws + 16777216 + 21233664;

    hipLaunchKernelGGL(k_embed, dim3((BSZ * NS * EMB + 255) / 256), dim3(256), 0, stream,
                       x, emb, pos, h);
    hipLaunchKernelGGL(k_qkv, dim3(3, 1152), dim3(256), 0, stream,
                       h, Wqkv, bqkv, qkv);
    hipLaunchKernelGGL(k_attnc, dim3(BSZ * NHEAD / 4), dim3(256), 0, stream, qkv);
    hipLaunchKernelGGL(k_oproj, dim3(1152), dim3(256), 0, stream,
                       qkv, Wo, bo, h);
    for (int e8 = 0; e8 < 8; ++e8) {
        const float* h_e = h + (size_t)e8 * 9216 * EMB;
        hipLaunchKernelGGL(k_gemm1, dim3(4, 144), dim3(256), 0, stream,
                           h_e, W1, b1, Hm_e);
        hipLaunchKernelGGL(k_gemm2, dim3(84, 4), dim3(256), 0, stream,
                           Hm_e, W2, b2, ftn, vecs, e8);
    }
    hipLaunchKernelGGL(k_build, dim3(2 * BSZ), dim3(256), 0, stream, vecs, x, psi);
    hipLaunchKernelGGL(k_svd, dim3(BSZ), dim3(128), 0, stream, psi, wv);
    hipLaunchKernelGGL(k_amp, dim3(BSZ), dim3(256), 0, stream, wv, out);
}

// Round 12
// 3076.295 us; speedup vs baseline: 1.7689x; 1.0701x over previous
//
#include <hip/hip_runtime.h>
#include <math.h>

// ---------------------------------------------------------------------------
// Transformer_fPEPS: transformer (f32 VALU GEMMs) + PEPS amplitude.
//
// Math reduction (validated R1, absmax 3.8e-6): every SVD in the reference
// _compress is lossless gauge EXCEPT the bond-(2,3) truncation (64 -> chi=16)
// on each side. amp(b) = < rank16(Psi_L), rank16(Psi_R) >_F.
//
// R12: k_svd is DS-pipe-bound; dur tracks sweep count (R11 validated:
// coarse-exit 1e-3 cut 1.96->1.45ms, absmax 3.8e-6). One more notch:
// coarse-exit 4e-3, cap 5. Error chain measured: 1e-5 rot -> 1.9e-6;
// 1e-3 exit -> 3.8e-6; predict 4e-3 -> ~1-2e-5 < 3.43e-5 threshold.
// ---------------------------------------------------------------------------

#define BSZ   2048
#define NS    36
#define EMB   128
#define NHEAD 8
#define DH    16
#define HIDD  512
#define TOTV  10368

typedef float f16v __attribute__((ext_vector_type(16)));

__device__ __forceinline__ float hsum16(f16v v) {
    float a = (v[0] + v[1]) + (v[2] + v[3]);
    float b = (v[4] + v[5]) + (v[6] + v[7]);
    float c = (v[8] + v[9]) + (v[10] + v[11]);
    float d = (v[12] + v[13]) + (v[14] + v[15]);
    return (a + b) + (c + d);
}

__constant__ int c_offs[37] = {
    0,32,160,288,416,544,576,
    704,1216,1728,2240,2752,2880,
    3008,3520,4032,4544,5056,5184,
    5312,5824,6336,6848,7360,7488,
    7616,8128,8640,9152,9664,9792,
    9824,9952,10080,10208,10336,10368};

// (site, col-chunk) pairs for trimmed GEMM2: 84 pairs
__constant__ int c_ps[84] = {
    0,1,2,3,4,5,
    6,7,7,7,7,8,8,8,8,9,9,9,9,10,10,10,10,11,
    12,13,13,13,13,14,14,14,14,15,15,15,15,16,16,16,16,17,
    18,19,19,19,19,20,20,20,20,21,21,21,21,22,22,22,22,23,
    24,25,25,25,25,26,26,26,26,27,27,27,27,28,28,28,28,29,
    30,31,32,33,34,35};
__constant__ int c_pc[84] = {
    0,0,0,0,0,0,
    0,0,1,2,3,0,1,2,3,0,1,2,3,0,1,2,3,0,
    0,0,1,2,3,0,1,2,3,0,1,2,3,0,1,2,3,0,
    0,0,1,2,3,0,1,2,3,0,1,2,3,0,1,2,3,0,
    0,0,1,2,3,0,1,2,3,0,1,2,3,0,1,2,3,0,
    0,0,0,0,0,0};

// ------------------------------ K1: embed ----------------------------------
__global__ __launch_bounds__(256) void k_embed(const int* __restrict__ x,
        const float* __restrict__ emb, const float* __restrict__ pos,
        float* __restrict__ h) {
    int idx = blockIdx.x * 256 + threadIdx.x;
    if (idx >= BSZ * NS * EMB) return;
    int e = idx & (EMB - 1);
    int g = idx >> 7;            // token
    int s = g % NS;
    h[idx] = emb[x[g] * EMB + e] + pos[s * EMB + e];
}

// ------------------------------ K2a: QKV GEMM ------------------------------
// [73728 x 128] @ [128 x 384] + bias. 64 tokens x 128 cols per block.
__global__ __launch_bounds__(256) void k_qkv(const float* __restrict__ h,
        const float* __restrict__ Wqkv, const float* __restrict__ bqkv,
        float* __restrict__ qkv) {
    __shared__ float As[64 * 132];
    __shared__ float Ws[32 * 132];
    int tid = threadIdx.x;
    int chunk = blockIdx.x;          // 0..2 -> output cols chunk*128..+127
    int tok0 = blockIdx.y * 64;
    int tx = tid & 15, ty = tid >> 4;
    for (int idx = tid; idx < 64 * 128; idx += 256) {
        int t = idx >> 7, k = idx & 127;
        As[t * 132 + k] = h[(size_t)(tok0 + t) * EMB + k];
    }
    float acc[4][8];
    #pragma unroll
    for (int i = 0; i < 4; ++i)
        #pragma unroll
        for (int q = 0; q < 8; ++q) acc[i][q] = 0.f;
    for (int ks = 0; ks < 4; ++ks) {
        __syncthreads();
        for (int idx = tid; idx < 32 * 128; idx += 256) {
            int kk = idx >> 7, c = idx & 127;
            Ws[kk * 132 + c] = Wqkv[(size_t)(ks * 32 + kk) * 384 + chunk * 128 + c];
        }
        __syncthreads();
        #pragma unroll 4
        for (int kk = 0; kk < 32; ++kk) {
            float4 w0 = *(const float4*)&Ws[kk * 132 + tx * 8];
            float4 w1 = *(const float4*)&Ws[kk * 132 + tx * 8 + 4];
            #pragma unroll
            for (int i = 0; i < 4; ++i) {
                float a = As[(ty * 4 + i) * 132 + ks * 32 + kk];
                acc[i][0] += a * w0.x; acc[i][1] += a * w0.y;
                acc[i][2] += a * w0.z; acc[i][3] += a * w0.w;
                acc[i][4] += a * w1.x; acc[i][5] += a * w1.y;
                acc[i][6] += a * w1.z; acc[i][7] += a * w1.w;
            }
        }
    }
    #pragma unroll
    for (int i = 0; i < 4; ++i) {
        size_t base = (size_t)(tok0 + ty * 4 + i) * 384 + chunk * 128 + tx * 8;
        #pragma unroll
        for (int q = 0; q < 8; ++q)
            qkv[base + q] = acc[i][q] + bqkv[chunk * 128 + tx * 8 + q];
    }
}

// ------------------------------ K2b: attention core ------------------------
// One wave per (batch, head). q/k/v staged in padded LDS (stride 17),
// scores in stride-37 LDS, softmax per row, o overwrites the dead q-slot.
__global__ __launch_bounds__(256) void k_attnc(float* __restrict__ qkv) {
    __shared__ float qs[4][NS * 17];
    __shared__ float ks_[4][NS * 17];
    __shared__ float vs[4][NS * 17];
    __shared__ float S[4][NS * 37];
    int wid = threadIdx.x >> 6, lane = threadIdx.x & 63;
    int m = blockIdx.x * 4 + wid;
    int b = m >> 3, hd = m & 7;
    float* Q = qkv + (size_t)b * NS * 384 + hd * DH;   // row stride 384
    for (int idx = lane; idx < NS * DH; idx += 64) {
        int t = idx >> 4, d = idx & 15;
        qs[wid][t * 17 + d]  = Q[t * 384 + d];
        ks_[wid][t * 17 + d] = Q[t * 384 + 128 + d];
        vs[wid][t * 17 + d]  = Q[t * 384 + 256 + d];
    }
    __syncthreads();
    for (int idx = lane; idx < NS * NS; idx += 64) {
        int qp = idx / NS, kp = idx - qp * NS;
        float acc = 0.f;
        #pragma unroll
        for (int d = 0; d < DH; ++d)
            acc += qs[wid][qp * 17 + d] * ks_[wid][kp * 17 + d];
        S[wid][qp * 37 + kp] = acc * 0.25f;     // 1/sqrt(16)
    }
    __syncthreads();
    if (lane < NS) {
        float mx = -1e30f;
        for (int j = 0; j < NS; ++j) mx = fmaxf(mx, S[wid][lane * 37 + j]);
        float z = 0.f;
        for (int j = 0; j < NS; ++j) {
            float e = expf(S[wid][lane * 37 + j] - mx);
            S[wid][lane * 37 + j] = e; z += e;
        }
        float inv = 1.f / z;
        for (int j = 0; j < NS; ++j) S[wid][lane * 37 + j] *= inv;
    }
    __syncthreads();
    for (int idx = lane; idx < NS * DH; idx += 64) {
        int qp = idx >> 4, d = idx & 15;
        float acc = 0.f;
        for (int kp = 0; kp < NS; ++kp)
            acc += S[wid][qp * 37 + kp] * vs[wid][kp * 17 + d];
        Q[qp * 384 + d] = acc;                  // o into dead q-slot
    }
}

// ------------------------------ K2c: out-proj + residual -------------------
// h += o @ Wo + bo, o rows at qkv[tok*384 + 0..127].
__global__ __launch_bounds__(256) void k_oproj(const float* __restrict__ qkv,
        const float* __restrict__ Wo, const float* __restrict__ bo,
        float* __restrict__ h) {
    __shared__ float As[64 * 132];
    __shared__ float Ws[32 * 132];
    int tid = threadIdx.x;
    int tok0 = blockIdx.x * 64;
    int tx = tid & 15, ty = tid >> 4;
    for (int idx = tid; idx < 64 * 128; idx += 256) {
        int t = idx >> 7, k = idx & 127;
        As[t * 132 + k] = qkv[(size_t)(tok0 + t) * 384 + k];
    }
    float acc[4][8];
    #pragma unroll
    for (int i = 0; i < 4; ++i)
        #pragma unroll
        for (int q = 0; q < 8; ++q) acc[i][q] = 0.f;
    for (int ks = 0; ks < 4; ++ks) {
        __syncthreads();
        for (int idx = tid; idx < 32 * 128; idx += 256) {
            int kk = idx >> 7, c = idx & 127;
            Ws[kk * 132 + c] = Wo[(size_t)(ks * 32 + kk) * EMB + c];
        }
        __syncthreads();
        #pragma unroll 4
        for (int kk = 0; kk < 32; ++kk) {
            float4 w0 = *(const float4*)&Ws[kk * 132 + tx * 8];
            float4 w1 = *(const float4*)&Ws[kk * 132 + tx * 8 + 4];
            #pragma unroll
            for (int i = 0; i < 4; ++i) {
                float a = As[(ty * 4 + i) * 132 + ks * 32 + kk];
                acc[i][0] += a * w0.x; acc[i][1] += a * w0.y;
                acc[i][2] += a * w0.z; acc[i][3] += a * w0.w;
                acc[i][4] += a * w1.x; acc[i][5] += a * w1.y;
                acc[i][6] += a * w1.z; acc[i][7] += a * w1.w;
            }
        }
    }
    #pragma unroll
    for (int i = 0; i < 4; ++i) {
        size_t base = (size_t)(tok0 + ty * 4 + i) * EMB + tx * 8;
        #pragma unroll
        for (int q = 0; q < 8; ++q)
            h[base + q] = h[base + q] + acc[i][q] + bo[tx * 8 + q];
    }
}

// ------------------------------ K3a: GEMM1 (h@W1, gelu) --------------------
__global__ __launch_bounds__(256) void k_gemm1(const float* __restrict__ h,
        const float* __restrict__ W1, const float* __restrict__ b1,
        float* __restrict__ Hm) {
    __shared__ float As[64 * 132];   // [token][k], pad 132
    __shared__ float Ws[32 * 132];   // [kk][col], pad 132
    int tid = threadIdx.x;
    int chunk = blockIdx.x;          // 0..3 -> output cols chunk*128..+127
    int tok0 = blockIdx.y * 64;      // token tile (local to eighth)
    int tx = tid & 15, ty = tid >> 4;
    for (int idx = tid; idx < 64 * 128; idx += 256) {
        int t = idx >> 7, k = idx & 127;
        As[t * 132 + k] = h[(size_t)(tok0 + t) * EMB + k];
    }
    float acc[4][8];
    #pragma unroll
    for (int i = 0; i < 4; ++i)
        #pragma unroll
        for (int q = 0; q < 8; ++q) acc[i][q] = 0.f;
    for (int ks = 0; ks < 4; ++ks) {
        __syncthreads();
        for (int idx = tid; idx < 32 * 128; idx += 256) {
            int kk = idx >> 7, c = idx & 127;
            Ws[kk * 132 + c] = W1[(size_t)(ks * 32 + kk) * HIDD + chunk * 128 + c];
        }
        __syncthreads();
        #pragma unroll 4
        for (int kk = 0; kk < 32; ++kk) {
            float4 w0 = *(const float4*)&Ws[kk * 132 + tx * 8];
            float4 w1 = *(const float4*)&Ws[kk * 132 + tx * 8 + 4];
            #pragma unroll
            for (int i = 0; i < 4; ++i) {
                float a = As[(ty * 4 + i) * 132 + ks * 32 + kk];
                acc[i][0] += a * w0.x; acc[i][1] += a * w0.y;
                acc[i][2] += a * w0.z; acc[i][3] += a * w0.w;
                acc[i][4] += a * w1.x; acc[i][5] += a * w1.y;
                acc[i][6] += a * w1.z; acc[i][7] += a * w1.w;
            }
        }
    }
    #pragma unroll
    for (int i = 0; i < 4; ++i) {
        size_t base = (size_t)(tok0 + ty * 4 + i) * HIDD + chunk * 128 + tx * 8;
        #pragma unroll
        for (int q = 0; q < 8; ++q) {
            float a = acc[i][q] + b1[chunk * 128 + tx * 8 + q];
            Hm[base + q] = 0.5f * a * (1.f + erff(a * 0.70710678118654752f));
        }
    }
}

// ------------------------------ K3b: GEMM2 (Hm@W2, backflow) ---------------
__global__ __launch_bounds__(256) void k_gemm2(const float* __restrict__ Hm,
        const float* __restrict__ W2, const float* __restrict__ b2,
        const float* __restrict__ ftn, float* __restrict__ vecs, int e8) {
    __shared__ float As[64 * 33];    // [batch][kk], pad 33
    __shared__ float Ws[32 * 132];   // [kk][col], pad 132
    int tid = threadIdx.x;
    int pair = blockIdx.x;
    int s = c_ps[pair], chunk = c_pc[pair];
    int b0 = blockIdx.y * 64;        // batch tile (local to eighth)
    int off = c_offs[s], size = c_offs[s + 1] - off;
    int tx = tid & 15, ty = tid >> 4;
    float acc[4][8];
    #pragma unroll
    for (int i = 0; i < 4; ++i)
        #pragma unroll
        for (int q = 0; q < 8; ++q) acc[i][q] = 0.f;
    for (int ks = 0; ks < 16; ++ks) {
        __syncthreads();
        for (int idx = tid; idx < 64 * 32; idx += 256) {
            int t = idx >> 5, kk = idx & 31;
            As[t * 33 + kk] = Hm[(size_t)((b0 + t) * NS + s) * HIDD + ks * 32 + kk];
        }
        for (int idx = tid; idx < 32 * 128; idx += 256) {
            int kk = idx >> 7, c = idx & 127;
            Ws[kk * 132 + c] = W2[(size_t)(ks * 32 + kk) * HIDD + chunk * 128 + c];
        }
        __syncthreads();
        #pragma unroll 4
        for (int kk = 0; kk < 32; ++kk) {
            float4 w0 = *(const float4*)&Ws[kk * 132 + tx * 8];
            float4 w1 = *(const float4*)&Ws[kk * 132 + tx * 8 + 4];
            #pragma unroll
            for (int i = 0; i < 4; ++i) {
                float a = As[(ty * 4 + i) * 33 + kk];
                acc[i][0] += a * w0.x; acc[i][1] += a * w0.y;
                acc[i][2] += a * w0.z; acc[i][3] += a * w0.w;
                acc[i][4] += a * w1.x; acc[i][5] += a * w1.y;
                acc[i][6] += a * w1.z; acc[i][7] += a * w1.w;
            }
        }
    }
    #pragma unroll
    for (int i = 0; i < 4; ++i) {
        int bg = e8 * 256 + b0 + ty * 4 + i;     // global batch
        #pragma unroll
        for (int q = 0; q < 8; ++q) {
            int col = chunk * 128 + tx * 8 + q;
            if (col < size) {
                float o = acc[i][q] + b2[col];
                vecs[(size_t)bg * TOTV + off + col] = ftn[off + col] + 0.1f * o;
            }
        }
    }
}

// ------------------------------ K4a: build Psi -----------------------------
__device__ __forceinline__ float* build_half(const float* __restrict__ vb,
        const int* __restrict__ xb, int side, int upper,
        float* cur, float* fre, float* ts0, float* ts1, float* ts2, int tid) {
    if (tid == 0) cur[0] = 1.0f;
    __syncthreads();
    int bd = 1, lgbd = 0;
    for (int t = 0; t < 3; ++t) {
        int xd = t ? 4 : 1, lgxd = t ? 2 : 0;
        int j = side ? (5 - t) : t;
        int rows[3];
        rows[0] = upper ? 0 : 5; rows[1] = upper ? 1 : 4; rows[2] = upper ? 2 : 3;
        for (int role = 0; role < 3; ++role) {
            int i = rows[role];
            int dd = (i < 5) ? 4 : 1, dl = (j > 0) ? 4 : 1, dr = (j < 5) ? 4 : 1;
            int su = dd * dl * dr * 2, sd = dl * dr * 2, sl = dr * 2, sr = 2;
            int xstr = side ? sr : sl, ystr = side ? sl : sr;
            int base = c_offs[i * 6 + j] + xb[i * 6 + j];
            if (role == 0) {
                int astr = upper ? sd : su;
                int n = 4 * xd * 4;
                for (int idx = tid; idx < n; idx += 256) {
                    int y = idx & 3, xx = (idx >> 2) & (xd - 1), a = idx >> (2 + lgxd);
                    ts0[idx] = vb[base + a * astr + xx * xstr + y * ystr];
                }
            } else if (role == 1) {
                int astr = upper ? su : sd, cstr = upper ? sd : su;
                int n = 16 * xd * 4;
                for (int idx = tid; idx < n; idx += 256) {
                    int y = idx & 3, xx = (idx >> 2) & (xd - 1);
                    int c = (idx >> (2 + lgxd)) & 3, a = idx >> (4 + lgxd);
                    ts1[idx] = vb[base + a * astr + c * cstr + xx * xstr + y * ystr];
                }
            } else {
                int cstr = upper ? su : sd, bstr = upper ? sd : su;
                int n = 16 * xd * 4;
                for (int idx = tid; idx < n; idx += 256) {
                    int y = idx & 3, xx = (idx >> 2) & (xd - 1);
                    int bb = (idx >> (2 + lgxd)) & 3, c = idx >> (4 + lgxd);
                    ts2[idx] = vb[base + c * cstr + bb * bstr + xx * xstr + y * ystr];
                }
            }
        }
        __syncthreads();
        int n1 = 16 * xd * xd * bd;
        for (int idx = tid; idx < n1; idx += 256) {
            int bt = idx & (bd - 1);
            int r = idx >> lgbd;
            int x2 = r & (xd - 1); r >>= lgxd;
            int x1 = r & (xd - 1); r >>= lgxd;
            int a = r & 3, y0 = r >> 2;
            float s2 = 0.f;
            for (int x0 = 0; x0 < xd; ++x0)
                s2 += cur[(((((x0 << lgxd) | x1) << lgxd) | x2) << lgbd) | bt]
                    * ts0[(((a << lgxd) | x0) << 2) | y0];
            fre[idx] = s2;
        }
        __syncthreads();
        int n2 = 64 * xd * bd;
        for (int idx = tid; idx < n2; idx += 256) {
            int bt = idx & (bd - 1);
            int r = idx >> lgbd;
            int x2 = r & (xd - 1); r >>= lgxd;
            int c = r & 3, y1 = (r >> 2) & 3, y0 = r >> 4;
            float s2 = 0.f;
            for (int a = 0; a < 4; ++a)
                for (int x1 = 0; x1 < xd; ++x1)
                    s2 += fre[((((((((y0 << 2) | a) << lgxd) | x1) << lgxd) | x2)) << lgbd) | bt]
                        * ts1[((((a * 4 + c) << lgxd) | x1) << 2) | y1];
            cur[idx] = s2;
        }
        __syncthreads();
        int n3 = 256 * bd;
        for (int idx = tid; idx < n3; idx += 256) {
            int bn = idx & (4 * bd - 1);
            int bt = bn >> 2, bb = bn & 3;
            int r = idx >> (lgbd + 2);
            int y2 = r & 3, y1 = (r >> 2) & 3, y0 = r >> 4;
            float s2 = 0.f;
            for (int c = 0; c < 4; ++c)
                for (int x2 = 0; x2 < xd; ++x2)
                    s2 += cur[((((((y0 << 2) | y1) << 2 | c) << lgxd) | x2) << lgbd) | bt]
                        * ts2[((((c * 4 + bb) << lgxd) | x2) << 2) | y2];
            fre[idx] = s2;
        }
        __syncthreads();
        float* tmp = cur; cur = fre; fre = tmp;
        bd <<= 2; lgbd += 2;
    }
    return cur;
}

__global__ __launch_bounds__(256) void k_build(const float* __restrict__ vecs,
        const int* __restrict__ x, float* __restrict__ psi) {
    __shared__ float X1[4096], X2[4096], X3[4096];
    __shared__ float ts0[64], ts1[256], ts2[256];
    int m = blockIdx.x;
    int b = m >> 1, side = m & 1;
    int tid = threadIdx.x;
    const float* vb = vecs + (size_t)b * TOTV;
    const int* xb = x + b * NS;
    float* A  = build_half(vb, xb, side, 1, X1, X2, ts0, ts1, ts2, tid);
    float* Bt = build_half(vb, xb, side, 0, X1, X3, ts0, ts1, ts2, tid);
    float* po = psi + (size_t)m * 4096;
    for (int idx = tid; idx < 4096; idx += 256) {
        int u = idx >> 6, l = idx & 63;
        const float4* a4 = (const float4*)(A + u * 64);
        const float4* b4 = (const float4*)(Bt + l * 64);
        float s2 = 0.f;
        #pragma unroll
        for (int q = 0; q < 16; ++q) {
            float4 av = a4[q], bv = b4[q];
            s2 += av.x * bv.x + av.y * bv.y + av.z * bv.z + av.w * bv.w;
        }
        po[idx] = s2;
    }
}

// ------------------------------ K4b: Jacobi SVD ----------------------------
// 2 waves per 128-thread block, each wave owns one 64x64 matrix. Lane j
// holds column j of W in 4 ext_vector(16) values (packed fp32 math).
// R12: coarse sweep-exit 4e-3 (was 1e-3), cap 5 -- rotations still applied
// down to 1e-5 rel while sweeping. DS-pipe-bound => dur ~ sweep count.
__global__ __launch_bounds__(128, 2) void k_svd(const float* __restrict__ psi,
                                                float* __restrict__ wv) {
    __shared__ __align__(16) float qlds[2][64 * 20];   // per-wave Q slab
    int wid = threadIdx.x >> 6, lane = threadIdx.x & 63;
    int m = blockIdx.x * 2 + wid;
    const float* P = psi + (size_t)m * 4096;
    f16v w0, w1, w2, w3;
    #pragma unroll
    for (int r = 0; r < 16; ++r) w0[r] = P[r * 64 + lane];
    #pragma unroll
    for (int r = 0; r < 16; ++r) w1[r] = P[(r + 16) * 64 + lane];
    #pragma unroll
    for (int r = 0; r < 16; ++r) w2[r] = P[(r + 32) * 64 + lane];
    #pragma unroll
    for (int r = 0; r < 16; ++r) w3[r] = P[(r + 48) * 64 + lane];

    for (int sweep = 0; sweep < 5; ++sweep) {
        f16v nv = w0 * w0 + w1 * w1 + w2 * w2 + w3 * w3;
        float n2 = hsum16(nv);                  // exact refresh per sweep
        bool anyBig = false;
        for (int mm = 1; mm < 64; ++mm) {
            int partner = lane ^ mm;
            f16v p0, p1, p2, p3;
            #pragma unroll
            for (int r = 0; r < 16; ++r) p0[r] = __shfl(w0[r], partner);
            #pragma unroll
            for (int r = 0; r < 16; ++r) p1[r] = __shfl(w1[r], partner);
            #pragma unroll
            for (int r = 0; r < 16; ++r) p2[r] = __shfl(w2[r], partner);
            #pragma unroll
            for (int r = 0; r < 16; ++r) p3[r] = __shfl(w3[r], partner);
            f16v gv = w0 * p0 + w1 * p1 + w2 * p2 + w3 * p3;
            float gam = hsum16(gv);
            float beta2 = __shfl(n2, partner);
            float scale = sqrtf(fmaxf(n2 * beta2, 0.f));
            bool rot = fabsf(gam) > 1e-5f * scale;
            bool big = fabsf(gam) > 4e-3f * scale;
            unsigned long long balBig = __ballot(big);
            if (balBig != 0ull) anyBig = true;
            unsigned long long bal = __ballot(rot);
            if (bal == 0ull) continue;
            float c = 1.f, s = 0.f;
            if (rot) {
                float zeta = (n2 - beta2) / (2.f * gam);
                float sgn = (zeta > 0.f) ? 1.f :
                            ((zeta < 0.f) ? -1.f : ((lane < partner) ? 1.f : -1.f));
                float tt = sgn / (fabsf(zeta) + sqrtf(1.f + zeta * zeta));
                c = 1.f / sqrtf(1.f + tt * tt);
                s = c * tt;
            }
            w0 = c * w0 + s * p0;
            w1 = c * w1 + s * p1;
            w2 = c * w2 + s * p2;
            w3 = c * w3 + s * p3;
            n2 = c * c * n2 + s * s * beta2 + 2.f * c * s * gam;
        }
        if (!anyBig) break;
    }
    // exact norms -> rank by descending norm (index tie-break)
    f16v ne = w0 * w0 + w1 * w1 + w2 * w2 + w3 * w3;
    float n2e = hsum16(ne);
    int rank = 0;
    for (int j = 0; j < 64; ++j) {
        float nj = __shfl(n2e, j);
        if (nj > n2e || (nj == n2e && j < lane)) ++rank;
    }
    float inv = (n2e > 1e-30f) ? 1.f / sqrtf(n2e) : 0.f;
    // stage Q (top-16 normalized columns) into this wave's LDS slab
    if (rank < 16) {
        #pragma unroll
        for (int r = 0; r < 16; ++r) {
            qlds[wid][r * 20 + rank]        = w0[r] * inv;
            qlds[wid][(r + 16) * 20 + rank] = w1[r] * inv;
            qlds[wid][(r + 32) * 20 + rank] = w2[r] * inv;
            qlds[wid][(r + 48) * 20 + rank] = w3[r] * inv;
        }
    }
    __syncthreads();
    float* o = wv + (size_t)m * 2048;
    #pragma unroll
    for (int k = 0; k < 16; ++k) o[k * 64 + lane] = qlds[wid][lane * 20 + k];
    // T = Q^T Psi : lane computes T[0..15][lane], re-reading Psi from L2
    f16v t;
    #pragma unroll
    for (int k = 0; k < 16; ++k) t[k] = 0.f;
    for (int r = 0; r < 64; ++r) {
        float pr = P[r * 64 + lane];
        const float4* q4 = (const float4*)&qlds[wid][r * 20];
        float4 a = q4[0], b = q4[1], cc = q4[2], d = q4[3];
        t[0]  += a.x  * pr; t[1]  += a.y  * pr; t[2]  += a.z  * pr; t[3]  += a.w  * pr;
        t[4]  += b.x  * pr; t[5]  += b.y  * pr; t[6]  += b.z  * pr; t[7]  += b.w  * pr;
        t[8]  += cc.x * pr; t[9]  += cc.y * pr; t[10] += cc.z * pr; t[11] += cc.w * pr;
        t[12] += d.x  * pr; t[13] += d.y  * pr; t[14] += d.z  * pr; t[15] += d.w  * pr;
    }
    #pragma unroll
    for (int k = 0; k < 16; ++k) o[1024 + k * 64 + lane] = t[k];
}

// ------------------------------ K4c: amplitude -----------------------------
__global__ __launch_bounds__(256) void k_amp(const float* __restrict__ wv,
                                             float* __restrict__ out) {
    __shared__ float s[4096];
    __shared__ float part[4];
    int b = blockIdx.x, tid = threadIdx.x;
    const float* src = wv + (size_t)b * 4096;
    for (int i = tid; i < 4096; i += 256) s[i] = src[i];
    __syncthreads();
    int k = tid >> 4, mm = tid & 15;
    const float* WL = s;
    const float* VL = s + 1024;
    const float* WR = s + 2048;
    const float* VR = s + 3072;
    float du = 0.f, dv = 0.f;
    for (int r = 0; r < 64; ++r) {
        du += WL[k * 64 + r] * WR[mm * 64 + r];
        dv += VL[k * 64 + r] * VR[mm * 64 + r];
    }
    float p = du * dv;
    for (int off = 32; off > 0; off >>= 1) p += __shfl_down(p, off);
    if ((tid & 63) == 0) part[tid >> 6] = p;
    __syncthreads();
    if (tid == 0) out[b] = part[0] + part[1] + part[2] + part[3];
}

// ------------------------------ launch -------------------------------------
extern "C" void kernel_launch(void* const* d_in, const int* in_sizes, int n_in,
                              void* d_out, int out_size, void* d_ws, size_t ws_size,
                              hipStream_t stream) {
    const int*   x    = (const int*)d_in[0];
    const float* ftn  = (const float*)d_in[1];
    const float* emb  = (const float*)d_in[2];
    const float* pos  = (const float*)d_in[3];
    const float* Wqkv = (const float*)d_in[4];
    const float* bqkv = (const float*)d_in[5];
    const float* Wo   = (const float*)d_in[6];
    const float* bo   = (const float*)d_in[7];
    const float* W1   = (const float*)d_in[8];
    const float* b1   = (const float*)d_in[9];
    const float* W2   = (const float*)d_in[10];
    const float* b2   = (const float*)d_in[11];
    float* out = (float*)d_out;
    float* ws  = (float*)d_ws;

    // layout (floats), total 46.4M = 186 MB:
    //   [0, 16777216)           psi; h at [0, 9437184), Hm_e at [9437184,..)
    //   [16777216, 38010880)    vecs (2048*10368)
    //   [38010880, 46399488)    wv
    //   qkv (28.3M) transiently occupies [16777216, 45088768) -- dead before
    //   gemm2 writes vecs and before svd writes wv.
    float* h    = ws;
    float* Hm_e = ws + 9437184;          // 2304 tokens * 512
    float* psi  = ws;
    float* vecs = ws + 16777216;
    float* qkv  = ws + 16777216;
    float* wv   = ws + 16777216 + 21233664;

    hipLaunchKernelGGL(k_embed, dim3((BSZ * NS * EMB + 255) / 256), dim3(256), 0, stream,
                       x, emb, pos, h);
    hipLaunchKernelGGL(k_qkv, dim3(3, 1152), dim3(256), 0, stream,
                       h, Wqkv, bqkv, qkv);
    hipLaunchKernelGGL(k_attnc, dim3(BSZ * NHEAD / 4), dim3(256), 0, stream, qkv);
    hipLaunchKernelGGL(k_oproj, dim3(1152), dim3(256), 0, stream,
                       qkv, Wo, bo, h);
    for (int e8 = 0; e8 < 8; ++e8) {
        const float* h_e = h + (size_t)e8 * 9216 * EMB;
        hipLaunchKernelGGL(k_gemm1, dim3(4, 144), dim3(256), 0, stream,
                           h_e, W1, b1, Hm_e);
        hipLaunchKernelGGL(k_gemm2, dim3(84, 4), dim3(256), 0, stream,
                           Hm_e, W2, b2, ftn, vecs, e8);
    }
    hipLaunchKernelGGL(k_build, dim3(2 * BSZ), dim3(256), 0, stream, vecs, x, psi);
    hipLaunchKernelGGL(k_svd, dim3(BSZ), dim3(128), 0, stream, psi, wv);
    hipLaunchKernelGGL(k_amp, dim3(BSZ), dim3(256), 0, stream, wv, out);
}

// Round 13
// 2928.563 us; speedup vs baseline: 1.8581x; 1.0504x over previous
//
#include <hip/hip_runtime.h>
#include <math.h>

// ---------------------------------------------------------------------------
// Transformer_fPEPS: transformer (f32 VALU GEMMs) + PEPS amplitude.
//
// Math reduction (validated R1): every SVD in the reference _compress is
// lossless gauge EXCEPT the bond-(2,3) truncation (64 -> chi=16) per side.
// amp(b) = < rank16(Psi_L), rank16(Psi_R) >_F.
//
// R13: k_svd is latency-bound on the shfl->gam->rotate chain (measured DS
// floor ~0.62ms vs 1.24ms actual; VALUBusy 42%, occ 23%). Two matrices per
// wave (64-thr blocks, launch_bounds(64,1) => VGPR cap 512, no spill risk):
// A's shfls overlap B's VALU. Per-matrix math is bit-identical to R12
// (absmax must stay 3.147e-5 -- frozen, margin is thin: 3.15e-5/3.43e-5).
// ---------------------------------------------------------------------------

#define BSZ   2048
#define NS    36
#define EMB   128
#define NHEAD 8
#define DH    16
#define HIDD  512
#define TOTV  10368

typedef float f16v __attribute__((ext_vector_type(16)));

__device__ __forceinline__ float hsum16(f16v v) {
    float a = (v[0] + v[1]) + (v[2] + v[3]);
    float b = (v[4] + v[5]) + (v[6] + v[7]);
    float c = (v[8] + v[9]) + (v[10] + v[11]);
    float d = (v[12] + v[13]) + (v[14] + v[15]);
    return (a + b) + (c + d);
}

__constant__ int c_offs[37] = {
    0,32,160,288,416,544,576,
    704,1216,1728,2240,2752,2880,
    3008,3520,4032,4544,5056,5184,
    5312,5824,6336,6848,7360,7488,
    7616,8128,8640,9152,9664,9792,
    9824,9952,10080,10208,10336,10368};

// (site, col-chunk) pairs for trimmed GEMM2: 84 pairs
__constant__ int c_ps[84] = {
    0,1,2,3,4,5,
    6,7,7,7,7,8,8,8,8,9,9,9,9,10,10,10,10,11,
    12,13,13,13,13,14,14,14,14,15,15,15,15,16,16,16,16,17,
    18,19,19,19,19,20,20,20,20,21,21,21,21,22,22,22,22,23,
    24,25,25,25,25,26,26,26,26,27,27,27,27,28,28,28,28,29,
    30,31,32,33,34,35};
__constant__ int c_pc[84] = {
    0,0,0,0,0,0,
    0,0,1,2,3,0,1,2,3,0,1,2,3,0,1,2,3,0,
    0,0,1,2,3,0,1,2,3,0,1,2,3,0,1,2,3,0,
    0,0,1,2,3,0,1,2,3,0,1,2,3,0,1,2,3,0,
    0,0,1,2,3,0,1,2,3,0,1,2,3,0,1,2,3,0,
    0,0,0,0,0,0};

// ------------------------------ K1: embed ----------------------------------
__global__ __launch_bounds__(256) void k_embed(const int* __restrict__ x,
        const float* __restrict__ emb, const float* __restrict__ pos,
        float* __restrict__ h) {
    int idx = blockIdx.x * 256 + threadIdx.x;
    if (idx >= BSZ * NS * EMB) return;
    int e = idx & (EMB - 1);
    int g = idx >> 7;            // token
    int s = g % NS;
    h[idx] = emb[x[g] * EMB + e] + pos[s * EMB + e];
}

// ------------------------------ K2a: QKV GEMM ------------------------------
// [73728 x 128] @ [128 x 384] + bias. 64 tokens x 128 cols per block.
__global__ __launch_bounds__(256) void k_qkv(const float* __restrict__ h,
        const float* __restrict__ Wqkv, const float* __restrict__ bqkv,
        float* __restrict__ qkv) {
    __shared__ float As[64 * 132];
    __shared__ float Ws[32 * 132];
    int tid = threadIdx.x;
    int chunk = blockIdx.x;          // 0..2 -> output cols chunk*128..+127
    int tok0 = blockIdx.y * 64;
    int tx = tid & 15, ty = tid >> 4;
    for (int idx = tid; idx < 64 * 128; idx += 256) {
        int t = idx >> 7, k = idx & 127;
        As[t * 132 + k] = h[(size_t)(tok0 + t) * EMB + k];
    }
    float acc[4][8];
    #pragma unroll
    for (int i = 0; i < 4; ++i)
        #pragma unroll
        for (int q = 0; q < 8; ++q) acc[i][q] = 0.f;
    for (int ks = 0; ks < 4; ++ks) {
        __syncthreads();
        for (int idx = tid; idx < 32 * 128; idx += 256) {
            int kk = idx >> 7, c = idx & 127;
            Ws[kk * 132 + c] = Wqkv[(size_t)(ks * 32 + kk) * 384 + chunk * 128 + c];
        }
        __syncthreads();
        #pragma unroll 4
        for (int kk = 0; kk < 32; ++kk) {
            float4 w0 = *(const float4*)&Ws[kk * 132 + tx * 8];
            float4 w1 = *(const float4*)&Ws[kk * 132 + tx * 8 + 4];
            #pragma unroll
            for (int i = 0; i < 4; ++i) {
                float a = As[(ty * 4 + i) * 132 + ks * 32 + kk];
                acc[i][0] += a * w0.x; acc[i][1] += a * w0.y;
                acc[i][2] += a * w0.z; acc[i][3] += a * w0.w;
                acc[i][4] += a * w1.x; acc[i][5] += a * w1.y;
                acc[i][6] += a * w1.z; acc[i][7] += a * w1.w;
            }
        }
    }
    #pragma unroll
    for (int i = 0; i < 4; ++i) {
        size_t base = (size_t)(tok0 + ty * 4 + i) * 384 + chunk * 128 + tx * 8;
        #pragma unroll
        for (int q = 0; q < 8; ++q)
            qkv[base + q] = acc[i][q] + bqkv[chunk * 128 + tx * 8 + q];
    }
}

// ------------------------------ K2b: attention core ------------------------
__global__ __launch_bounds__(256) void k_attnc(float* __restrict__ qkv) {
    __shared__ float qs[4][NS * 17];
    __shared__ float ks_[4][NS * 17];
    __shared__ float vs[4][NS * 17];
    __shared__ float S[4][NS * 37];
    int wid = threadIdx.x >> 6, lane = threadIdx.x & 63;
    int m = blockIdx.x * 4 + wid;
    int b = m >> 3, hd = m & 7;
    float* Q = qkv + (size_t)b * NS * 384 + hd * DH;   // row stride 384
    for (int idx = lane; idx < NS * DH; idx += 64) {
        int t = idx >> 4, d = idx & 15;
        qs[wid][t * 17 + d]  = Q[t * 384 + d];
        ks_[wid][t * 17 + d] = Q[t * 384 + 128 + d];
        vs[wid][t * 17 + d]  = Q[t * 384 + 256 + d];
    }
    __syncthreads();
    for (int idx = lane; idx < NS * NS; idx += 64) {
        int qp = idx / NS, kp = idx - qp * NS;
        float acc = 0.f;
        #pragma unroll
        for (int d = 0; d < DH; ++d)
            acc += qs[wid][qp * 17 + d] * ks_[wid][kp * 17 + d];
        S[wid][qp * 37 + kp] = acc * 0.25f;     // 1/sqrt(16)
    }
    __syncthreads();
    if (lane < NS) {
        float mx = -1e30f;
        for (int j = 0; j < NS; ++j) mx = fmaxf(mx, S[wid][lane * 37 + j]);
        float z = 0.f;
        for (int j = 0; j < NS; ++j) {
            float e = expf(S[wid][lane * 37 + j] - mx);
            S[wid][lane * 37 + j] = e; z += e;
        }
        float inv = 1.f / z;
        for (int j = 0; j < NS; ++j) S[wid][lane * 37 + j] *= inv;
    }
    __syncthreads();
    for (int idx = lane; idx < NS * DH; idx += 64) {
        int qp = idx >> 4, d = idx & 15;
        float acc = 0.f;
        for (int kp = 0; kp < NS; ++kp)
            acc += S[wid][qp * 37 + kp] * vs[wid][kp * 17 + d];
        Q[qp * 384 + d] = acc;                  // o into dead q-slot
    }
}

// ------------------------------ K2c: out-proj + residual -------------------
__global__ __launch_bounds__(256) void k_oproj(const float* __restrict__ qkv,
        const float* __restrict__ Wo, const float* __restrict__ bo,
        float* __restrict__ h) {
    __shared__ float As[64 * 132];
    __shared__ float Ws[32 * 132];
    int tid = threadIdx.x;
    int tok0 = blockIdx.x * 64;
    int tx = tid & 15, ty = tid >> 4;
    for (int idx = tid; idx < 64 * 128; idx += 256) {
        int t = idx >> 7, k = idx & 127;
        As[t * 132 + k] = qkv[(size_t)(tok0 + t) * 384 + k];
    }
    float acc[4][8];
    #pragma unroll
    for (int i = 0; i < 4; ++i)
        #pragma unroll
        for (int q = 0; q < 8; ++q) acc[i][q] = 0.f;
    for (int ks = 0; ks < 4; ++ks) {
        __syncthreads();
        for (int idx = tid; idx < 32 * 128; idx += 256) {
            int kk = idx >> 7, c = idx & 127;
            Ws[kk * 132 + c] = Wo[(size_t)(ks * 32 + kk) * EMB + c];
        }
        __syncthreads();
        #pragma unroll 4
        for (int kk = 0; kk < 32; ++kk) {
            float4 w0 = *(const float4*)&Ws[kk * 132 + tx * 8];
            float4 w1 = *(const float4*)&Ws[kk * 132 + tx * 8 + 4];
            #pragma unroll
            for (int i = 0; i < 4; ++i) {
                float a = As[(ty * 4 + i) * 132 + ks * 32 + kk];
                acc[i][0] += a * w0.x; acc[i][1] += a * w0.y;
                acc[i][2] += a * w0.z; acc[i][3] += a * w0.w;
                acc[i][4] += a * w1.x; acc[i][5] += a * w1.y;
                acc[i][6] += a * w1.z; acc[i][7] += a * w1.w;
            }
        }
    }
    #pragma unroll
    for (int i = 0; i < 4; ++i) {
        size_t base = (size_t)(tok0 + ty * 4 + i) * EMB + tx * 8;
        #pragma unroll
        for (int q = 0; q < 8; ++q)
            h[base + q] = h[base + q] + acc[i][q] + bo[tx * 8 + q];
    }
}

// ------------------------------ K3a: GEMM1 (h@W1, gelu) --------------------
__global__ __launch_bounds__(256) void k_gemm1(const float* __restrict__ h,
        const float* __restrict__ W1, const float* __restrict__ b1,
        float* __restrict__ Hm) {
    __shared__ float As[64 * 132];   // [token][k], pad 132
    __shared__ float Ws[32 * 132];   // [kk][col], pad 132
    int tid = threadIdx.x;
    int chunk = blockIdx.x;          // 0..3 -> output cols chunk*128..+127
    int tok0 = blockIdx.y * 64;      // token tile (local to eighth)
    int tx = tid & 15, ty = tid >> 4;
    for (int idx = tid; idx < 64 * 128; idx += 256) {
        int t = idx >> 7, k = idx & 127;
        As[t * 132 + k] = h[(size_t)(tok0 + t) * EMB + k];
    }
    float acc[4][8];
    #pragma unroll
    for (int i = 0; i < 4; ++i)
        #pragma unroll
        for (int q = 0; q < 8; ++q) acc[i][q] = 0.f;
    for (int ks = 0; ks < 4; ++ks) {
        __syncthreads();
        for (int idx = tid; idx < 32 * 128; idx += 256) {
            int kk = idx >> 7, c = idx & 127;
            Ws[kk * 132 + c] = W1[(size_t)(ks * 32 + kk) * HIDD + chunk * 128 + c];
        }
        __syncthreads();
        #pragma unroll 4
        for (int kk = 0; kk < 32; ++kk) {
            float4 w0 = *(const float4*)&Ws[kk * 132 + tx * 8];
            float4 w1 = *(const float4*)&Ws[kk * 132 + tx * 8 + 4];
            #pragma unroll
            for (int i = 0; i < 4; ++i) {
                float a = As[(ty * 4 + i) * 132 + ks * 32 + kk];
                acc[i][0] += a * w0.x; acc[i][1] += a * w0.y;
                acc[i][2] += a * w0.z; acc[i][3] += a * w0.w;
                acc[i][4] += a * w1.x; acc[i][5] += a * w1.y;
                acc[i][6] += a * w1.z; acc[i][7] += a * w1.w;
            }
        }
    }
    #pragma unroll
    for (int i = 0; i < 4; ++i) {
        size_t base = (size_t)(tok0 + ty * 4 + i) * HIDD + chunk * 128 + tx * 8;
        #pragma unroll
        for (int q = 0; q < 8; ++q) {
            float a = acc[i][q] + b1[chunk * 128 + tx * 8 + q];
            Hm[base + q] = 0.5f * a * (1.f + erff(a * 0.70710678118654752f));
        }
    }
}

// ------------------------------ K3b: GEMM2 (Hm@W2, backflow) ---------------
__global__ __launch_bounds__(256) void k_gemm2(const float* __restrict__ Hm,
        const float* __restrict__ W2, const float* __restrict__ b2,
        const float* __restrict__ ftn, float* __restrict__ vecs, int e8) {
    __shared__ float As[64 * 33];    // [batch][kk], pad 33
    __shared__ float Ws[32 * 132];   // [kk][col], pad 132
    int tid = threadIdx.x;
    int pair = blockIdx.x;
    int s = c_ps[pair], chunk = c_pc[pair];
    int b0 = blockIdx.y * 64;        // batch tile (local to eighth)
    int off = c_offs[s], size = c_offs[s + 1] - off;
    int tx = tid & 15, ty = tid >> 4;
    float acc[4][8];
    #pragma unroll
    for (int i = 0; i < 4; ++i)
        #pragma unroll
        for (int q = 0; q < 8; ++q) acc[i][q] = 0.f;
    for (int ks = 0; ks < 16; ++ks) {
        __syncthreads();
        for (int idx = tid; idx < 64 * 32; idx += 256) {
            int t = idx >> 5, kk = idx & 31;
            As[t * 33 + kk] = Hm[(size_t)((b0 + t) * NS + s) * HIDD + ks * 32 + kk];
        }
        for (int idx = tid; idx < 32 * 128; idx += 256) {
            int kk = idx >> 7, c = idx & 127;
            Ws[kk * 132 + c] = W2[(size_t)(ks * 32 + kk) * HIDD + chunk * 128 + c];
        }
        __syncthreads();
        #pragma unroll 4
        for (int kk = 0; kk < 32; ++kk) {
            float4 w0 = *(const float4*)&Ws[kk * 132 + tx * 8];
            float4 w1 = *(const float4*)&Ws[kk * 132 + tx * 8 + 4];
            #pragma unroll
            for (int i = 0; i < 4; ++i) {
                float a = As[(ty * 4 + i) * 33 + kk];
                acc[i][0] += a * w0.x; acc[i][1] += a * w0.y;
                acc[i][2] += a * w0.z; acc[i][3] += a * w0.w;
                acc[i][4] += a * w1.x; acc[i][5] += a * w1.y;
                acc[i][6] += a * w1.z; acc[i][7] += a * w1.w;
            }
        }
    }
    #pragma unroll
    for (int i = 0; i < 4; ++i) {
        int bg = e8 * 256 + b0 + ty * 4 + i;     // global batch
        #pragma unroll
        for (int q = 0; q < 8; ++q) {
            int col = chunk * 128 + tx * 8 + q;
            if (col < size) {
                float o = acc[i][q] + b2[col];
                vecs[(size_t)bg * TOTV + off + col] = ftn[off + col] + 0.1f * o;
            }
        }
    }
}

// ------------------------------ K4a: build Psi -----------------------------
__device__ __forceinline__ float* build_half(const float* __restrict__ vb,
        const int* __restrict__ xb, int side, int upper,
        float* cur, float* fre, float* ts0, float* ts1, float* ts2, int tid) {
    if (tid == 0) cur[0] = 1.0f;
    __syncthreads();
    int bd = 1, lgbd = 0;
    for (int t = 0; t < 3; ++t) {
        int xd = t ? 4 : 1, lgxd = t ? 2 : 0;
        int j = side ? (5 - t) : t;
        int rows[3];
        rows[0] = upper ? 0 : 5; rows[1] = upper ? 1 : 4; rows[2] = upper ? 2 : 3;
        for (int role = 0; role < 3; ++role) {
            int i = rows[role];
            int dd = (i < 5) ? 4 : 1, dl = (j > 0) ? 4 : 1, dr = (j < 5) ? 4 : 1;
            int su = dd * dl * dr * 2, sd = dl * dr * 2, sl = dr * 2, sr = 2;
            int xstr = side ? sr : sl, ystr = side ? sl : sr;
            int base = c_offs[i * 6 + j] + xb[i * 6 + j];
            if (role == 0) {
                int astr = upper ? sd : su;
                int n = 4 * xd * 4;
                for (int idx = tid; idx < n; idx += 256) {
                    int y = idx & 3, xx = (idx >> 2) & (xd - 1), a = idx >> (2 + lgxd);
                    ts0[idx] = vb[base + a * astr + xx * xstr + y * ystr];
                }
            } else if (role == 1) {
                int astr = upper ? su : sd, cstr = upper ? sd : su;
                int n = 16 * xd * 4;
                for (int idx = tid; idx < n; idx += 256) {
                    int y = idx & 3, xx = (idx >> 2) & (xd - 1);
                    int c = (idx >> (2 + lgxd)) & 3, a = idx >> (4 + lgxd);
                    ts1[idx] = vb[base + a * astr + c * cstr + xx * xstr + y * ystr];
                }
            } else {
                int cstr = upper ? su : sd, bstr = upper ? sd : su;
                int n = 16 * xd * 4;
                for (int idx = tid; idx < n; idx += 256) {
                    int y = idx & 3, xx = (idx >> 2) & (xd - 1);
                    int bb = (idx >> (2 + lgxd)) & 3, c = idx >> (4 + lgxd);
                    ts2[idx] = vb[base + c * cstr + bb * bstr + xx * xstr + y * ystr];
                }
            }
        }
        __syncthreads();
        int n1 = 16 * xd * xd * bd;
        for (int idx = tid; idx < n1; idx += 256) {
            int bt = idx & (bd - 1);
            int r = idx >> lgbd;
            int x2 = r & (xd - 1); r >>= lgxd;
            int x1 = r & (xd - 1); r >>= lgxd;
            int a = r & 3, y0 = r >> 2;
            float s2 = 0.f;
            for (int x0 = 0; x0 < xd; ++x0)
                s2 += cur[(((((x0 << lgxd) | x1) << lgxd) | x2) << lgbd) | bt]
                    * ts0[(((a << lgxd) | x0) << 2) | y0];
            fre[idx] = s2;
        }
        __syncthreads();
        int n2 = 64 * xd * bd;
        for (int idx = tid; idx < n2; idx += 256) {
            int bt = idx & (bd - 1);
            int r = idx >> lgbd;
            int x2 = r & (xd - 1); r >>= lgxd;
            int c = r & 3, y1 = (r >> 2) & 3, y0 = r >> 4;
            float s2 = 0.f;
            for (int a = 0; a < 4; ++a)
                for (int x1 = 0; x1 < xd; ++x1)
                    s2 += fre[((((((((y0 << 2) | a) << lgxd) | x1) << lgxd) | x2)) << lgbd) | bt]
                        * ts1[((((a * 4 + c) << lgxd) | x1) << 2) | y1];
            cur[idx] = s2;
        }
        __syncthreads();
        int n3 = 256 * bd;
        for (int idx = tid; idx < n3; idx += 256) {
            int bn = idx & (4 * bd - 1);
            int bt = bn >> 2, bb = bn & 3;
            int r = idx >> (lgbd + 2);
            int y2 = r & 3, y1 = (r >> 2) & 3, y0 = r >> 4;
            float s2 = 0.f;
            for (int c = 0; c < 4; ++c)
                for (int x2 = 0; x2 < xd; ++x2)
                    s2 += cur[((((((y0 << 2) | y1) << 2 | c) << lgxd) | x2) << lgbd) | bt]
                        * ts2[((((c * 4 + bb) << lgxd) | x2) << 2) | y2];
            fre[idx] = s2;
        }
        __syncthreads();
        float* tmp = cur; cur = fre; fre = tmp;
        bd <<= 2; lgbd += 2;
    }
    return cur;
}

__global__ __launch_bounds__(256) void k_build(const float* __restrict__ vecs,
        const int* __restrict__ x, float* __restrict__ psi) {
    __shared__ float X1[4096], X2[4096], X3[4096];
    __shared__ float ts0[64], ts1[256], ts2[256];
    int m = blockIdx.x;
    int b = m >> 1, side = m & 1;
    int tid = threadIdx.x;
    const float* vb = vecs + (size_t)b * TOTV;
    const int* xb = x + b * NS;
    float* A  = build_half(vb, xb, side, 1, X1, X2, ts0, ts1, ts2, tid);
    float* Bt = build_half(vb, xb, side, 0, X1, X3, ts0, ts1, ts2, tid);
    float* po = psi + (size_t)m * 4096;
    for (int idx = tid; idx < 4096; idx += 256) {
        int u = idx >> 6, l = idx & 63;
        const float4* a4 = (const float4*)(A + u * 64);
        const float4* b4 = (const float4*)(Bt + l * 64);
        float s2 = 0.f;
        #pragma unroll
        for (int q = 0; q < 16; ++q) {
            float4 av = a4[q], bv = b4[q];
            s2 += av.x * bv.x + av.y * bv.y + av.z * bv.z + av.w * bv.w;
        }
        po[idx] = s2;
    }
}

// ------------------------------ K4b: Jacobi SVD ----------------------------
// R13: ONE wave per block, TWO matrices per wave (lane j holds column j of
// both). A's shfl batch overlaps B's VALU -> 2x ILP on the latency chain.
// Per-matrix rotation sequence identical to R12 (absmax frozen at 3.147e-5).
// launch_bounds(64,1): VGPR cap 512 -- ~200 live regs, no spill possible.
__global__ __launch_bounds__(64, 1) void k_svd(const float* __restrict__ psi,
                                               float* __restrict__ wv) {
    __shared__ __align__(16) float qlds[2][64 * 20];
    int lane = threadIdx.x;
    int mA = blockIdx.x * 2;
    const float* PA = psi + (size_t)mA * 4096;
    const float* PB = PA + 4096;
    f16v a0, a1, a2, a3, b0, b1, b2, b3;
    #pragma unroll
    for (int r = 0; r < 16; ++r) a0[r] = PA[r * 64 + lane];
    #pragma unroll
    for (int r = 0; r < 16; ++r) a1[r] = PA[(r + 16) * 64 + lane];
    #pragma unroll
    for (int r = 0; r < 16; ++r) a2[r] = PA[(r + 32) * 64 + lane];
    #pragma unroll
    for (int r = 0; r < 16; ++r) a3[r] = PA[(r + 48) * 64 + lane];
    #pragma unroll
    for (int r = 0; r < 16; ++r) b0[r] = PB[r * 64 + lane];
    #pragma unroll
    for (int r = 0; r < 16; ++r) b1[r] = PB[(r + 16) * 64 + lane];
    #pragma unroll
    for (int r = 0; r < 16; ++r) b2[r] = PB[(r + 32) * 64 + lane];
    #pragma unroll
    for (int r = 0; r < 16; ++r) b3[r] = PB[(r + 48) * 64 + lane];

    bool actA = true, actB = true;
    for (int sweep = 0; sweep < 5; ++sweep) {
        if (!actA && !actB) break;
        float nA = 0.f, nB = 0.f;
        if (actA) {
            f16v nv = a0 * a0 + a1 * a1 + a2 * a2 + a3 * a3;
            nA = hsum16(nv);
        }
        if (actB) {
            f16v nv = b0 * b0 + b1 * b1 + b2 * b2 + b3 * b3;
            nB = hsum16(nv);
        }
        bool bigA = false, bigB = false;
        for (int mm = 1; mm < 64; ++mm) {
            int partner = lane ^ mm;
            if (actA) {
                f16v p0, p1, p2, p3;
                #pragma unroll
                for (int r = 0; r < 16; ++r) p0[r] = __shfl(a0[r], partner);
                #pragma unroll
                for (int r = 0; r < 16; ++r) p1[r] = __shfl(a1[r], partner);
                #pragma unroll
                for (int r = 0; r < 16; ++r) p2[r] = __shfl(a2[r], partner);
                #pragma unroll
                for (int r = 0; r < 16; ++r) p3[r] = __shfl(a3[r], partner);
                f16v gv = a0 * p0 + a1 * p1 + a2 * p2 + a3 * p3;
                float gam = hsum16(gv);
                float beta2 = __shfl(nA, partner);
                float scale = sqrtf(fmaxf(nA * beta2, 0.f));
                bool rot = fabsf(gam) > 1e-5f * scale;
                bool big = fabsf(gam) > 4e-3f * scale;
                if (__ballot(big) != 0ull) bigA = true;
                if (__ballot(rot) != 0ull) {
                    float c = 1.f, s = 0.f;
                    if (rot) {
                        float zeta = (nA - beta2) / (2.f * gam);
                        float sgn = (zeta > 0.f) ? 1.f :
                                    ((zeta < 0.f) ? -1.f : ((lane < partner) ? 1.f : -1.f));
                        float tt = sgn / (fabsf(zeta) + sqrtf(1.f + zeta * zeta));
                        c = 1.f / sqrtf(1.f + tt * tt);
                        s = c * tt;
                    }
                    a0 = c * a0 + s * p0;
                    a1 = c * a1 + s * p1;
                    a2 = c * a2 + s * p2;
                    a3 = c * a3 + s * p3;
                    nA = c * c * nA + s * s * beta2 + 2.f * c * s * gam;
                }
            }
            if (actB) {
                f16v p0, p1, p2, p3;
                #pragma unroll
                for (int r = 0; r < 16; ++r) p0[r] = __shfl(b0[r], partner);
                #pragma unroll
                for (int r = 0; r < 16; ++r) p1[r] = __shfl(b1[r], partner);
                #pragma unroll
                for (int r = 0; r < 16; ++r) p2[r] = __shfl(b2[r], partner);
                #pragma unroll
                for (int r = 0; r < 16; ++r) p3[r] = __shfl(b3[r], partner);
                f16v gv = b0 * p0 + b1 * p1 + b2 * p2 + b3 * p3;
                float gam = hsum16(gv);
                float beta2 = __shfl(nB, partner);
                float scale = sqrtf(fmaxf(nB * beta2, 0.f));
                bool rot = fabsf(gam) > 1e-5f * scale;
                bool big = fabsf(gam) > 4e-3f * scale;
                if (__ballot(big) != 0ull) bigB = true;
                if (__ballot(rot) != 0ull) {
                    float c = 1.f, s = 0.f;
                    if (rot) {
                        float zeta = (nB - beta2) / (2.f * gam);
                        float sgn = (zeta > 0.f) ? 1.f :
                                    ((zeta < 0.f) ? -1.f : ((lane < partner) ? 1.f : -1.f));
                        float tt = sgn / (fabsf(zeta) + sqrtf(1.f + zeta * zeta));
                        c = 1.f / sqrtf(1.f + tt * tt);
                        s = c * tt;
                    }
                    b0 = c * b0 + s * p0;
                    b1 = c * b1 + s * p1;
                    b2 = c * b2 + s * p2;
                    b3 = c * b3 + s * p3;
                    nB = c * c * nB + s * s * beta2 + 2.f * c * s * gam;
                }
            }
        }
        actA = actA && bigA;
        actB = actB && bigB;
    }

    // ---- epilogue matrix A ----
    {
        f16v ne = a0 * a0 + a1 * a1 + a2 * a2 + a3 * a3;
        float n2e = hsum16(ne);
        int rank = 0;
        for (int j = 0; j < 64; ++j) {
            float nj = __shfl(n2e, j);
            if (nj > n2e || (nj == n2e && j < lane)) ++rank;
        }
        float inv = (n2e > 1e-30f) ? 1.f / sqrtf(n2e) : 0.f;
        if (rank < 16) {
            #pragma unroll
            for (int r = 0; r < 16; ++r) {
                qlds[0][r * 20 + rank]        = a0[r] * inv;
                qlds[0][(r + 16) * 20 + rank] = a1[r] * inv;
                qlds[0][(r + 32) * 20 + rank] = a2[r] * inv;
                qlds[0][(r + 48) * 20 + rank] = a3[r] * inv;
            }
        }
    }
    // ---- epilogue matrix B ----
    {
        f16v ne = b0 * b0 + b1 * b1 + b2 * b2 + b3 * b3;
        float n2e = hsum16(ne);
        int rank = 0;
        for (int j = 0; j < 64; ++j) {
            float nj = __shfl(n2e, j);
            if (nj > n2e || (nj == n2e && j < lane)) ++rank;
        }
        float inv = (n2e > 1e-30f) ? 1.f / sqrtf(n2e) : 0.f;
        if (rank < 16) {
            #pragma unroll
            for (int r = 0; r < 16; ++r) {
                qlds[1][r * 20 + rank]        = b0[r] * inv;
                qlds[1][(r + 16) * 20 + rank] = b1[r] * inv;
                qlds[1][(r + 32) * 20 + rank] = b2[r] * inv;
                qlds[1][(r + 48) * 20 + rank] = b3[r] * inv;
            }
        }
    }
    __syncthreads();
    #pragma unroll
    for (int g = 0; g < 2; ++g) {
        const float* P = g ? PB : PA;
        float* o = wv + (size_t)(mA + g) * 2048;
        #pragma unroll
        for (int k = 0; k < 16; ++k) o[k * 64 + lane] = qlds[g][lane * 20 + k];
        f16v t;
        #pragma unroll
        for (int k = 0; k < 16; ++k) t[k] = 0.f;
        for (int r = 0; r < 64; ++r) {
            float pr = P[r * 64 + lane];
            const float4* q4 = (const float4*)&qlds[g][r * 20];
            float4 a = q4[0], b = q4[1], cc = q4[2], d = q4[3];
            t[0]  += a.x  * pr; t[1]  += a.y  * pr; t[2]  += a.z  * pr; t[3]  += a.w  * pr;
            t[4]  += b.x  * pr; t[5]  += b.y  * pr; t[6]  += b.z  * pr; t[7]  += b.w  * pr;
            t[8]  += cc.x * pr; t[9]  += cc.y * pr; t[10] += cc.z * pr; t[11] += cc.w * pr;
            t[12] += d.x  * pr; t[13] += d.y  * pr; t[14] += d.z  * pr; t[15] += d.w  * pr;
        }
        #pragma unroll
        for (int k = 0; k < 16; ++k) o[1024 + k * 64 + lane] = t[k];
    }
}

// ------------------------------ K4c: amplitude -----------------------------
__global__ __launch_bounds__(256) void k_amp(const float* __restrict__ wv,
                                             float* __restrict__ out) {
    __shared__ float s[4096];
    __shared__ float part[4];
    int b = blockIdx.x, tid = threadIdx.x;
    const float* src = wv + (size_t)b * 4096;
    for (int i = tid; i < 4096; i += 256) s[i] = src[i];
    __syncthreads();
    int k = tid >> 4, mm = tid & 15;
    const float* WL = s;
    const float* VL = s + 1024;
    const float* WR = s + 2048;
    const float* VR = s + 3072;
    float du = 0.f, dv = 0.f;
    for (int r = 0; r < 64; ++r) {
        du += WL[k * 64 + r] * WR[mm * 64 + r];
        dv += VL[k * 64 + r] * VR[mm * 64 + r];
    }
    float p = du * dv;
    for (int off = 32; off > 0; off >>= 1) p += __shfl_down(p, off);
    if ((tid & 63) == 0) part[tid >> 6] = p;
    __syncthreads();
    if (tid == 0) out[b] = part[0] + part[1] + part[2] + part[3];
}

// ------------------------------ launch -------------------------------------
extern "C" void kernel_launch(void* const* d_in, const int* in_sizes, int n_in,
                              void* d_out, int out_size, void* d_ws, size_t ws_size,
                              hipStream_t stream) {
    const int*   x    = (const int*)d_in[0];
    const float* ftn  = (const float*)d_in[1];
    const float* emb  = (const float*)d_in[2];
    const float* pos  = (const float*)d_in[3];
    const float* Wqkv = (const float*)d_in[4];
    const float* bqkv = (const float*)d_in[5];
    const float* Wo   = (const float*)d_in[6];
    const float* bo   = (const float*)d_in[7];
    const float* W1   = (const float*)d_in[8];
    const float* b1   = (const float*)d_in[9];
    const float* W2   = (const float*)d_in[10];
    const float* b2   = (const float*)d_in[11];
    float* out = (float*)d_out;
    float* ws  = (float*)d_ws;

    // layout (floats), total 46.4M = 186 MB:
    //   [0, 16777216)           psi; h at [0, 9437184), Hm_e at [9437184,..)
    //   [16777216, 38010880)    vecs (2048*10368)
    //   [38010880, 46399488)    wv
    //   qkv (28.3M) transiently occupies [16777216, 45088768) -- dead before
    //   gemm2 writes vecs and before svd writes wv.
    float* h    = ws;
    float* Hm_e = ws + 9437184;          // 2304 tokens * 512
    float* psi  = ws;
    float* vecs = ws + 16777216;
    float* qkv  = ws + 16777216;
    float* wv   = ws + 16777216 + 21233664;

    hipLaunchKernelGGL(k_embed, dim3((BSZ * NS * EMB + 255) / 256), dim3(256), 0, stream,
                       x, emb, pos, h);
    hipLaunchKernelGGL(k_qkv, dim3(3, 1152), dim3(256), 0, stream,
                       h, Wqkv, bqkv, qkv);
    hipLaunchKernelGGL(k_attnc, dim3(BSZ * NHEAD / 4), dim3(256), 0, stream, qkv);
    hipLaunchKernelGGL(k_oproj, dim3(1152), dim3(256), 0, stream,
                       qkv, Wo, bo, h);
    for (int e8 = 0; e8 < 8; ++e8) {
        const float* h_e = h + (size_t)e8 * 9216 * EMB;
        hipLaunchKernelGGL(k_gemm1, dim3(4, 144), dim3(256), 0, stream,
                           h_e, W1, b1, Hm_e);
        hipLaunchKernelGGL(k_gemm2, dim3(84, 4), dim3(256), 0, stream,
                           Hm_e, W2, b2, ftn, vecs, e8);
    }
    hipLaunchKernelGGL(k_build, dim3(2 * BSZ), dim3(256), 0, stream, vecs, x, psi);
    hipLaunchKernelGGL(k_svd, dim3(BSZ), dim3(64), 0, stream, psi, wv);
    hipLaunchKernelGGL(k_amp, dim3(BSZ), dim3(256), 0, stream, wv, out);
}